// Round 4
// baseline (330.271 us; speedup 1.0000x reference)
//
#include <hip/hip_runtime.h>
#include <math.h>

// Top-1 MoE, 7-dispatch pipeline.
//   memset -> prep -> gate_partial -> gate_finalize -> gemm1 -> gemm2 -> cheap.
// r13: cheap-expert dots ride gate_partial's MFMA (gvec); cheap blocks stream.
// r14: XCD-chunked swizzle on all MFMA GEMMs (FETCH 132->59MB).
// r15: 128x128 tiles, 4 waves of 64x64, global_load_lds dbuf staging.
// r16: un-fuse gemm2+cheap. The fused kernel's 33KB LDS starved the 8192
// one-token cheap blocks (Occupancy 10.8%, MfmaUtil 3.4%, 55us latency-bound).
// gemm2 is now pure GEMM (256 blocks); cheap_kernel is zero-LDS, 8-token
// expert-sorted tiles from tlist (no eid read, no divergence), FiLM j-outer
// with per-tile register accumulators -> fl_uw read once per tile (8x cut).

#define E 1024
#define GH 256
#define NEXP 6
#define NTOK 8192
#define NCH 24   // cheap-dot cols: 2 p2 + 4 p4 + 1 rg + 16 film + 1 pad

typedef __attribute__((ext_vector_type(8))) short bf16x8;
typedef __attribute__((ext_vector_type(4))) float f32x4;

__device__ __forceinline__ float gelu_erf(float v) {
    return 0.5f * v * (1.0f + erff(v * 0.70710678118654752440f));
}

__device__ __forceinline__ unsigned short f2bf(float f) {
    union { float f; unsigned u; } c; c.f = f;
    unsigned u = c.u;
    u += 0x7fffu + ((u >> 16) & 1u);   // RNE
    return (unsigned short)(u >> 16);
}

__device__ __forceinline__ float bf2f(unsigned short h) {
    union { unsigned u; float f; } c; c.u = ((unsigned)h) << 16;
    return c.f;
}

// LDS tile addressing (ushort units): row stride 32 (=64B), k-group XOR swizzle.
__device__ __forceinline__ int ldso(int row, int q) {
    return row * 32 + ((q ^ ((row >> 1) & 3)) << 3);
}

// async global->LDS, 16B per lane; lds dest is wave-uniform base + lane*16.
__device__ __forceinline__ void glds16(const void* g, void* l) {
    __builtin_amdgcn_global_load_lds(
        (const __attribute__((address_space(1))) void*)g,
        (__attribute__((address_space(3))) void*)l, 16, 0, 0);
}

// ---------------- prep: convert + all transposes, one kernel ----------------
__global__ __launch_bounds__(256)
void prep_kernel(const float* __restrict__ x, unsigned short* __restrict__ xh,
                 unsigned short* __restrict__ xl,
                 const float* __restrict__ gw1, unsigned short* __restrict__ w1cat,
                 const float* __restrict__ p2_w, const float* __restrict__ p4_w,
                 const float* __restrict__ rg_u, const float* __restrict__ fl_dw,
                 unsigned short* __restrict__ w1cheap,
                 const float* __restrict__ dfc_w, unsigned short* __restrict__ dfc_wt,
                 const float* __restrict__ dproj_w, unsigned short* __restrict__ dpj_wt,
                 const float* __restrict__ sfc_w, unsigned short* __restrict__ sfc_wt,
                 const float* __restrict__ sproj_w, unsigned short* __restrict__ spj_wt) {
    __shared__ float tile[32][33];
    const int tid = threadIdx.x;
    const int tx = tid & 31, ty = tid >> 5;
    int b = blockIdx.x;
    if (b < 2048) {                       // x -> x_hi + x_lo
        const int n4 = NTOK * E / 4;
        for (int i = b * 256 + tid; i < n4; i += 2048 * 256) {
            float4 v = reinterpret_cast<const float4*>(x)[i];
            ushort4 h, l;
            h.x = f2bf(v.x); l.x = f2bf(v.x - bf2f(h.x));
            h.y = f2bf(v.y); l.y = f2bf(v.y - bf2f(h.y));
            h.z = f2bf(v.z); l.z = f2bf(v.z - bf2f(h.z));
            h.w = f2bf(v.w); l.w = f2bf(v.w - bf2f(h.w));
            reinterpret_cast<ushort4*>(xh)[i] = h;
            reinterpret_cast<ushort4*>(xl)[i] = l;
        }
        return;
    }
    b -= 2048;
    if (b < 256) {                        // gw1 [E][GH] -> w1cat [GH][hi|lo]
        const int c0 = (b & 7) * 32, r0 = (b >> 3) * 32;
#pragma unroll
        for (int i = 0; i < 4; ++i)
            tile[ty + i * 8][tx] = gw1[(size_t)(r0 + ty + i * 8) * GH + c0 + tx];
        __syncthreads();
#pragma unroll
        for (int i = 0; i < 4; ++i) {
            float v = tile[tx][ty + i * 8];
            unsigned short h = f2bf(v);
            size_t row = (size_t)(c0 + ty + i * 8) * 2048;
            w1cat[row + r0 + tx] = h;
            w1cat[row + 1024 + r0 + tx] = f2bf(v - bf2f(h));
        }
        return;
    }
    b -= 256;
    if (b < 64) {                         // cheap-dot weights -> w1cheap [64][hi|lo]
        const int r = b;
        const int k4 = tid * 4;
        float4 v = {0.f, 0.f, 0.f, 0.f};
        if (r < 2)       v = *reinterpret_cast<const float4*>(&p2_w[r * E + k4]);
        else if (r < 6)  v = *reinterpret_cast<const float4*>(&p4_w[(r - 2) * E + k4]);
        else if (r == 6) v = *reinterpret_cast<const float4*>(&rg_u[k4]);
        else if (r < 23) {
            const int j = r - 7;          // fl_dw is [E][16]: gather column j
            v.x = fl_dw[(k4 + 0) * 16 + j];
            v.y = fl_dw[(k4 + 1) * 16 + j];
            v.z = fl_dw[(k4 + 2) * 16 + j];
            v.w = fl_dw[(k4 + 3) * 16 + j];
        }
        ushort4 h, l;
        h.x = f2bf(v.x); l.x = f2bf(v.x - bf2f(h.x));
        h.y = f2bf(v.y); l.y = f2bf(v.y - bf2f(h.y));
        h.z = f2bf(v.z); l.z = f2bf(v.z - bf2f(h.z));
        h.w = f2bf(v.w); l.w = f2bf(v.w - bf2f(h.w));
        *reinterpret_cast<ushort4*>(&w1cheap[r * 2048 + k4]) = h;
        *reinterpret_cast<ushort4*>(&w1cheap[r * 2048 + 1024 + k4]) = l;
        return;
    }
    b -= 64;
    const float* src; unsigned short* dst; int R, C, nbx;
    if (b < 2048)      { src = dfc_w;   dst = dfc_wt; R = 1024; C = 2048; nbx = 64; }
    else if (b < 4096) { src = dproj_w; dst = dpj_wt; R = 2048; C = 1024; nbx = 32; b -= 2048; }
    else if (b < 5120) { src = sfc_w;   dst = sfc_wt; R = 1024; C = 1024; nbx = 32; b -= 4096; }
    else               { src = sproj_w; dst = spj_wt; R = 1024; C = 1024; nbx = 32; b -= 5120; }
    const int c0 = (b % nbx) * 32, r0 = (b / nbx) * 32;
#pragma unroll
    for (int i = 0; i < 4; ++i)
        tile[ty + i * 8][tx] = src[(size_t)(r0 + ty + i * 8) * C + c0 + tx];
    __syncthreads();
#pragma unroll
    for (int i = 0; i < 4; ++i)
        dst[(size_t)(c0 + ty + i * 8) * R + r0 + tx] = f2bf(tile[tx][ty + i * 8]);
}

// ------ gate partial GEMM: hp[c2] = A_z @ w1cat[:, h-half], 128x128 tiles ---
// Grid 512. xcd=bid&7, slot=bid>>3; nx=slot&1; strip=xcd*32+(slot>>1);
// m=strip>>2, c2=strip&3 (z=c2&1, h=c2>>1). 4 waves of 64x64, glds dbuf.
// Cheap dots: every wave adds 2 MFMAs (cols nx*16..+15, rows wr*64+wc*32..+31).
__global__ __launch_bounds__(256)
void gate_partial_kernel(const unsigned short* __restrict__ xh,
                         const unsigned short* __restrict__ xl,
                         const unsigned short* __restrict__ w1cat,
                         const unsigned short* __restrict__ w1cheap,
                         float* __restrict__ hp,      // [4][NTOK][GH]
                         float* __restrict__ cdot) {  // [4][NTOK][NCH]
    __shared__ __align__(16) unsigned short As[2][128 * 32];
    __shared__ __align__(16) unsigned short Bs[2][128 * 32];
    const int tid = threadIdx.x;
    const int bid = blockIdx.x;
    const int xcd = bid & 7, slot = bid >> 3;
    const int nx = slot & 1;
    const int strip = xcd * 32 + (slot >> 1);      // [0,256)
    const int m = strip >> 2, c2 = strip & 3;
    const int z = c2 & 1, h = c2 >> 1;
    const int t0 = m * 128, n0 = nx * 128;
    const unsigned short* A = z ? xl : xh;
    float* hpz = hp + (size_t)c2 * ((size_t)NTOK * GH);
    float* cd  = cdot + (size_t)c2 * ((size_t)NTOK * NCH);

    const int lane = tid & 63, wv = tid >> 6;
    const int wr = wv >> 1, wc = wv & 1;
    const int lm = lane & 15, q = lane >> 4;
    const int r0 = tid >> 2, gsl = tid & 3;
    const int g = gsl ^ ((r0 >> 1) & 3);
    const int lbase = wv * 512;

    const unsigned short* pa0 = A + (size_t)(t0 + r0) * E + g * 8;
    const unsigned short* pa1 = A + (size_t)(t0 + 64 + r0) * E + g * 8;
    const unsigned short* pb0 = w1cat + (size_t)(n0 + r0) * 2048 + h * 1024 + g * 8;
    const unsigned short* pb1 = w1cat + (size_t)(n0 + 64 + r0) * 2048 + h * 1024 + g * 8;
    const unsigned short* pcw = w1cheap + (size_t)(nx * 16 + lm) * 2048 + h * 1024 + q * 8;

    f32x4 acc[4][4];
#pragma unroll
    for (int s = 0; s < 4; ++s)
#pragma unroll
        for (int t = 0; t < 4; ++t) acc[s][t] = (f32x4){0.f, 0.f, 0.f, 0.f};
    f32x4 accC[2];
    accC[0] = (f32x4){0.f, 0.f, 0.f, 0.f};
    accC[1] = (f32x4){0.f, 0.f, 0.f, 0.f};

    glds16(pa0, &As[0][lbase]);
    glds16(pa1, &As[0][2048 + lbase]);
    glds16(pb0, &Bs[0][lbase]);
    glds16(pb1, &Bs[0][2048 + lbase]);
    bf16x8 cfv = *(const bf16x8*)pcw;

    int cur = 0;
    for (int k0 = 0;; k0 += 32) {
        __syncthreads();                  // drains vmcnt -> buf[cur] landed
        const int kn = k0 + 32;
        bf16x8 cfn;
        if (kn < 1024) {
            glds16(pa0 + kn, &As[cur ^ 1][lbase]);
            glds16(pa1 + kn, &As[cur ^ 1][2048 + lbase]);
            glds16(pb0 + kn, &Bs[cur ^ 1][lbase]);
            glds16(pb1 + kn, &Bs[cur ^ 1][2048 + lbase]);
            cfn = *(const bf16x8*)(pcw + kn);
        }
        bf16x8 af[4], bfr[4];
#pragma unroll
        for (int s = 0; s < 4; ++s) af[s] = *(const bf16x8*)&As[cur][ldso(wr * 64 + s * 16 + lm, q)];
#pragma unroll
        for (int t = 0; t < 4; ++t) bfr[t] = *(const bf16x8*)&Bs[cur][ldso(wc * 64 + t * 16 + lm, q)];
#pragma unroll
        for (int s = 0; s < 4; ++s)
#pragma unroll
            for (int t = 0; t < 4; ++t)
                acc[s][t] = __builtin_amdgcn_mfma_f32_16x16x32_bf16(af[s], bfr[t], acc[s][t], 0, 0, 0);
        {
            bf16x8 ac0 = wc ? af[2] : af[0];
            bf16x8 ac1 = wc ? af[3] : af[1];
            accC[0] = __builtin_amdgcn_mfma_f32_16x16x32_bf16(ac0, cfv, accC[0], 0, 0, 0);
            accC[1] = __builtin_amdgcn_mfma_f32_16x16x32_bf16(ac1, cfv, accC[1], 0, 0, 0);
        }
        if (kn >= 1024) break;
        cfv = cfn; cur ^= 1;
    }
#pragma unroll
    for (int s = 0; s < 4; ++s)
#pragma unroll
        for (int t = 0; t < 4; ++t)
#pragma unroll
            for (int rg = 0; rg < 4; ++rg) {
                int rl = wr * 64 + s * 16 + q * 4 + rg;
                int c  = wc * 64 + t * 16 + lm;
                hpz[(size_t)(t0 + rl) * GH + n0 + c] = acc[s][t][rg];
            }
    const int cc = nx * 16 + lm;
    if (cc < NCH) {
#pragma unroll
        for (int i = 0; i < 2; ++i)
#pragma unroll
            for (int rg = 0; rg < 4; ++rg) {
                int rl = wr * 64 + wc * 32 + i * 16 + q * 4 + rg;
                cd[(size_t)(t0 + rl) * NCH + cc] = accC[i][rg];
            }
    }
}

// ------- finalize: h=gelu(sum4 hp+gb1); logits=h@gw2; softmax/argmax --------
// Also converts summed cheap dots (4 partials) into gate scalars gvec[NCH].
__global__ __launch_bounds__(256)
void gate_finalize_kernel(const float* __restrict__ hp,    // [4][NTOK][GH]
                          const float* __restrict__ gb1, const float* __restrict__ gw2,
                          const float* __restrict__ gb2, const float* __restrict__ ebias,
                          const float* __restrict__ pm_alpha,
                          const float* __restrict__ cdot,  // [4][NTOK][NCH]
                          const float* __restrict__ p2_alpha, const float* __restrict__ p2_b,
                          const float* __restrict__ p4_alpha, const float* __restrict__ p4_b,
                          const float* __restrict__ rg_b, const float* __restrict__ fl_db,
                          float* __restrict__ scale, int* __restrict__ counts,
                          int* __restrict__ tlist, int* __restrict__ eid,
                          float* __restrict__ gvec) {
    __shared__ float hs[32][264];
    __shared__ float g2s[GH * NEXP];
    __shared__ int tokexp[32];
    const int tid = threadIdx.x;
    const int t0 = blockIdx.x * 32;
    const size_t HPS = (size_t)NTOK * GH;
    for (int i = tid; i < GH * NEXP; i += 256) g2s[i] = gw2[i];
#pragma unroll
    for (int i = 0; i < 8; ++i) {
        int f4 = i * 256 + tid;
        int row = f4 >> 6, c4 = (f4 & 63) * 4;
        size_t base = (size_t)(t0 + row) * GH + c4;
        float4 a = *reinterpret_cast<const float4*>(&hp[base]);
        float4 b = *reinterpret_cast<const float4*>(&hp[HPS + base]);
        float4 c = *reinterpret_cast<const float4*>(&hp[2 * HPS + base]);
        float4 d = *reinterpret_cast<const float4*>(&hp[3 * HPS + base]);
        float4 o;
        o.x = gelu_erf(a.x + b.x + c.x + d.x + gb1[c4 + 0]);
        o.y = gelu_erf(a.y + b.y + c.y + d.y + gb1[c4 + 1]);
        o.z = gelu_erf(a.z + b.z + c.z + d.z + gb1[c4 + 2]);
        o.w = gelu_erf(a.w + b.w + c.w + d.w + gb1[c4 + 3]);
        *reinterpret_cast<float4*>(&hs[row][c4]) = o;
    }
    __syncthreads();
    const int t = tid >> 3, j = tid & 7;
    float p[NEXP] = {0.f, 0.f, 0.f, 0.f, 0.f, 0.f};
#pragma unroll 8
    for (int kk = 0; kk < 32; ++kk) {
        int k = j + kk * 8;
        float hv = hs[t][k];
        const float* gr = &g2s[k * NEXP];
#pragma unroll
        for (int m = 0; m < NEXP; ++m) p[m] += hv * gr[m];
    }
#pragma unroll
    for (int m = 0; m < NEXP; ++m) {
        p[m] += __shfl_xor(p[m], 4, 64);
        p[m] += __shfl_xor(p[m], 2, 64);
        p[m] += __shfl_xor(p[m], 1, 64);
    }
    if (j == 0) {
        float L[NEXP];
#pragma unroll
        for (int m = 0; m < NEXP; ++m) L[m] = p[m] + gb2[m] + ebias[m];
        float mx = L[0]; int am = 0;
#pragma unroll
        for (int m = 1; m < NEXP; ++m) { if (L[m] > mx) { mx = L[m]; am = m; } }
        float S = 0.f;
#pragma unroll
        for (int m = 0; m < NEXP; ++m) S += expf(L[m] - mx);
        float pt = 1.f / S;
        scale[t0 + t] = pm_alpha[0] * (pt / (pt + 1e-9f));
        eid[t0 + t] = am;
        tokexp[t] = am;
    }
    __syncthreads();
    if (tid < NEXP) {
        const int e = tid;
        int cnt = 0;
#pragma unroll
        for (int i = 0; i < 32; ++i) cnt += (tokexp[i] == e);
        if (cnt) {
            int base = atomicAdd(&counts[e], cnt);
            int pos = 0;
#pragma unroll
            for (int i = 0; i < 32; ++i)
                if (tokexp[i] == e) tlist[e * NTOK + base + (pos++)] = t0 + i;
        }
    }
    // ---- per-token cheap-gate scalars (independent of the above) ----
    const size_t CDS = (size_t)NTOK * NCH;
    for (int i = tid; i < 32 * NCH; i += 256) {
        const int tt = i / NCH, slot = i - tt * NCH;
        const int tok = t0 + tt;
        size_t idx = (size_t)tok * NCH + slot;
        float s = cdot[idx] + cdot[CDS + idx] + cdot[2 * CDS + idx] + cdot[3 * CDS + idx];
        float val;
        if (slot < 2)       val = p2_alpha[slot] * gelu_erf(s + p2_b[slot]);
        else if (slot < 6)  val = p4_alpha[slot - 2] * gelu_erf(s + p4_b[slot - 2]);
        else if (slot == 6) val = 1.f / (1.f + expf(-(s + rg_b[0])));
        else if (slot < 23) val = gelu_erf(s + fl_db[slot - 7]);
        else                val = 0.f;
        gvec[(size_t)tok * NCH + slot] = val;
    }
}

// ---------------- GEMM1: gather x_hi -> gelu -> packed bf16 h ---------------
// Grid 384. xcd=bid&7, slot=bid>>3 in [0,48): slot<32 -> z0, else z1.
// m = xcd + 8*l (strided). 128x128 tiles, 4 waves of 64x64, glds dbuf.
__global__ __launch_bounds__(256)
void moe_gemm1_kernel(const unsigned short* __restrict__ xh,
                      const unsigned short* __restrict__ B0, const unsigned short* __restrict__ B1,
                      const float* __restrict__ bias0, const float* __restrict__ bias1,
                      const int* __restrict__ counts, const int* __restrict__ tlist,
                      unsigned short* __restrict__ H0, unsigned short* __restrict__ H1) {
    __shared__ __align__(16) unsigned short As[2][128 * 32];
    __shared__ __align__(16) unsigned short Bs[2][128 * 32];
    __shared__ int toks[128];
    const int tid = threadIdx.x;
    const int bid = blockIdx.x;
    const int xcd = bid & 7, slot = bid >> 3;      // [0,48)
    int z, l, nx;
    if (slot < 32) { z = 0; l = slot >> 4; nx = slot & 15; }
    else           { z = 1; l = (slot - 32) >> 3; nx = (slot - 32) & 7; }
    const int mtile = xcd + 8 * l;
    const int i0 = mtile * 128, n0 = nx * 128;
    const int N = z ? 1024 : 2048;
    const int cnt = counts[z];
    if (i0 >= cnt) return;
    const unsigned short* Bz = z ? B1 : B0;
    const float* bias = z ? bias1 : bias0;

    if (tid < 128) toks[tid] = tlist[z * NTOK + min(i0 + tid, cnt - 1)];
    __syncthreads();

    const int lane = tid & 63, wv = tid >> 6;
    const int wr = wv >> 1, wc = wv & 1;
    const int lm = lane & 15, q = lane >> 4;
    const int r0 = tid >> 2, gsl = tid & 3;
    const int g = gsl ^ ((r0 >> 1) & 3);
    const int lbase = wv * 512;

    const unsigned short* pa0 = xh + (size_t)toks[r0] * E + g * 8;
    const unsigned short* pa1 = xh + (size_t)toks[64 + r0] * E + g * 8;
    const unsigned short* pb0 = Bz + (size_t)(n0 + r0) * E + g * 8;
    const unsigned short* pb1 = Bz + (size_t)(n0 + 64 + r0) * E + g * 8;

    f32x4 acc[4][4];
#pragma unroll
    for (int s = 0; s < 4; ++s)
#pragma unroll
        for (int t = 0; t < 4; ++t) acc[s][t] = (f32x4){0.f, 0.f, 0.f, 0.f};

    glds16(pa0, &As[0][lbase]);
    glds16(pa1, &As[0][2048 + lbase]);
    glds16(pb0, &Bs[0][lbase]);
    glds16(pb1, &Bs[0][2048 + lbase]);

    int cur = 0;
    for (int k0 = 0;; k0 += 32) {
        __syncthreads();
        const int kn = k0 + 32;
        if (kn < E) {
            glds16(pa0 + kn, &As[cur ^ 1][lbase]);
            glds16(pa1 + kn, &As[cur ^ 1][2048 + lbase]);
            glds16(pb0 + kn, &Bs[cur ^ 1][lbase]);
            glds16(pb1 + kn, &Bs[cur ^ 1][2048 + lbase]);
        }
        bf16x8 af[4], bfr[4];
#pragma unroll
        for (int s = 0; s < 4; ++s) af[s] = *(const bf16x8*)&As[cur][ldso(wr * 64 + s * 16 + lm, q)];
#pragma unroll
        for (int t = 0; t < 4; ++t) bfr[t] = *(const bf16x8*)&Bs[cur][ldso(wc * 64 + t * 16 + lm, q)];
#pragma unroll
        for (int s = 0; s < 4; ++s)
#pragma unroll
            for (int t = 0; t < 4; ++t)
                acc[s][t] = __builtin_amdgcn_mfma_f32_16x16x32_bf16(af[s], bfr[t], acc[s][t], 0, 0, 0);
        if (kn >= E) break;
        cur ^= 1;
    }
    unsigned short* Hz = z ? H1 : H0;
#pragma unroll
    for (int s = 0; s < 4; ++s)
#pragma unroll
        for (int t = 0; t < 4; ++t)
#pragma unroll
            for (int rg = 0; rg < 4; ++rg) {
                int rl = wr * 64 + s * 16 + q * 4 + rg;
                int gc = n0 + wc * 64 + t * 16 + lm;
                float v = acc[s][t][rg] + bias[gc];
                Hz[(size_t)(i0 + rl) * N + gc] = f2bf(gelu_erf(v));
            }
}

// ---------------- GEMM2 (experts 0/1 down-proj), pure GEMM ------------------
// Grid 256. xcd=bb&7, slot=bb>>3 in [0,32): z=slot>>4, l=(slot&15)>>3,
// nx=slot&7; m = xcd + 8*l. 128x128 tiles, glds dbuf.
__global__ __launch_bounds__(256)
void moe_gemm2_kernel(const unsigned short* __restrict__ h1, const unsigned short* __restrict__ h2,
                      const unsigned short* __restrict__ dpj, const unsigned short* __restrict__ spj,
                      const float* __restrict__ dproj_b, const float* __restrict__ sproj_b,
                      const int* __restrict__ counts, const int* __restrict__ tlist,
                      const float* __restrict__ scale,
                      float* __restrict__ out) {
    __shared__ __align__(16) unsigned short As[2][128 * 32];
    __shared__ __align__(16) unsigned short Bs[2][128 * 32];
    __shared__ int toks[128];
    const int tid = threadIdx.x;
    const int bb = blockIdx.x;
    const int lane = tid & 63;

    const int xcd = bb & 7, slot = bb >> 3;    // [0,32)
    const int z = slot >> 4;
    const int s2 = slot & 15;
    const int l = s2 >> 3, nx = s2 & 7;
    const int mtile = xcd + 8 * l;
    const int i0 = mtile * 128, n0 = nx * 128;
    const int K = z ? 1024 : 2048;
    const int cnt = counts[z];
    if (i0 >= cnt) return;
    const int rows = min(128, cnt - i0);
    const unsigned short* Az = z ? h2 : h1;
    const unsigned short* Bz = z ? spj : dpj;
    const float* bias = z ? sproj_b : dproj_b;

    if (tid < 128) toks[tid] = tlist[z * NTOK + min(i0 + tid, cnt - 1)];
    __syncthreads();

    const int wv = tid >> 6;
    const int wr = wv >> 1, wc = wv & 1;
    const int lm = lane & 15, q = lane >> 4;
    const int r0 = tid >> 2, gsl = tid & 3;
    const int g = gsl ^ ((r0 >> 1) & 3);
    const int lbase = wv * 512;

    const unsigned short* pa0 = Az + (size_t)(i0 + r0) * K + g * 8;
    const unsigned short* pa1 = Az + (size_t)(i0 + 64 + r0) * K + g * 8;
    const unsigned short* pb0 = Bz + (size_t)(n0 + r0) * K + g * 8;
    const unsigned short* pb1 = Bz + (size_t)(n0 + 64 + r0) * K + g * 8;

    f32x4 acc[4][4];
#pragma unroll
    for (int s = 0; s < 4; ++s)
#pragma unroll
        for (int t = 0; t < 4; ++t) acc[s][t] = (f32x4){0.f, 0.f, 0.f, 0.f};

    glds16(pa0, &As[0][lbase]);
    glds16(pa1, &As[0][2048 + lbase]);
    glds16(pb0, &Bs[0][lbase]);
    glds16(pb1, &Bs[0][2048 + lbase]);

    int cur = 0;
    for (int k0 = 0;; k0 += 32) {
        __syncthreads();
        const int kn = k0 + 32;
        if (kn < K) {
            glds16(pa0 + kn, &As[cur ^ 1][lbase]);
            glds16(pa1 + kn, &As[cur ^ 1][2048 + lbase]);
            glds16(pb0 + kn, &Bs[cur ^ 1][lbase]);
            glds16(pb1 + kn, &Bs[cur ^ 1][2048 + lbase]);
        }
        bf16x8 af[4], bfr[4];
#pragma unroll
        for (int s = 0; s < 4; ++s) af[s] = *(const bf16x8*)&As[cur][ldso(wr * 64 + s * 16 + lm, q)];
#pragma unroll
        for (int t = 0; t < 4; ++t) bfr[t] = *(const bf16x8*)&Bs[cur][ldso(wc * 64 + t * 16 + lm, q)];
#pragma unroll
        for (int s = 0; s < 4; ++s)
#pragma unroll
            for (int t = 0; t < 4; ++t)
                acc[s][t] = __builtin_amdgcn_mfma_f32_16x16x32_bf16(af[s], bfr[t], acc[s][t], 0, 0, 0);
        if (kn >= K) break;
        cur ^= 1;
    }
#pragma unroll
    for (int s = 0; s < 4; ++s)
#pragma unroll
        for (int t = 0; t < 4; ++t)
#pragma unroll
            for (int rg = 0; rg < 4; ++rg) {
                int rl = wr * 64 + s * 16 + q * 4 + rg;
                if (rl < rows) {
                    int gc = n0 + wc * 64 + t * 16 + lm;
                    int tok = toks[rl];
                    out[(size_t)tok * E + gc] = scale[tok] * (acc[s][t][rg] + bias[gc]);
                }
            }
}

// ---------------- cheap experts (2..5): batched 8-token tiles ---------------
// Grid 2048, zero-LDS (sub-1KB). Slot s in [0,4096): e = 2+(s&3), ti = s>>2.
// Tokens come expert-sorted from tlist -> no eid read, no divergence within a
// block. FiLM is j-outer with 8 tokens' gamma/beta register accumulators so
// fl_uw (131KB) is read once per TILE, not per token (8x traffic cut).
__global__ __launch_bounds__(256)
void cheap_kernel(const int* __restrict__ counts, const int* __restrict__ tlist,
                  const float* __restrict__ scale, const float* __restrict__ x,
                  const float* __restrict__ gvec,
                  const float* __restrict__ p2_v, const float* __restrict__ p2_bias,
                  const float* __restrict__ p4_v, const float* __restrict__ p4_bias,
                  const float* __restrict__ rg_a, const float* __restrict__ rg_bias,
                  const float* __restrict__ fl_uw, const float* __restrict__ fl_ub,
                  float* __restrict__ out) {
    __shared__ int stoks[8];
    __shared__ float ssc[8];
    __shared__ float sgv[8][17];
    const int tid = threadIdx.x;
    const int k4 = tid * 4;
    for (int s = blockIdx.x; s < 4096; s += 2048) {
        const int e = 2 + (s & 3);
        const int ti = s >> 2;
        const int cnt = counts[e];
        const int i0 = ti * 8;
        if (i0 >= cnt) continue;
        const int nt = min(8, cnt - i0);
        __syncthreads();                       // LDS reuse guard across strides
        if (tid < 128) {
            const int tt = tid >> 4, sl = tid & 15;
            const int tk = tlist[e * NTOK + min(i0 + tt, cnt - 1)];
            if (sl == 0) { stoks[tt] = tk; ssc[tt] = scale[tk]; }
            const int base = (e == 2) ? 0 : (e == 3) ? 2 : (e == 4) ? 6 : 7;
            const int ng   = (e == 2) ? 2 : (e == 3) ? 4 : (e == 4) ? 1 : 16;
            if (sl < ng) sgv[tt][sl] = gvec[(size_t)tk * NCH + base + sl];
        }
        __syncthreads();
        if (e == 2) {
            const float4 b0 = *reinterpret_cast<const float4*>(&p2_bias[k4]);
            const float4 v0 = *reinterpret_cast<const float4*>(&p2_v[k4]);
            const float4 v1 = *reinterpret_cast<const float4*>(&p2_v[E + k4]);
#pragma unroll
            for (int tt = 0; tt < 8; ++tt) {
                if (tt < nt) {
                    const float g0 = sgv[tt][0], g1 = sgv[tt][1], sc = ssc[tt];
                    float4 o;
                    o.x = (b0.x + g0 * v0.x + g1 * v1.x) * sc;
                    o.y = (b0.y + g0 * v0.y + g1 * v1.y) * sc;
                    o.z = (b0.z + g0 * v0.z + g1 * v1.z) * sc;
                    o.w = (b0.w + g0 * v0.w + g1 * v1.w) * sc;
                    *reinterpret_cast<float4*>(&out[(size_t)stoks[tt] * E + k4]) = o;
                }
            }
        } else if (e == 3) {
            const float4 b0 = *reinterpret_cast<const float4*>(&p4_bias[k4]);
            float4 vv[4];
#pragma unroll
            for (int j = 0; j < 4; ++j)
                vv[j] = *reinterpret_cast<const float4*>(&p4_v[j * E + k4]);
#pragma unroll
            for (int tt = 0; tt < 8; ++tt) {
                if (tt < nt) {
                    float4 o = b0;
#pragma unroll
                    for (int j = 0; j < 4; ++j) {
                        const float gj = sgv[tt][j];
                        o.x += gj * vv[j].x; o.y += gj * vv[j].y;
                        o.z += gj * vv[j].z; o.w += gj * vv[j].w;
                    }
                    const float sc = ssc[tt];
                    o.x *= sc; o.y *= sc; o.z *= sc; o.w *= sc;
                    *reinterpret_cast<float4*>(&out[(size_t)stoks[tt] * E + k4]) = o;
                }
            }
        } else if (e == 4) {
            const float4 av = *reinterpret_cast<const float4*>(&rg_a[k4]);
            const float4 bv = *reinterpret_cast<const float4*>(&rg_bias[k4]);
#pragma unroll
            for (int tt = 0; tt < 8; ++tt) {
                if (tt < nt) {
                    const float sg = sgv[tt][0], sc = ssc[tt];
                    const float4 xv = *reinterpret_cast<const float4*>(&x[(size_t)stoks[tt] * E + k4]);
                    float4 o;
                    o.x = (sg * xv.x * av.x + bv.x) * sc;
                    o.y = (sg * xv.y * av.y + bv.y) * sc;
                    o.z = (sg * xv.z * av.z + bv.z) * sc;
                    o.w = (sg * xv.w * av.w + bv.w) * sc;
                    *reinterpret_cast<float4*>(&out[(size_t)stoks[tt] * E + k4]) = o;
                }
            }
        } else {  // FiLM: j-outer, 8-token register accumulators
            float4 ga[8], be[8];
            const float4 g0 = *reinterpret_cast<const float4*>(&fl_ub[k4]);
            const float4 b0 = *reinterpret_cast<const float4*>(&fl_ub[E + k4]);
#pragma unroll
            for (int tt = 0; tt < 8; ++tt) { ga[tt] = g0; be[tt] = b0; }
#pragma unroll
            for (int j = 0; j < 16; ++j) {
                const float4 ug = *reinterpret_cast<const float4*>(&fl_uw[(size_t)j * 2 * E + k4]);
                const float4 ub = *reinterpret_cast<const float4*>(&fl_uw[(size_t)j * 2 * E + E + k4]);
#pragma unroll
                for (int tt = 0; tt < 8; ++tt) {
                    const float tj = sgv[tt][j];
                    ga[tt].x += tj * ug.x; ga[tt].y += tj * ug.y;
                    ga[tt].z += tj * ug.z; ga[tt].w += tj * ug.w;
                    be[tt].x += tj * ub.x; be[tt].y += tj * ub.y;
                    be[tt].z += tj * ub.z; be[tt].w += tj * ub.w;
                }
            }
#pragma unroll
            for (int tt = 0; tt < 8; ++tt) {
                if (tt < nt) {
                    const float sc = ssc[tt];
                    const float4 xv = *reinterpret_cast<const float4*>(&x[(size_t)stoks[tt] * E + k4]);
                    float4 o;
                    o.x = (ga[tt].x * xv.x + be[tt].x) * sc;
                    o.y = (ga[tt].y * xv.y + be[tt].y) * sc;
                    o.z = (ga[tt].z * xv.z + be[tt].z) * sc;
                    o.w = (ga[tt].w * xv.w + be[tt].w) * sc;
                    *reinterpret_cast<float4*>(&out[(size_t)stoks[tt] * E + k4]) = o;
                }
            }
        }
    }
}

extern "C" void kernel_launch(void* const* d_in, const int* in_sizes, int n_in,
                              void* d_out, int out_size, void* d_ws, size_t ws_size,
                              hipStream_t stream) {
    const float* x        = (const float*)d_in[0];
    const float* gw1      = (const float*)d_in[1];
    const float* gb1      = (const float*)d_in[2];
    const float* gw2      = (const float*)d_in[3];
    const float* gb2      = (const float*)d_in[4];
    const float* ebias    = (const float*)d_in[5];
    const float* pm_alpha = (const float*)d_in[6];
    const float* dfc_w    = (const float*)d_in[7];
    const float* dfc_b    = (const float*)d_in[8];
    const float* dproj_w  = (const float*)d_in[9];
    const float* dproj_b  = (const float*)d_in[10];
    const float* sfc_w    = (const float*)d_in[11];
    const float* sfc_b    = (const float*)d_in[12];
    const float* sproj_w  = (const float*)d_in[13];
    const float* sproj_b  = (const float*)d_in[14];
    const float* p2_w     = (const float*)d_in[15];
    const float* p2_v     = (const float*)d_in[16];
    const float* p2_alpha = (const float*)d_in[17];
    const float* p2_b     = (const float*)d_in[18];
    const float* p2_bias  = (const float*)d_in[19];
    const float* p4_w     = (const float*)d_in[20];
    const float* p4_v     = (const float*)d_in[21];
    const float* p4_alpha = (const float*)d_in[22];
    const float* p4_b     = (const float*)d_in[23];
    const float* p4_bias  = (const float*)d_in[24];
    const float* rg_u     = (const float*)d_in[25];
    const float* rg_a     = (const float*)d_in[26];
    const float* rg_b     = (const float*)d_in[27];
    const float* rg_bias  = (const float*)d_in[28];
    const float* fl_dw    = (const float*)d_in[29];
    const float* fl_db    = (const float*)d_in[30];
    const float* fl_uw    = (const float*)d_in[31];
    const float* fl_ub    = (const float*)d_in[32];
    float* out = (float*)d_out;

    char* ws = (char*)d_ws;
    size_t off = 0;
    int*            counts = (int*)(ws + off);            off += 256;
    float*          scale  = (float*)(ws + off);          off += (size_t)NTOK * 4;
    int*            tlist  = (int*)(ws + off);            off += (size_t)NEXP * NTOK * 4;
    int*            eid    = (int*)(ws + off);            off += (size_t)NTOK * 4;
    float*          gvec   = (float*)(ws + off);          off += (size_t)NTOK * NCH * 4;
    float*          cdot   = (float*)(ws + off);          off += (size_t)4 * NTOK * NCH * 4;
    unsigned short* w1cheap= (unsigned short*)(ws + off); off += (size_t)64 * 2048 * 2;
    unsigned short* w1cat  = (unsigned short*)(ws + off); off += (size_t)GH * 2048 * 2;
    unsigned short* dfc_wt = (unsigned short*)(ws + off); off += (size_t)2048 * 1024 * 2;
    unsigned short* dpj_wt = (unsigned short*)(ws + off); off += (size_t)1024 * 2048 * 2;
    unsigned short* sfc_wt = (unsigned short*)(ws + off); off += (size_t)1024 * 1024 * 2;
    unsigned short* spj_wt = (unsigned short*)(ws + off); off += (size_t)1024 * 1024 * 2;
    unsigned short* x_hi   = (unsigned short*)(ws + off); off += (size_t)NTOK * E * 2;
    // Union region: gate phase {x_lo} then expert phase {h1, h2}
    char* U = ws + off;
    unsigned short* x_lo = (unsigned short*)U;                              // 16 MB
    unsigned short* h1   = (unsigned short*)U;                              // 16 MB (2048 x 2048)
    unsigned short* h2   = (unsigned short*)(U + (size_t)16 * 1024 * 1024); // 8 MB (2048 x 1024)
    // 4 hp partials (4 x 8 MB = 32 MB) live in d_out (dead after finalize,
    // before gemm2/cheap rewrite every token row).
    float* hp = out;

    hipMemsetAsync(counts, 0, 256, stream);
    prep_kernel<<<8512, 256, 0, stream>>>(x, x_hi, x_lo, gw1, w1cat,
                                          p2_w, p4_w, rg_u, fl_dw, w1cheap,
                                          dfc_w, dfc_wt, dproj_w, dpj_wt,
                                          sfc_w, sfc_wt, sproj_w, spj_wt);
    gate_partial_kernel<<<512, 256, 0, stream>>>(
        x_hi, x_lo, w1cat, w1cheap, hp, cdot);
    gate_finalize_kernel<<<NTOK / 32, 256, 0, stream>>>(
        hp, gb1, gw2, gb2, ebias, pm_alpha, cdot,
        p2_alpha, p2_b, p4_alpha, p4_b, rg_b, fl_db,
        scale, counts, tlist, eid, gvec);
    // y: 16 x 128-row tiles = 2048 rows per expert (mean+20sigma of counts)
    moe_gemm1_kernel<<<384, 256, 0, stream>>>(
        x_hi, dfc_wt, sfc_wt, dfc_b, sfc_b, counts, tlist, h1, h2);
    moe_gemm2_kernel<<<256, 256, 0, stream>>>(
        h1, h2, dpj_wt, spj_wt, dproj_b, sproj_b, counts, tlist, scale, out);
    cheap_kernel<<<2048, 256, 0, stream>>>(
        counts, tlist, scale, x, gvec,
        p2_v, p2_bias, p4_v, p4_bias,
        rg_a, rg_bias, fl_uw, fl_ub, out);
    (void)in_sizes; (void)n_in; (void)out_size; (void)ws_size;
}

// Round 5
// 294.026 us; speedup vs baseline: 1.1233x; 1.1233x over previous
//
#include <hip/hip_runtime.h>
#include <math.h>

// Top-1 MoE, 6-dispatch pipeline.
//   memset -> prep -> gate_partial -> gate_finalize -> gemm1 -> gemm2+cheap.
// r13: cheap-expert dots ride gate_partial's MFMA (gvec); cheap blocks stream.
// r14: XCD-chunked swizzle on all MFMA GEMMs (FETCH 132->59MB).
// r15: gate_partial -> 128x128 tiles + global_load_lds dbuf (gate 60->~40us).
// r16: batched 8-token cheap tiles (fl_uw traffic 8x cut).
// r17: fix r15/r16's latency-bound expert GEMMs. 128² tiles starved the grid
// (gemm2: 176 active blocks = 1/CU, Occ 3.6%, Mfma 3.7%, 50us). gemm1/gemm2
// back to 64² tiles (1056/704 active blocks = 3-4/CU, r14-proven) but with
// glds16 staging; gemm2 re-fused with batched cheap (16.6KB LDS -> 9 blk/CU)
// so cheap blocks co-schedule into gemm2's load-latency stalls.

#define E 1024
#define GH 256
#define NEXP 6
#define NTOK 8192
#define NCH 24   // cheap-dot cols: 2 p2 + 4 p4 + 1 rg + 16 film + 1 pad

typedef __attribute__((ext_vector_type(8))) short bf16x8;
typedef __attribute__((ext_vector_type(4))) float f32x4;

__device__ __forceinline__ float gelu_erf(float v) {
    return 0.5f * v * (1.0f + erff(v * 0.70710678118654752440f));
}

__device__ __forceinline__ unsigned short f2bf(float f) {
    union { float f; unsigned u; } c; c.f = f;
    unsigned u = c.u;
    u += 0x7fffu + ((u >> 16) & 1u);   // RNE
    return (unsigned short)(u >> 16);
}

__device__ __forceinline__ float bf2f(unsigned short h) {
    union { unsigned u; float f; } c; c.u = ((unsigned)h) << 16;
    return c.f;
}

// LDS tile addressing (ushort units): row stride 32 (=64B), k-group XOR swizzle.
__device__ __forceinline__ int ldso(int row, int q) {
    return row * 32 + ((q ^ ((row >> 1) & 3)) << 3);
}

// async global->LDS, 16B per lane; lds dest is wave-uniform base + lane*16.
__device__ __forceinline__ void glds16(const void* g, void* l) {
    __builtin_amdgcn_global_load_lds(
        (const __attribute__((address_space(1))) void*)g,
        (__attribute__((address_space(3))) void*)l, 16, 0, 0);
}

// ---------------- prep: convert + all transposes, one kernel ----------------
__global__ __launch_bounds__(256)
void prep_kernel(const float* __restrict__ x, unsigned short* __restrict__ xh,
                 unsigned short* __restrict__ xl,
                 const float* __restrict__ gw1, unsigned short* __restrict__ w1cat,
                 const float* __restrict__ p2_w, const float* __restrict__ p4_w,
                 const float* __restrict__ rg_u, const float* __restrict__ fl_dw,
                 unsigned short* __restrict__ w1cheap,
                 const float* __restrict__ dfc_w, unsigned short* __restrict__ dfc_wt,
                 const float* __restrict__ dproj_w, unsigned short* __restrict__ dpj_wt,
                 const float* __restrict__ sfc_w, unsigned short* __restrict__ sfc_wt,
                 const float* __restrict__ sproj_w, unsigned short* __restrict__ spj_wt) {
    __shared__ float tile[32][33];
    const int tid = threadIdx.x;
    const int tx = tid & 31, ty = tid >> 5;
    int b = blockIdx.x;
    if (b < 2048) {                       // x -> x_hi + x_lo
        const int n4 = NTOK * E / 4;
        for (int i = b * 256 + tid; i < n4; i += 2048 * 256) {
            float4 v = reinterpret_cast<const float4*>(x)[i];
            ushort4 h, l;
            h.x = f2bf(v.x); l.x = f2bf(v.x - bf2f(h.x));
            h.y = f2bf(v.y); l.y = f2bf(v.y - bf2f(h.y));
            h.z = f2bf(v.z); l.z = f2bf(v.z - bf2f(h.z));
            h.w = f2bf(v.w); l.w = f2bf(v.w - bf2f(h.w));
            reinterpret_cast<ushort4*>(xh)[i] = h;
            reinterpret_cast<ushort4*>(xl)[i] = l;
        }
        return;
    }
    b -= 2048;
    if (b < 256) {                        // gw1 [E][GH] -> w1cat [GH][hi|lo]
        const int c0 = (b & 7) * 32, r0 = (b >> 3) * 32;
#pragma unroll
        for (int i = 0; i < 4; ++i)
            tile[ty + i * 8][tx] = gw1[(size_t)(r0 + ty + i * 8) * GH + c0 + tx];
        __syncthreads();
#pragma unroll
        for (int i = 0; i < 4; ++i) {
            float v = tile[tx][ty + i * 8];
            unsigned short h = f2bf(v);
            size_t row = (size_t)(c0 + ty + i * 8) * 2048;
            w1cat[row + r0 + tx] = h;
            w1cat[row + 1024 + r0 + tx] = f2bf(v - bf2f(h));
        }
        return;
    }
    b -= 256;
    if (b < 64) {                         // cheap-dot weights -> w1cheap [64][hi|lo]
        const int r = b;
        const int k4 = tid * 4;
        float4 v = {0.f, 0.f, 0.f, 0.f};
        if (r < 2)       v = *reinterpret_cast<const float4*>(&p2_w[r * E + k4]);
        else if (r < 6)  v = *reinterpret_cast<const float4*>(&p4_w[(r - 2) * E + k4]);
        else if (r == 6) v = *reinterpret_cast<const float4*>(&rg_u[k4]);
        else if (r < 23) {
            const int j = r - 7;          // fl_dw is [E][16]: gather column j
            v.x = fl_dw[(k4 + 0) * 16 + j];
            v.y = fl_dw[(k4 + 1) * 16 + j];
            v.z = fl_dw[(k4 + 2) * 16 + j];
            v.w = fl_dw[(k4 + 3) * 16 + j];
        }
        ushort4 h, l;
        h.x = f2bf(v.x); l.x = f2bf(v.x - bf2f(h.x));
        h.y = f2bf(v.y); l.y = f2bf(v.y - bf2f(h.y));
        h.z = f2bf(v.z); l.z = f2bf(v.z - bf2f(h.z));
        h.w = f2bf(v.w); l.w = f2bf(v.w - bf2f(h.w));
        *reinterpret_cast<ushort4*>(&w1cheap[r * 2048 + k4]) = h;
        *reinterpret_cast<ushort4*>(&w1cheap[r * 2048 + 1024 + k4]) = l;
        return;
    }
    b -= 64;
    const float* src; unsigned short* dst; int R, C, nbx;
    if (b < 2048)      { src = dfc_w;   dst = dfc_wt; R = 1024; C = 2048; nbx = 64; }
    else if (b < 4096) { src = dproj_w; dst = dpj_wt; R = 2048; C = 1024; nbx = 32; b -= 2048; }
    else if (b < 5120) { src = sfc_w;   dst = sfc_wt; R = 1024; C = 1024; nbx = 32; b -= 4096; }
    else               { src = sproj_w; dst = spj_wt; R = 1024; C = 1024; nbx = 32; b -= 5120; }
    const int c0 = (b % nbx) * 32, r0 = (b / nbx) * 32;
#pragma unroll
    for (int i = 0; i < 4; ++i)
        tile[ty + i * 8][tx] = src[(size_t)(r0 + ty + i * 8) * C + c0 + tx];
    __syncthreads();
#pragma unroll
    for (int i = 0; i < 4; ++i)
        dst[(size_t)(c0 + ty + i * 8) * R + r0 + tx] = f2bf(tile[tx][ty + i * 8]);
}

// ------ gate partial GEMM: hp[c2] = A_z @ w1cat[:, h-half], 128x128 tiles ---
// Grid 512. xcd=bid&7, slot=bid>>3; nx=slot&1; strip=xcd*32+(slot>>1);
// m=strip>>2, c2=strip&3 (z=c2&1, h=c2>>1). 4 waves of 64x64, glds dbuf.
// Cheap dots: every wave adds 2 MFMAs (cols nx*16..+15, rows wr*64+wc*32..+31).
__global__ __launch_bounds__(256)
void gate_partial_kernel(const unsigned short* __restrict__ xh,
                         const unsigned short* __restrict__ xl,
                         const unsigned short* __restrict__ w1cat,
                         const unsigned short* __restrict__ w1cheap,
                         float* __restrict__ hp,      // [4][NTOK][GH]
                         float* __restrict__ cdot) {  // [4][NTOK][NCH]
    __shared__ __align__(16) unsigned short As[2][128 * 32];
    __shared__ __align__(16) unsigned short Bs[2][128 * 32];
    const int tid = threadIdx.x;
    const int bid = blockIdx.x;
    const int xcd = bid & 7, slot = bid >> 3;
    const int nx = slot & 1;
    const int strip = xcd * 32 + (slot >> 1);      // [0,256)
    const int m = strip >> 2, c2 = strip & 3;
    const int z = c2 & 1, h = c2 >> 1;
    const int t0 = m * 128, n0 = nx * 128;
    const unsigned short* A = z ? xl : xh;
    float* hpz = hp + (size_t)c2 * ((size_t)NTOK * GH);
    float* cd  = cdot + (size_t)c2 * ((size_t)NTOK * NCH);

    const int lane = tid & 63, wv = tid >> 6;
    const int wr = wv >> 1, wc = wv & 1;
    const int lm = lane & 15, q = lane >> 4;
    const int r0 = tid >> 2, gsl = tid & 3;
    const int g = gsl ^ ((r0 >> 1) & 3);
    const int lbase = wv * 512;

    const unsigned short* pa0 = A + (size_t)(t0 + r0) * E + g * 8;
    const unsigned short* pa1 = A + (size_t)(t0 + 64 + r0) * E + g * 8;
    const unsigned short* pb0 = w1cat + (size_t)(n0 + r0) * 2048 + h * 1024 + g * 8;
    const unsigned short* pb1 = w1cat + (size_t)(n0 + 64 + r0) * 2048 + h * 1024 + g * 8;
    const unsigned short* pcw = w1cheap + (size_t)(nx * 16 + lm) * 2048 + h * 1024 + q * 8;

    f32x4 acc[4][4];
#pragma unroll
    for (int s = 0; s < 4; ++s)
#pragma unroll
        for (int t = 0; t < 4; ++t) acc[s][t] = (f32x4){0.f, 0.f, 0.f, 0.f};
    f32x4 accC[2];
    accC[0] = (f32x4){0.f, 0.f, 0.f, 0.f};
    accC[1] = (f32x4){0.f, 0.f, 0.f, 0.f};

    glds16(pa0, &As[0][lbase]);
    glds16(pa1, &As[0][2048 + lbase]);
    glds16(pb0, &Bs[0][lbase]);
    glds16(pb1, &Bs[0][2048 + lbase]);
    bf16x8 cfv = *(const bf16x8*)pcw;

    int cur = 0;
    for (int k0 = 0;; k0 += 32) {
        __syncthreads();                  // drains vmcnt -> buf[cur] landed
        const int kn = k0 + 32;
        bf16x8 cfn;
        if (kn < 1024) {
            glds16(pa0 + kn, &As[cur ^ 1][lbase]);
            glds16(pa1 + kn, &As[cur ^ 1][2048 + lbase]);
            glds16(pb0 + kn, &Bs[cur ^ 1][lbase]);
            glds16(pb1 + kn, &Bs[cur ^ 1][2048 + lbase]);
            cfn = *(const bf16x8*)(pcw + kn);
        }
        bf16x8 af[4], bfr[4];
#pragma unroll
        for (int s = 0; s < 4; ++s) af[s] = *(const bf16x8*)&As[cur][ldso(wr * 64 + s * 16 + lm, q)];
#pragma unroll
        for (int t = 0; t < 4; ++t) bfr[t] = *(const bf16x8*)&Bs[cur][ldso(wc * 64 + t * 16 + lm, q)];
#pragma unroll
        for (int s = 0; s < 4; ++s)
#pragma unroll
            for (int t = 0; t < 4; ++t)
                acc[s][t] = __builtin_amdgcn_mfma_f32_16x16x32_bf16(af[s], bfr[t], acc[s][t], 0, 0, 0);
        {
            bf16x8 ac0 = wc ? af[2] : af[0];
            bf16x8 ac1 = wc ? af[3] : af[1];
            accC[0] = __builtin_amdgcn_mfma_f32_16x16x32_bf16(ac0, cfv, accC[0], 0, 0, 0);
            accC[1] = __builtin_amdgcn_mfma_f32_16x16x32_bf16(ac1, cfv, accC[1], 0, 0, 0);
        }
        if (kn >= 1024) break;
        cfv = cfn; cur ^= 1;
    }
#pragma unroll
    for (int s = 0; s < 4; ++s)
#pragma unroll
        for (int t = 0; t < 4; ++t)
#pragma unroll
            for (int rg = 0; rg < 4; ++rg) {
                int rl = wr * 64 + s * 16 + q * 4 + rg;
                int c  = wc * 64 + t * 16 + lm;
                hpz[(size_t)(t0 + rl) * GH + n0 + c] = acc[s][t][rg];
            }
    const int cc = nx * 16 + lm;
    if (cc < NCH) {
#pragma unroll
        for (int i = 0; i < 2; ++i)
#pragma unroll
            for (int rg = 0; rg < 4; ++rg) {
                int rl = wr * 64 + wc * 32 + i * 16 + q * 4 + rg;
                cd[(size_t)(t0 + rl) * NCH + cc] = accC[i][rg];
            }
    }
}

// ------- finalize: h=gelu(sum4 hp+gb1); logits=h@gw2; softmax/argmax --------
// Also converts summed cheap dots (4 partials) into gate scalars gvec[NCH].
__global__ __launch_bounds__(256)
void gate_finalize_kernel(const float* __restrict__ hp,    // [4][NTOK][GH]
                          const float* __restrict__ gb1, const float* __restrict__ gw2,
                          const float* __restrict__ gb2, const float* __restrict__ ebias,
                          const float* __restrict__ pm_alpha,
                          const float* __restrict__ cdot,  // [4][NTOK][NCH]
                          const float* __restrict__ p2_alpha, const float* __restrict__ p2_b,
                          const float* __restrict__ p4_alpha, const float* __restrict__ p4_b,
                          const float* __restrict__ rg_b, const float* __restrict__ fl_db,
                          float* __restrict__ scale, int* __restrict__ counts,
                          int* __restrict__ tlist, int* __restrict__ eid,
                          float* __restrict__ gvec) {
    __shared__ float hs[32][264];
    __shared__ float g2s[GH * NEXP];
    __shared__ int tokexp[32];
    const int tid = threadIdx.x;
    const int t0 = blockIdx.x * 32;
    const size_t HPS = (size_t)NTOK * GH;
    for (int i = tid; i < GH * NEXP; i += 256) g2s[i] = gw2[i];
#pragma unroll
    for (int i = 0; i < 8; ++i) {
        int f4 = i * 256 + tid;
        int row = f4 >> 6, c4 = (f4 & 63) * 4;
        size_t base = (size_t)(t0 + row) * GH + c4;
        float4 a = *reinterpret_cast<const float4*>(&hp[base]);
        float4 b = *reinterpret_cast<const float4*>(&hp[HPS + base]);
        float4 c = *reinterpret_cast<const float4*>(&hp[2 * HPS + base]);
        float4 d = *reinterpret_cast<const float4*>(&hp[3 * HPS + base]);
        float4 o;
        o.x = gelu_erf(a.x + b.x + c.x + d.x + gb1[c4 + 0]);
        o.y = gelu_erf(a.y + b.y + c.y + d.y + gb1[c4 + 1]);
        o.z = gelu_erf(a.z + b.z + c.z + d.z + gb1[c4 + 2]);
        o.w = gelu_erf(a.w + b.w + c.w + d.w + gb1[c4 + 3]);
        *reinterpret_cast<float4*>(&hs[row][c4]) = o;
    }
    __syncthreads();
    const int t = tid >> 3, j = tid & 7;
    float p[NEXP] = {0.f, 0.f, 0.f, 0.f, 0.f, 0.f};
#pragma unroll 8
    for (int kk = 0; kk < 32; ++kk) {
        int k = j + kk * 8;
        float hv = hs[t][k];
        const float* gr = &g2s[k * NEXP];
#pragma unroll
        for (int m = 0; m < NEXP; ++m) p[m] += hv * gr[m];
    }
#pragma unroll
    for (int m = 0; m < NEXP; ++m) {
        p[m] += __shfl_xor(p[m], 4, 64);
        p[m] += __shfl_xor(p[m], 2, 64);
        p[m] += __shfl_xor(p[m], 1, 64);
    }
    if (j == 0) {
        float L[NEXP];
#pragma unroll
        for (int m = 0; m < NEXP; ++m) L[m] = p[m] + gb2[m] + ebias[m];
        float mx = L[0]; int am = 0;
#pragma unroll
        for (int m = 1; m < NEXP; ++m) { if (L[m] > mx) { mx = L[m]; am = m; } }
        float S = 0.f;
#pragma unroll
        for (int m = 0; m < NEXP; ++m) S += expf(L[m] - mx);
        float pt = 1.f / S;
        scale[t0 + t] = pm_alpha[0] * (pt / (pt + 1e-9f));
        eid[t0 + t] = am;
        tokexp[t] = am;
    }
    __syncthreads();
    if (tid < NEXP) {
        const int e = tid;
        int cnt = 0;
#pragma unroll
        for (int i = 0; i < 32; ++i) cnt += (tokexp[i] == e);
        if (cnt) {
            int base = atomicAdd(&counts[e], cnt);
            int pos = 0;
#pragma unroll
            for (int i = 0; i < 32; ++i)
                if (tokexp[i] == e) tlist[e * NTOK + base + (pos++)] = t0 + i;
        }
    }
    // ---- per-token cheap-gate scalars (independent of the above) ----
    const size_t CDS = (size_t)NTOK * NCH;
    for (int i = tid; i < 32 * NCH; i += 256) {
        const int tt = i / NCH, slot = i - tt * NCH;
        const int tok = t0 + tt;
        size_t idx = (size_t)tok * NCH + slot;
        float s = cdot[idx] + cdot[CDS + idx] + cdot[2 * CDS + idx] + cdot[3 * CDS + idx];
        float val;
        if (slot < 2)       val = p2_alpha[slot] * gelu_erf(s + p2_b[slot]);
        else if (slot < 6)  val = p4_alpha[slot - 2] * gelu_erf(s + p4_b[slot - 2]);
        else if (slot == 6) val = 1.f / (1.f + expf(-(s + rg_b[0])));
        else if (slot < 23) val = gelu_erf(s + fl_db[slot - 7]);
        else                val = 0.f;
        gvec[(size_t)tok * NCH + slot] = val;
    }
}

// ---------------- GEMM1: gather x_hi -> gelu -> packed bf16 h ---------------
// Grid 2048 (r14 decode). xcd=bid&7, slot=bid>>3 in [0,256): nx=slot&31,
// strip = xcd + 8*(slot>>5) in [0,64), z=strip&1, i0=(strip>>1)*64.
// 64x64 tiles, 4 waves of 32x32, glds16 double-buffer.
__global__ __launch_bounds__(256)
void moe_gemm1_kernel(const unsigned short* __restrict__ xh,
                      const unsigned short* __restrict__ B0, const unsigned short* __restrict__ B1,
                      const float* __restrict__ bias0, const float* __restrict__ bias1,
                      const int* __restrict__ counts, const int* __restrict__ tlist,
                      unsigned short* __restrict__ H0, unsigned short* __restrict__ H1) {
    __shared__ __align__(16) unsigned short As[2][64 * 32];
    __shared__ __align__(16) unsigned short Bs[2][64 * 32];
    __shared__ int toks[64];
    const int tid = threadIdx.x;
    const int bid = blockIdx.x;
    const int xcd = bid & 7, slot = bid >> 3;      // [0,256)
    const int nx = slot & 31;
    const int strip = xcd + 8 * (slot >> 5);       // [0,64), XCD-strided
    const int z = strip & 1;
    const int N = z ? 1024 : 2048;
    const int cnt = counts[z];
    const int i0 = (strip >> 1) * 64;
    const int n0 = nx * 64;
    if (i0 >= cnt || n0 >= N) return;
    const unsigned short* Bz = z ? B1 : B0;
    const float* bias = z ? bias1 : bias0;

    if (tid < 64) toks[tid] = tlist[z * NTOK + min(i0 + tid, cnt - 1)];
    __syncthreads();

    const int lane = tid & 63, wv = tid >> 6;
    const int wm = (wv & 1) * 32, wn = (wv >> 1) * 32;
    const int lm = lane & 15, q = lane >> 4;
    const int r0 = tid >> 2, gsl = tid & 3;
    const int g = gsl ^ ((r0 >> 1) & 3);
    const int lbase = wv * 512;

    const unsigned short* pa = xh + (size_t)toks[r0] * E + g * 8;
    const unsigned short* pb = Bz + (size_t)(n0 + r0) * E + g * 8;

    f32x4 acc[2][2];
#pragma unroll
    for (int s = 0; s < 2; ++s)
#pragma unroll
        for (int t = 0; t < 2; ++t) acc[s][t] = (f32x4){0.f, 0.f, 0.f, 0.f};

    glds16(pa, &As[0][lbase]);
    glds16(pb, &Bs[0][lbase]);

    int cur = 0;
    for (int k0 = 0;; k0 += 32) {
        __syncthreads();
        const int kn = k0 + 32;
        if (kn < E) {
            glds16(pa + kn, &As[cur ^ 1][lbase]);
            glds16(pb + kn, &Bs[cur ^ 1][lbase]);
        }
        bf16x8 af[2], bfr[2];
#pragma unroll
        for (int s = 0; s < 2; ++s) af[s] = *(const bf16x8*)&As[cur][ldso(wm + s * 16 + lm, q)];
#pragma unroll
        for (int t = 0; t < 2; ++t) bfr[t] = *(const bf16x8*)&Bs[cur][ldso(wn + t * 16 + lm, q)];
#pragma unroll
        for (int s = 0; s < 2; ++s)
#pragma unroll
            for (int t = 0; t < 2; ++t)
                acc[s][t] = __builtin_amdgcn_mfma_f32_16x16x32_bf16(af[s], bfr[t], acc[s][t], 0, 0, 0);
        if (kn >= E) break;
        cur ^= 1;
    }
    unsigned short* Hz = z ? H1 : H0;
#pragma unroll
    for (int s = 0; s < 2; ++s)
#pragma unroll
        for (int t = 0; t < 2; ++t)
#pragma unroll
            for (int rg = 0; rg < 4; ++rg) {
                int rl = wm + s * 16 + q * 4 + rg;
                int gc = n0 + wn + t * 16 + lm;
                float v = acc[s][t][rg] + bias[gc];
                Hz[(size_t)(i0 + rl) * N + gc] = f2bf(gelu_erf(v));
            }
}

// -------- fused GEMM2 (experts 0/1 down-proj) + cheap experts (2..5) --------
// blocks [0,1024): gemm2 64x64 tile, glds16 dbuf. xcd=bb&7, slot=bb>>3 in
// [0,128): nx=slot&15, strip=xcd+8*(slot>>4) in [0,64), z=strip&1,
// i0=(strip>>1)*64. ~704 active blocks; cheap blocks fill the latency gaps.
// blocks [1024, 3072): batched cheap tiles (grid-stride over 4096 slots):
// e=2+(s&3), 8 expert-sorted tokens; FiLM j-outer, fl_uw once per tile.
__global__ __launch_bounds__(256)
void gemm2_cheap_kernel(const unsigned short* __restrict__ h1, const unsigned short* __restrict__ h2,
                        const unsigned short* __restrict__ dpj, const unsigned short* __restrict__ spj,
                        const float* __restrict__ dproj_b, const float* __restrict__ sproj_b,
                        const int* __restrict__ counts, const int* __restrict__ tlist,
                        const float* __restrict__ scale,
                        const float* __restrict__ x, const float* __restrict__ gvec,
                        const float* __restrict__ p2_v, const float* __restrict__ p2_bias,
                        const float* __restrict__ p4_v, const float* __restrict__ p4_bias,
                        const float* __restrict__ rg_a, const float* __restrict__ rg_bias,
                        const float* __restrict__ fl_uw, const float* __restrict__ fl_ub,
                        float* __restrict__ out) {
    __shared__ __align__(16) char smem[2 * 64 * 32 * 2 * 2 + 64 * 4];  // 16.6 KB
    const int tid = threadIdx.x;
    const int bb = blockIdx.x;
    const int lane = tid & 63;

    if (bb < 1024) {
        const int xcd = bb & 7, slot = bb >> 3;    // [0,128)
        const int nx = slot & 15;
        const int strip = xcd + 8 * (slot >> 4);   // [0,64)
        const int z = strip & 1;
        const int i0 = (strip >> 1) * 64;
        const int n0 = nx * 64;
        const int K = z ? 1024 : 2048;
        const int cnt = counts[z];
        if (i0 >= cnt) return;
        const int rows = min(64, cnt - i0);
        const unsigned short* Az = z ? h2 : h1;
        const unsigned short* Bz = z ? spj : dpj;
        const float* bias = z ? sproj_b : dproj_b;

        unsigned short (*As)[64 * 32] = (unsigned short (*)[64 * 32])smem;
        unsigned short (*Bs)[64 * 32] = (unsigned short (*)[64 * 32])(smem + 2 * 64 * 32 * 2);
        int* toks = (int*)(smem + 2 * 64 * 32 * 2 * 2);
        if (tid < 64) toks[tid] = tlist[z * NTOK + min(i0 + tid, cnt - 1)];
        __syncthreads();

        const int wv = tid >> 6;
        const int wm = (wv & 1) * 32, wn = (wv >> 1) * 32;
        const int lm = lane & 15, q = lane >> 4;
        const int r0 = tid >> 2, gsl = tid & 3;
        const int g = gsl ^ ((r0 >> 1) & 3);
        const int lbase = wv * 512;

        const unsigned short* pa = Az + (size_t)(i0 + r0) * K + g * 8;
        const unsigned short* pb = Bz + (size_t)(n0 + r0) * K + g * 8;

        f32x4 acc[2][2];
#pragma unroll
        for (int s = 0; s < 2; ++s)
#pragma unroll
            for (int t = 0; t < 2; ++t) acc[s][t] = (f32x4){0.f, 0.f, 0.f, 0.f};

        glds16(pa, &As[0][lbase]);
        glds16(pb, &Bs[0][lbase]);

        int cur = 0;
        for (int k0 = 0;; k0 += 32) {
            __syncthreads();
            const int kn = k0 + 32;
            if (kn < K) {
                glds16(pa + kn, &As[cur ^ 1][lbase]);
                glds16(pb + kn, &Bs[cur ^ 1][lbase]);
            }
            bf16x8 af[2], bfr[2];
#pragma unroll
            for (int s = 0; s < 2; ++s) af[s] = *(const bf16x8*)&As[cur][ldso(wm + s * 16 + lm, q)];
#pragma unroll
            for (int t = 0; t < 2; ++t) bfr[t] = *(const bf16x8*)&Bs[cur][ldso(wn + t * 16 + lm, q)];
#pragma unroll
            for (int s = 0; s < 2; ++s)
#pragma unroll
                for (int t = 0; t < 2; ++t)
                    acc[s][t] = __builtin_amdgcn_mfma_f32_16x16x32_bf16(af[s], bfr[t], acc[s][t], 0, 0, 0);
            if (kn >= K) break;
            cur ^= 1;
        }
#pragma unroll
        for (int s = 0; s < 2; ++s)
#pragma unroll
            for (int t = 0; t < 2; ++t)
#pragma unroll
                for (int rg = 0; rg < 4; ++rg) {
                    int rl = wm + s * 16 + q * 4 + rg;
                    if (rl < rows) {
                        int gc = n0 + wn + t * 16 + lm;
                        int tok = toks[rl];
                        out[(size_t)tok * E + gc] = scale[tok] * (acc[s][t][rg] + bias[gc]);
                    }
                }
        return;
    }

    // ---- cheap experts: batched 8-token tiles, grid-stride ----
    int* stoks = (int*)smem;
    float* ssc = (float*)(smem + 32);
    float (*sgv)[17] = (float (*)[17])(smem + 64);
    const int k4 = tid * 4;
    for (int s = bb - 1024; s < 4096; s += 2048) {
        const int e = 2 + (s & 3);
        const int ti = s >> 2;
        const int cnt = counts[e];
        const int i0 = ti * 8;
        if (i0 >= cnt) continue;
        const int nt = min(8, cnt - i0);
        __syncthreads();                       // LDS reuse guard across strides
        if (tid < 128) {
            const int tt = tid >> 4, sl = tid & 15;
            const int tk = tlist[e * NTOK + min(i0 + tt, cnt - 1)];
            if (sl == 0) { stoks[tt] = tk; ssc[tt] = scale[tk]; }
            const int base = (e == 2) ? 0 : (e == 3) ? 2 : (e == 4) ? 6 : 7;
            const int ng   = (e == 2) ? 2 : (e == 3) ? 4 : (e == 4) ? 1 : 16;
            if (sl < ng) sgv[tt][sl] = gvec[(size_t)tk * NCH + base + sl];
        }
        __syncthreads();
        if (e == 2) {
            const float4 b0 = *reinterpret_cast<const float4*>(&p2_bias[k4]);
            const float4 v0 = *reinterpret_cast<const float4*>(&p2_v[k4]);
            const float4 v1 = *reinterpret_cast<const float4*>(&p2_v[E + k4]);
#pragma unroll
            for (int tt = 0; tt < 8; ++tt) {
                if (tt < nt) {
                    const float g0 = sgv[tt][0], g1 = sgv[tt][1], sc = ssc[tt];
                    float4 o;
                    o.x = (b0.x + g0 * v0.x + g1 * v1.x) * sc;
                    o.y = (b0.y + g0 * v0.y + g1 * v1.y) * sc;
                    o.z = (b0.z + g0 * v0.z + g1 * v1.z) * sc;
                    o.w = (b0.w + g0 * v0.w + g1 * v1.w) * sc;
                    *reinterpret_cast<float4*>(&out[(size_t)stoks[tt] * E + k4]) = o;
                }
            }
        } else if (e == 3) {
            const float4 b0 = *reinterpret_cast<const float4*>(&p4_bias[k4]);
            float4 vv[4];
#pragma unroll
            for (int j = 0; j < 4; ++j)
                vv[j] = *reinterpret_cast<const float4*>(&p4_v[j * E + k4]);
#pragma unroll
            for (int tt = 0; tt < 8; ++tt) {
                if (tt < nt) {
                    float4 o = b0;
#pragma unroll
                    for (int j = 0; j < 4; ++j) {
                        const float gj = sgv[tt][j];
                        o.x += gj * vv[j].x; o.y += gj * vv[j].y;
                        o.z += gj * vv[j].z; o.w += gj * vv[j].w;
                    }
                    const float sc = ssc[tt];
                    o.x *= sc; o.y *= sc; o.z *= sc; o.w *= sc;
                    *reinterpret_cast<float4*>(&out[(size_t)stoks[tt] * E + k4]) = o;
                }
            }
        } else if (e == 4) {
            const float4 av = *reinterpret_cast<const float4*>(&rg_a[k4]);
            const float4 bv = *reinterpret_cast<const float4*>(&rg_bias[k4]);
#pragma unroll
            for (int tt = 0; tt < 8; ++tt) {
                if (tt < nt) {
                    const float sg = sgv[tt][0], sc = ssc[tt];
                    const float4 xv = *reinterpret_cast<const float4*>(&x[(size_t)stoks[tt] * E + k4]);
                    float4 o;
                    o.x = (sg * xv.x * av.x + bv.x) * sc;
                    o.y = (sg * xv.y * av.y + bv.y) * sc;
                    o.z = (sg * xv.z * av.z + bv.z) * sc;
                    o.w = (sg * xv.w * av.w + bv.w) * sc;
                    *reinterpret_cast<float4*>(&out[(size_t)stoks[tt] * E + k4]) = o;
                }
            }
        } else {  // FiLM: j-outer, 8-token register accumulators
            float4 ga[8], be[8];
            const float4 g0 = *reinterpret_cast<const float4*>(&fl_ub[k4]);
            const float4 b0 = *reinterpret_cast<const float4*>(&fl_ub[E + k4]);
#pragma unroll
            for (int tt = 0; tt < 8; ++tt) { ga[tt] = g0; be[tt] = b0; }
#pragma unroll
            for (int j = 0; j < 16; ++j) {
                const float4 ug = *reinterpret_cast<const float4*>(&fl_uw[(size_t)j * 2 * E + k4]);
                const float4 ub = *reinterpret_cast<const float4*>(&fl_uw[(size_t)j * 2 * E + E + k4]);
#pragma unroll
                for (int tt = 0; tt < 8; ++tt) {
                    const float tj = sgv[tt][j];
                    ga[tt].x += tj * ug.x; ga[tt].y += tj * ug.y;
                    ga[tt].z += tj * ug.z; ga[tt].w += tj * ug.w;
                    be[tt].x += tj * ub.x; be[tt].y += tj * ub.y;
                    be[tt].z += tj * ub.z; be[tt].w += tj * ub.w;
                }
            }
#pragma unroll
            for (int tt = 0; tt < 8; ++tt) {
                if (tt < nt) {
                    const float sc = ssc[tt];
                    const float4 xv = *reinterpret_cast<const float4*>(&x[(size_t)stoks[tt] * E + k4]);
                    float4 o;
                    o.x = (ga[tt].x * xv.x + be[tt].x) * sc;
                    o.y = (ga[tt].y * xv.y + be[tt].y) * sc;
                    o.z = (ga[tt].z * xv.z + be[tt].z) * sc;
                    o.w = (ga[tt].w * xv.w + be[tt].w) * sc;
                    *reinterpret_cast<float4*>(&out[(size_t)stoks[tt] * E + k4]) = o;
                }
            }
        }
    }
}

extern "C" void kernel_launch(void* const* d_in, const int* in_sizes, int n_in,
                              void* d_out, int out_size, void* d_ws, size_t ws_size,
                              hipStream_t stream) {
    const float* x        = (const float*)d_in[0];
    const float* gw1      = (const float*)d_in[1];
    const float* gb1      = (const float*)d_in[2];
    const float* gw2      = (const float*)d_in[3];
    const float* gb2      = (const float*)d_in[4];
    const float* ebias    = (const float*)d_in[5];
    const float* pm_alpha = (const float*)d_in[6];
    const float* dfc_w    = (const float*)d_in[7];
    const float* dfc_b    = (const float*)d_in[8];
    const float* dproj_w  = (const float*)d_in[9];
    const float* dproj_b  = (const float*)d_in[10];
    const float* sfc_w    = (const float*)d_in[11];
    const float* sfc_b    = (const float*)d_in[12];
    const float* sproj_w  = (const float*)d_in[13];
    const float* sproj_b  = (const float*)d_in[14];
    const float* p2_w     = (const float*)d_in[15];
    const float* p2_v     = (const float*)d_in[16];
    const float* p2_alpha = (const float*)d_in[17];
    const float* p2_b     = (const float*)d_in[18];
    const float* p2_bias  = (const float*)d_in[19];
    const float* p4_w     = (const float*)d_in[20];
    const float* p4_v     = (const float*)d_in[21];
    const float* p4_alpha = (const float*)d_in[22];
    const float* p4_b     = (const float*)d_in[23];
    const float* p4_bias  = (const float*)d_in[24];
    const float* rg_u     = (const float*)d_in[25];
    const float* rg_a     = (const float*)d_in[26];
    const float* rg_b     = (const float*)d_in[27];
    const float* rg_bias  = (const float*)d_in[28];
    const float* fl_dw    = (const float*)d_in[29];
    const float* fl_db    = (const float*)d_in[30];
    const float* fl_uw    = (const float*)d_in[31];
    const float* fl_ub    = (const float*)d_in[32];
    float* out = (float*)d_out;

    char* ws = (char*)d_ws;
    size_t off = 0;
    int*            counts = (int*)(ws + off);            off += 256;
    float*          scale  = (float*)(ws + off);          off += (size_t)NTOK * 4;
    int*            tlist  = (int*)(ws + off);            off += (size_t)NEXP * NTOK * 4;
    int*            eid    = (int*)(ws + off);            off += (size_t)NTOK * 4;
    float*          gvec   = (float*)(ws + off);          off += (size_t)NTOK * NCH * 4;
    float*          cdot   = (float*)(ws + off);          off += (size_t)4 * NTOK * NCH * 4;
    unsigned short* w1cheap= (unsigned short*)(ws + off); off += (size_t)64 * 2048 * 2;
    unsigned short* w1cat  = (unsigned short*)(ws + off); off += (size_t)GH * 2048 * 2;
    unsigned short* dfc_wt = (unsigned short*)(ws + off); off += (size_t)2048 * 1024 * 2;
    unsigned short* dpj_wt = (unsigned short*)(ws + off); off += (size_t)1024 * 2048 * 2;
    unsigned short* sfc_wt = (unsigned short*)(ws + off); off += (size_t)1024 * 1024 * 2;
    unsigned short* spj_wt = (unsigned short*)(ws + off); off += (size_t)1024 * 1024 * 2;
    unsigned short* x_hi   = (unsigned short*)(ws + off); off += (size_t)NTOK * E * 2;
    // Union region: gate phase {x_lo} then expert phase {h1, h2}
    char* U = ws + off;
    unsigned short* x_lo = (unsigned short*)U;                              // 16 MB
    unsigned short* h1   = (unsigned short*)U;                              // 16 MB (2048 x 2048)
    unsigned short* h2   = (unsigned short*)(U + (size_t)16 * 1024 * 1024); // 8 MB (2048 x 1024)
    // 4 hp partials (4 x 8 MB = 32 MB) live in d_out (dead after finalize,
    // before gemm2/cheap rewrite every token row).
    float* hp = out;

    hipMemsetAsync(counts, 0, 256, stream);
    prep_kernel<<<8512, 256, 0, stream>>>(x, x_hi, x_lo, gw1, w1cat,
                                          p2_w, p4_w, rg_u, fl_dw, w1cheap,
                                          dfc_w, dfc_wt, dproj_w, dpj_wt,
                                          sfc_w, sfc_wt, sproj_w, spj_wt);
    gate_partial_kernel<<<512, 256, 0, stream>>>(
        x_hi, x_lo, w1cat, w1cheap, hp, cdot);
    gate_finalize_kernel<<<NTOK / 32, 256, 0, stream>>>(
        hp, gb1, gw2, gb2, ebias, pm_alpha, cdot,
        p2_alpha, p2_b, p4_alpha, p4_b, rg_b, fl_db,
        scale, counts, tlist, eid, gvec);
    // y: 32 x 64-row tiles = 2048 rows per expert (mean+20sigma of counts)
    moe_gemm1_kernel<<<2048, 256, 0, stream>>>(
        x_hi, dfc_wt, sfc_wt, dfc_b, sfc_b, counts, tlist, h1, h2);
    gemm2_cheap_kernel<<<1024 + 2048, 256, 0, stream>>>(
        h1, h2, dpj_wt, spj_wt, dproj_b, sproj_b, counts, tlist, scale,
        x, gvec,
        p2_v, p2_bias, p4_v, p4_bias,
        rg_a, rg_bias, fl_uw, fl_ub, out);
    (void)in_sizes; (void)n_in; (void)out_size; (void)ws_size;
}

// Round 7
// 291.122 us; speedup vs baseline: 1.1345x; 1.0100x over previous
//
#include <hip/hip_runtime.h>
#include <math.h>

// Top-1 MoE, 6-dispatch pipeline.
//   memset -> prep -> gate_partial -> gate_finalize -> gemm1+cheap -> gemm2.
// r13: cheap-expert dots ride gate_partial's MFMA (gvec).
// r14: XCD-chunked swizzle on all MFMA GEMMs (FETCH 132->59MB).
// r15: gate_partial 128x128 tiles + global_load_lds dbuf.
// r16/r17: batched 8-token cheap tiles; 64^2 expert GEMMs.
// r18: BK=32 -> BK=64 on every MFMA K-loop. gemm2-class work was pinned at
// ~59us across r13/r16/r17 because 64 serialized barrier+vmcnt(0) drains per
// block each expose ~600-1200cy of load latency; doubling the K-chunk halves
// the round-trips (two glds16 rounds + two compute sub-steps per barrier).
// Also: cheap blocks move from gemm2 (r17 VGPR=216 coupling, Occ 8%) into
// gemm1's dispatch; FiLM split into two 4-token halves caps VGPR ~110.
// gemm2 is a pure GEMM again (~80 VGPR, 32KB LDS, 4 blocks/CU).
// (r18 resubmission: previous round hit GPUAcquisitionTimeout, no data.)

#define E 1024
#define GH 256
#define NEXP 6
#define NTOK 8192
#define NCH 24   // cheap-dot cols: 2 p2 + 4 p4 + 1 rg + 16 film + 1 pad

typedef __attribute__((ext_vector_type(8))) short bf16x8;
typedef __attribute__((ext_vector_type(4))) float f32x4;

__device__ __forceinline__ float gelu_erf(float v) {
    return 0.5f * v * (1.0f + erff(v * 0.70710678118654752440f));
}

__device__ __forceinline__ unsigned short f2bf(float f) {
    union { float f; unsigned u; } c; c.f = f;
    unsigned u = c.u;
    u += 0x7fffu + ((u >> 16) & 1u);   // RNE
    return (unsigned short)(u >> 16);
}

__device__ __forceinline__ float bf2f(unsigned short h) {
    union { unsigned u; float f; } c; c.u = ((unsigned)h) << 16;
    return c.f;
}

// LDS tile addressing (ushort units) within a [rows][32] sub-tile:
// row stride 32 (=64B), k-group XOR swizzle.
__device__ __forceinline__ int ldso(int row, int q) {
    return row * 32 + ((q ^ ((row >> 1) & 3)) << 3);
}

// async global->LDS, 16B per lane; lds dest is wave-uniform base + lane*16.
__device__ __forceinline__ void glds16(const void* g, void* l) {
    __builtin_amdgcn_global_load_lds(
        (const __attribute__((address_space(1))) void*)g,
        (__attribute__((address_space(3))) void*)l, 16, 0, 0);
}

// ---------------- prep: convert + all transposes, one kernel ----------------
__global__ __launch_bounds__(256)
void prep_kernel(const float* __restrict__ x, unsigned short* __restrict__ xh,
                 unsigned short* __restrict__ xl,
                 const float* __restrict__ gw1, unsigned short* __restrict__ w1cat,
                 const float* __restrict__ p2_w, const float* __restrict__ p4_w,
                 const float* __restrict__ rg_u, const float* __restrict__ fl_dw,
                 unsigned short* __restrict__ w1cheap,
                 const float* __restrict__ dfc_w, unsigned short* __restrict__ dfc_wt,
                 const float* __restrict__ dproj_w, unsigned short* __restrict__ dpj_wt,
                 const float* __restrict__ sfc_w, unsigned short* __restrict__ sfc_wt,
                 const float* __restrict__ sproj_w, unsigned short* __restrict__ spj_wt) {
    __shared__ float tile[32][33];
    const int tid = threadIdx.x;
    const int tx = tid & 31, ty = tid >> 5;
    int b = blockIdx.x;
    if (b < 2048) {                       // x -> x_hi + x_lo
        const int n4 = NTOK * E / 4;
        for (int i = b * 256 + tid; i < n4; i += 2048 * 256) {
            float4 v = reinterpret_cast<const float4*>(x)[i];
            ushort4 h, l;
            h.x = f2bf(v.x); l.x = f2bf(v.x - bf2f(h.x));
            h.y = f2bf(v.y); l.y = f2bf(v.y - bf2f(h.y));
            h.z = f2bf(v.z); l.z = f2bf(v.z - bf2f(h.z));
            h.w = f2bf(v.w); l.w = f2bf(v.w - bf2f(h.w));
            reinterpret_cast<ushort4*>(xh)[i] = h;
            reinterpret_cast<ushort4*>(xl)[i] = l;
        }
        return;
    }
    b -= 2048;
    if (b < 256) {                        // gw1 [E][GH] -> w1cat [GH][hi|lo]
        const int c0 = (b & 7) * 32, r0 = (b >> 3) * 32;
#pragma unroll
        for (int i = 0; i < 4; ++i)
            tile[ty + i * 8][tx] = gw1[(size_t)(r0 + ty + i * 8) * GH + c0 + tx];
        __syncthreads();
#pragma unroll
        for (int i = 0; i < 4; ++i) {
            float v = tile[tx][ty + i * 8];
            unsigned short h = f2bf(v);
            size_t row = (size_t)(c0 + ty + i * 8) * 2048;
            w1cat[row + r0 + tx] = h;
            w1cat[row + 1024 + r0 + tx] = f2bf(v - bf2f(h));
        }
        return;
    }
    b -= 256;
    if (b < 64) {                         // cheap-dot weights -> w1cheap [64][hi|lo]
        const int r = b;
        const int k4 = tid * 4;
        float4 v = {0.f, 0.f, 0.f, 0.f};
        if (r < 2)       v = *reinterpret_cast<const float4*>(&p2_w[r * E + k4]);
        else if (r < 6)  v = *reinterpret_cast<const float4*>(&p4_w[(r - 2) * E + k4]);
        else if (r == 6) v = *reinterpret_cast<const float4*>(&rg_u[k4]);
        else if (r < 23) {
            const int j = r - 7;          // fl_dw is [E][16]: gather column j
            v.x = fl_dw[(k4 + 0) * 16 + j];
            v.y = fl_dw[(k4 + 1) * 16 + j];
            v.z = fl_dw[(k4 + 2) * 16 + j];
            v.w = fl_dw[(k4 + 3) * 16 + j];
        }
        ushort4 h, l;
        h.x = f2bf(v.x); l.x = f2bf(v.x - bf2f(h.x));
        h.y = f2bf(v.y); l.y = f2bf(v.y - bf2f(h.y));
        h.z = f2bf(v.z); l.z = f2bf(v.z - bf2f(h.z));
        h.w = f2bf(v.w); l.w = f2bf(v.w - bf2f(h.w));
        *reinterpret_cast<ushort4*>(&w1cheap[r * 2048 + k4]) = h;
        *reinterpret_cast<ushort4*>(&w1cheap[r * 2048 + 1024 + k4]) = l;
        return;
    }
    b -= 64;
    const float* src; unsigned short* dst; int R, C, nbx;
    if (b < 2048)      { src = dfc_w;   dst = dfc_wt; R = 1024; C = 2048; nbx = 64; }
    else if (b < 4096) { src = dproj_w; dst = dpj_wt; R = 2048; C = 1024; nbx = 32; b -= 2048; }
    else if (b < 5120) { src = sfc_w;   dst = sfc_wt; R = 1024; C = 1024; nbx = 32; b -= 4096; }
    else               { src = sproj_w; dst = spj_wt; R = 1024; C = 1024; nbx = 32; b -= 5120; }
    const int c0 = (b % nbx) * 32, r0 = (b / nbx) * 32;
#pragma unroll
    for (int i = 0; i < 4; ++i)
        tile[ty + i * 8][tx] = src[(size_t)(r0 + ty + i * 8) * C + c0 + tx];
    __syncthreads();
#pragma unroll
    for (int i = 0; i < 4; ++i)
        dst[(size_t)(c0 + ty + i * 8) * R + r0 + tx] = f2bf(tile[tx][ty + i * 8]);
}

// ------ gate partial GEMM: hp[c2] = A_z @ w1cat[:, h-half], 128x128 tiles ---
// Grid 512, exactly 2 blocks/CU (LDS 64KB). BK=64: two [128][32] sub-chunks
// per LDS buffer, 16 barriers for K=1024. Decode as r15. Cheap dots: every
// wave adds 2 MFMAs per sub-step.
__global__ __launch_bounds__(256)
void gate_partial_kernel(const unsigned short* __restrict__ xh,
                         const unsigned short* __restrict__ xl,
                         const unsigned short* __restrict__ w1cat,
                         const unsigned short* __restrict__ w1cheap,
                         float* __restrict__ hp,      // [4][NTOK][GH]
                         float* __restrict__ cdot) {  // [4][NTOK][NCH]
    __shared__ __align__(16) unsigned short As[2][128 * 64];   // 32 KB
    __shared__ __align__(16) unsigned short Bs[2][128 * 64];   // 32 KB
    const int tid = threadIdx.x;
    const int bid = blockIdx.x;
    const int xcd = bid & 7, slot = bid >> 3;
    const int nx = slot & 1;
    const int strip = xcd * 32 + (slot >> 1);      // [0,256)
    const int m = strip >> 2, c2 = strip & 3;
    const int z = c2 & 1, h = c2 >> 1;
    const int t0 = m * 128, n0 = nx * 128;
    const unsigned short* A = z ? xl : xh;
    float* hpz = hp + (size_t)c2 * ((size_t)NTOK * GH);
    float* cd  = cdot + (size_t)c2 * ((size_t)NTOK * NCH);

    const int lane = tid & 63, wv = tid >> 6;
    const int wr = wv >> 1, wc = wv & 1;
    const int lm = lane & 15, q = lane >> 4;
    const int r0 = tid >> 2, gsl = tid & 3;
    const int g = gsl ^ ((r0 >> 1) & 3);
    const int lbase = wv * 512;

    const unsigned short* pa0 = A + (size_t)(t0 + r0) * E + g * 8;
    const unsigned short* pa1 = A + (size_t)(t0 + 64 + r0) * E + g * 8;
    const unsigned short* pb0 = w1cat + (size_t)(n0 + r0) * 2048 + h * 1024 + g * 8;
    const unsigned short* pb1 = w1cat + (size_t)(n0 + 64 + r0) * 2048 + h * 1024 + g * 8;
    const unsigned short* pcw = w1cheap + (size_t)(nx * 16 + lm) * 2048 + h * 1024 + q * 8;

    f32x4 acc[4][4];
#pragma unroll
    for (int s = 0; s < 4; ++s)
#pragma unroll
        for (int t = 0; t < 4; ++t) acc[s][t] = (f32x4){0.f, 0.f, 0.f, 0.f};
    f32x4 accC[2];
    accC[0] = (f32x4){0.f, 0.f, 0.f, 0.f};
    accC[1] = (f32x4){0.f, 0.f, 0.f, 0.f};

    glds16(pa0, &As[0][lbase]);
    glds16(pa1, &As[0][2048 + lbase]);
    glds16(pa0 + 32, &As[0][4096 + lbase]);
    glds16(pa1 + 32, &As[0][4096 + 2048 + lbase]);
    glds16(pb0, &Bs[0][lbase]);
    glds16(pb1, &Bs[0][2048 + lbase]);
    glds16(pb0 + 32, &Bs[0][4096 + lbase]);
    glds16(pb1 + 32, &Bs[0][4096 + 2048 + lbase]);
    bf16x8 cf0 = *(const bf16x8*)pcw;
    bf16x8 cf1 = *(const bf16x8*)(pcw + 32);

    int cur = 0;
    for (int k0 = 0;; k0 += 64) {
        __syncthreads();                  // drains vmcnt -> buf[cur] landed
        const int kn = k0 + 64;
        bf16x8 cf0n, cf1n;
        if (kn < 1024) {
            glds16(pa0 + kn, &As[cur ^ 1][lbase]);
            glds16(pa1 + kn, &As[cur ^ 1][2048 + lbase]);
            glds16(pa0 + kn + 32, &As[cur ^ 1][4096 + lbase]);
            glds16(pa1 + kn + 32, &As[cur ^ 1][4096 + 2048 + lbase]);
            glds16(pb0 + kn, &Bs[cur ^ 1][lbase]);
            glds16(pb1 + kn, &Bs[cur ^ 1][2048 + lbase]);
            glds16(pb0 + kn + 32, &Bs[cur ^ 1][4096 + lbase]);
            glds16(pb1 + kn + 32, &Bs[cur ^ 1][4096 + 2048 + lbase]);
            cf0n = *(const bf16x8*)(pcw + kn);
            cf1n = *(const bf16x8*)(pcw + kn + 32);
        }
#pragma unroll
        for (int sub = 0; sub < 2; ++sub) {
            const int off = sub * 4096;
            bf16x8 af[4], bfr[4];
#pragma unroll
            for (int s = 0; s < 4; ++s) af[s] = *(const bf16x8*)&As[cur][off + ldso(wr * 64 + s * 16 + lm, q)];
#pragma unroll
            for (int t = 0; t < 4; ++t) bfr[t] = *(const bf16x8*)&Bs[cur][off + ldso(wc * 64 + t * 16 + lm, q)];
#pragma unroll
            for (int s = 0; s < 4; ++s)
#pragma unroll
                for (int t = 0; t < 4; ++t)
                    acc[s][t] = __builtin_amdgcn_mfma_f32_16x16x32_bf16(af[s], bfr[t], acc[s][t], 0, 0, 0);
            bf16x8 cf = sub ? cf1 : cf0;
            bf16x8 ac0 = wc ? af[2] : af[0];
            bf16x8 ac1 = wc ? af[3] : af[1];
            accC[0] = __builtin_amdgcn_mfma_f32_16x16x32_bf16(ac0, cf, accC[0], 0, 0, 0);
            accC[1] = __builtin_amdgcn_mfma_f32_16x16x32_bf16(ac1, cf, accC[1], 0, 0, 0);
        }
        if (kn >= 1024) break;
        cf0 = cf0n; cf1 = cf1n; cur ^= 1;
    }
#pragma unroll
    for (int s = 0; s < 4; ++s)
#pragma unroll
        for (int t = 0; t < 4; ++t)
#pragma unroll
            for (int rg = 0; rg < 4; ++rg) {
                int rl = wr * 64 + s * 16 + q * 4 + rg;
                int c  = wc * 64 + t * 16 + lm;
                hpz[(size_t)(t0 + rl) * GH + n0 + c] = acc[s][t][rg];
            }
    const int cc = nx * 16 + lm;
    if (cc < NCH) {
#pragma unroll
        for (int i = 0; i < 2; ++i)
#pragma unroll
            for (int rg = 0; rg < 4; ++rg) {
                int rl = wr * 64 + wc * 32 + i * 16 + q * 4 + rg;
                cd[(size_t)(t0 + rl) * NCH + cc] = accC[i][rg];
            }
    }
}

// ------- finalize: h=gelu(sum4 hp+gb1); logits=h@gw2; softmax/argmax --------
// Also converts summed cheap dots (4 partials) into gate scalars gvec[NCH].
__global__ __launch_bounds__(256)
void gate_finalize_kernel(const float* __restrict__ hp,    // [4][NTOK][GH]
                          const float* __restrict__ gb1, const float* __restrict__ gw2,
                          const float* __restrict__ gb2, const float* __restrict__ ebias,
                          const float* __restrict__ pm_alpha,
                          const float* __restrict__ cdot,  // [4][NTOK][NCH]
                          const float* __restrict__ p2_alpha, const float* __restrict__ p2_b,
                          const float* __restrict__ p4_alpha, const float* __restrict__ p4_b,
                          const float* __restrict__ rg_b, const float* __restrict__ fl_db,
                          float* __restrict__ scale, int* __restrict__ counts,
                          int* __restrict__ tlist, int* __restrict__ eid,
                          float* __restrict__ gvec) {
    __shared__ float hs[32][264];
    __shared__ float g2s[GH * NEXP];
    __shared__ int tokexp[32];
    const int tid = threadIdx.x;
    const int t0 = blockIdx.x * 32;
    const size_t HPS = (size_t)NTOK * GH;
    for (int i = tid; i < GH * NEXP; i += 256) g2s[i] = gw2[i];
#pragma unroll
    for (int i = 0; i < 8; ++i) {
        int f4 = i * 256 + tid;
        int row = f4 >> 6, c4 = (f4 & 63) * 4;
        size_t base = (size_t)(t0 + row) * GH + c4;
        float4 a = *reinterpret_cast<const float4*>(&hp[base]);
        float4 b = *reinterpret_cast<const float4*>(&hp[HPS + base]);
        float4 c = *reinterpret_cast<const float4*>(&hp[2 * HPS + base]);
        float4 d = *reinterpret_cast<const float4*>(&hp[3 * HPS + base]);
        float4 o;
        o.x = gelu_erf(a.x + b.x + c.x + d.x + gb1[c4 + 0]);
        o.y = gelu_erf(a.y + b.y + c.y + d.y + gb1[c4 + 1]);
        o.z = gelu_erf(a.z + b.z + c.z + d.z + gb1[c4 + 2]);
        o.w = gelu_erf(a.w + b.w + c.w + d.w + gb1[c4 + 3]);
        *reinterpret_cast<float4*>(&hs[row][c4]) = o;
    }
    __syncthreads();
    const int t = tid >> 3, j = tid & 7;
    float p[NEXP] = {0.f, 0.f, 0.f, 0.f, 0.f, 0.f};
#pragma unroll 8
    for (int kk = 0; kk < 32; ++kk) {
        int k = j + kk * 8;
        float hv = hs[t][k];
        const float* gr = &g2s[k * NEXP];
#pragma unroll
        for (int m = 0; m < NEXP; ++m) p[m] += hv * gr[m];
    }
#pragma unroll
    for (int m = 0; m < NEXP; ++m) {
        p[m] += __shfl_xor(p[m], 4, 64);
        p[m] += __shfl_xor(p[m], 2, 64);
        p[m] += __shfl_xor(p[m], 1, 64);
    }
    if (j == 0) {
        float L[NEXP];
#pragma unroll
        for (int m = 0; m < NEXP; ++m) L[m] = p[m] + gb2[m] + ebias[m];
        float mx = L[0]; int am = 0;
#pragma unroll
        for (int m = 1; m < NEXP; ++m) { if (L[m] > mx) { mx = L[m]; am = m; } }
        float S = 0.f;
#pragma unroll
        for (int m = 0; m < NEXP; ++m) S += expf(L[m] - mx);
        float pt = 1.f / S;
        scale[t0 + t] = pm_alpha[0] * (pt / (pt + 1e-9f));
        eid[t0 + t] = am;
        tokexp[t] = am;
    }
    __syncthreads();
    if (tid < NEXP) {
        const int e = tid;
        int cnt = 0;
#pragma unroll
        for (int i = 0; i < 32; ++i) cnt += (tokexp[i] == e);
        if (cnt) {
            int base = atomicAdd(&counts[e], cnt);
            int pos = 0;
#pragma unroll
            for (int i = 0; i < 32; ++i)
                if (tokexp[i] == e) tlist[e * NTOK + base + (pos++)] = t0 + i;
        }
    }
    // ---- per-token cheap-gate scalars (independent of the above) ----
    const size_t CDS = (size_t)NTOK * NCH;
    for (int i = tid; i < 32 * NCH; i += 256) {
        const int tt = i / NCH, slot = i - tt * NCH;
        const int tok = t0 + tt;
        size_t idx = (size_t)tok * NCH + slot;
        float s = cdot[idx] + cdot[CDS + idx] + cdot[2 * CDS + idx] + cdot[3 * CDS + idx];
        float val;
        if (slot < 2)       val = p2_alpha[slot] * gelu_erf(s + p2_b[slot]);
        else if (slot < 6)  val = p4_alpha[slot - 2] * gelu_erf(s + p4_b[slot - 2]);
        else if (slot == 6) val = 1.f / (1.f + expf(-(s + rg_b[0])));
        else if (slot < 23) val = gelu_erf(s + fl_db[slot - 7]);
        else                val = 0.f;
        gvec[(size_t)tok * NCH + slot] = val;
    }
}

// -------- GEMM1 (gather x_hi -> gelu -> bf16 h) fused with cheap experts ----
// blocks [0,2048): gemm1, r14 decode (xcd=bid&7, nx=slot&31, strip strided),
// 64x64 tiles, BK=64 (two sub-chunks per buffer, 16 barriers for K=1024),
// LDS 32KB -> 4 blocks/CU.
// blocks [2048,4096): batched cheap tiles (grid-stride over 4096 slots):
// e=2+(s&3), 8 expert-sorted tokens; FiLM j-outer in two 4-token halves
// (keeps fused-kernel VGPR ~110 so gemm1 blocks keep 4 waves/SIMD).
__global__ __launch_bounds__(256)
void gemm1_cheap_kernel(const unsigned short* __restrict__ xh,
                        const unsigned short* __restrict__ B0, const unsigned short* __restrict__ B1,
                        const float* __restrict__ bias0, const float* __restrict__ bias1,
                        const int* __restrict__ counts, const int* __restrict__ tlist,
                        unsigned short* __restrict__ H0, unsigned short* __restrict__ H1,
                        const float* __restrict__ scale, const float* __restrict__ x,
                        const float* __restrict__ gvec,
                        const float* __restrict__ p2_v, const float* __restrict__ p2_bias,
                        const float* __restrict__ p4_v, const float* __restrict__ p4_bias,
                        const float* __restrict__ rg_a, const float* __restrict__ rg_bias,
                        const float* __restrict__ fl_uw, const float* __restrict__ fl_ub,
                        float* __restrict__ out) {
    __shared__ __align__(16) char smem[2 * 64 * 64 * 2 * 2 + 64 * 4];  // 32 KB + 256
    const int tid = threadIdx.x;
    const int bb = blockIdx.x;
    const int lane = tid & 63;

    if (bb < 2048) {
        const int xcd = bb & 7, slot = bb >> 3;      // [0,256)
        const int nx = slot & 31;
        const int strip = xcd + 8 * (slot >> 5);     // [0,64), XCD-strided
        const int z = strip & 1;
        const int N = z ? 1024 : 2048;
        const int cnt = counts[z];
        const int i0 = (strip >> 1) * 64;
        const int n0 = nx * 64;
        if (i0 >= cnt || n0 >= N) return;
        const unsigned short* Bz = z ? B1 : B0;
        const float* bias = z ? bias1 : bias0;

        unsigned short (*As)[64 * 64] = (unsigned short (*)[64 * 64])smem;
        unsigned short (*Bs)[64 * 64] = (unsigned short (*)[64 * 64])(smem + 2 * 64 * 64 * 2);
        int* toks = (int*)(smem + 2 * 64 * 64 * 2 * 2);
        if (tid < 64) toks[tid] = tlist[z * NTOK + min(i0 + tid, cnt - 1)];
        __syncthreads();

        const int wv = tid >> 6;
        const int wm = (wv & 1) * 32, wn = (wv >> 1) * 32;
        const int lm = lane & 15, q = lane >> 4;
        const int r0 = tid >> 2, gsl = tid & 3;
        const int g = gsl ^ ((r0 >> 1) & 3);
        const int lbase = wv * 512;

        const unsigned short* pa = xh + (size_t)toks[r0] * E + g * 8;
        const unsigned short* pb = Bz + (size_t)(n0 + r0) * E + g * 8;

        f32x4 acc[2][2];
#pragma unroll
        for (int s = 0; s < 2; ++s)
#pragma unroll
            for (int t = 0; t < 2; ++t) acc[s][t] = (f32x4){0.f, 0.f, 0.f, 0.f};

        glds16(pa, &As[0][lbase]);
        glds16(pa + 32, &As[0][2048 + lbase]);
        glds16(pb, &Bs[0][lbase]);
        glds16(pb + 32, &Bs[0][2048 + lbase]);

        int cur = 0;
        for (int k0 = 0;; k0 += 64) {
            __syncthreads();
            const int kn = k0 + 64;
            if (kn < E) {
                glds16(pa + kn, &As[cur ^ 1][lbase]);
                glds16(pa + kn + 32, &As[cur ^ 1][2048 + lbase]);
                glds16(pb + kn, &Bs[cur ^ 1][lbase]);
                glds16(pb + kn + 32, &Bs[cur ^ 1][2048 + lbase]);
            }
#pragma unroll
            for (int sub = 0; sub < 2; ++sub) {
                const int off = sub * 2048;
                bf16x8 af[2], bfr[2];
#pragma unroll
                for (int s = 0; s < 2; ++s) af[s] = *(const bf16x8*)&As[cur][off + ldso(wm + s * 16 + lm, q)];
#pragma unroll
                for (int t = 0; t < 2; ++t) bfr[t] = *(const bf16x8*)&Bs[cur][off + ldso(wn + t * 16 + lm, q)];
#pragma unroll
                for (int s = 0; s < 2; ++s)
#pragma unroll
                    for (int t = 0; t < 2; ++t)
                        acc[s][t] = __builtin_amdgcn_mfma_f32_16x16x32_bf16(af[s], bfr[t], acc[s][t], 0, 0, 0);
            }
            if (kn >= E) break;
            cur ^= 1;
        }
        unsigned short* Hz = z ? H1 : H0;
#pragma unroll
        for (int s = 0; s < 2; ++s)
#pragma unroll
            for (int t = 0; t < 2; ++t)
#pragma unroll
                for (int rg = 0; rg < 4; ++rg) {
                    int rl = wm + s * 16 + q * 4 + rg;
                    int gc = n0 + wn + t * 16 + lm;
                    float v = acc[s][t][rg] + bias[gc];
                    Hz[(size_t)(i0 + rl) * N + gc] = f2bf(gelu_erf(v));
                }
        return;
    }

    // ---- cheap experts: batched 8-token tiles, grid-stride ----
    int* stoks = (int*)smem;
    float* ssc = (float*)(smem + 32);
    float (*sgv)[17] = (float (*)[17])(smem + 64);
    const int k4 = tid * 4;
    for (int s = bb - 2048; s < 4096; s += 2048) {
        const int e = 2 + (s & 3);
        const int ti = s >> 2;
        const int cnt = counts[e];
        const int i0 = ti * 8;
        if (i0 >= cnt) continue;
        const int nt = min(8, cnt - i0);
        __syncthreads();                       // LDS reuse guard across strides
        if (tid < 128) {
            const int tt = tid >> 4, sl = tid & 15;
            const int tk = tlist[e * NTOK + min(i0 + tt, cnt - 1)];
            if (sl == 0) { stoks[tt] = tk; ssc[tt] = scale[tk]; }
            const int base = (e == 2) ? 0 : (e == 3) ? 2 : (e == 4) ? 6 : 7;
            const int ng   = (e == 2) ? 2 : (e == 3) ? 4 : (e == 4) ? 1 : 16;
            if (sl < ng) sgv[tt][sl] = gvec[(size_t)tk * NCH + base + sl];
        }
        __syncthreads();
        if (e == 2) {
            const float4 b0 = *reinterpret_cast<const float4*>(&p2_bias[k4]);
            const float4 v0 = *reinterpret_cast<const float4*>(&p2_v[k4]);
            const float4 v1 = *reinterpret_cast<const float4*>(&p2_v[E + k4]);
#pragma unroll
            for (int tt = 0; tt < 8; ++tt) {
                if (tt < nt) {
                    const float g0 = sgv[tt][0], g1 = sgv[tt][1], sc = ssc[tt];
                    float4 o;
                    o.x = (b0.x + g0 * v0.x + g1 * v1.x) * sc;
                    o.y = (b0.y + g0 * v0.y + g1 * v1.y) * sc;
                    o.z = (b0.z + g0 * v0.z + g1 * v1.z) * sc;
                    o.w = (b0.w + g0 * v0.w + g1 * v1.w) * sc;
                    *reinterpret_cast<float4*>(&out[(size_t)stoks[tt] * E + k4]) = o;
                }
            }
        } else if (e == 3) {
            const float4 b0 = *reinterpret_cast<const float4*>(&p4_bias[k4]);
            float4 vv[4];
#pragma unroll
            for (int j = 0; j < 4; ++j)
                vv[j] = *reinterpret_cast<const float4*>(&p4_v[j * E + k4]);
#pragma unroll
            for (int tt = 0; tt < 8; ++tt) {
                if (tt < nt) {
                    float4 o = b0;
#pragma unroll
                    for (int j = 0; j < 4; ++j) {
                        const float gj = sgv[tt][j];
                        o.x += gj * vv[j].x; o.y += gj * vv[j].y;
                        o.z += gj * vv[j].z; o.w += gj * vv[j].w;
                    }
                    const float sc = ssc[tt];
                    o.x *= sc; o.y *= sc; o.z *= sc; o.w *= sc;
                    *reinterpret_cast<float4*>(&out[(size_t)stoks[tt] * E + k4]) = o;
                }
            }
        } else if (e == 4) {
            const float4 av = *reinterpret_cast<const float4*>(&rg_a[k4]);
            const float4 bv = *reinterpret_cast<const float4*>(&rg_bias[k4]);
#pragma unroll
            for (int tt = 0; tt < 8; ++tt) {
                if (tt < nt) {
                    const float sg = sgv[tt][0], sc = ssc[tt];
                    const float4 xv = *reinterpret_cast<const float4*>(&x[(size_t)stoks[tt] * E + k4]);
                    float4 o;
                    o.x = (sg * xv.x * av.x + bv.x) * sc;
                    o.y = (sg * xv.y * av.y + bv.y) * sc;
                    o.z = (sg * xv.z * av.z + bv.z) * sc;
                    o.w = (sg * xv.w * av.w + bv.w) * sc;
                    *reinterpret_cast<float4*>(&out[(size_t)stoks[tt] * E + k4]) = o;
                }
            }
        } else {  // FiLM: j-outer, two 4-token halves (VGPR cap)
#pragma unroll
            for (int half = 0; half < 2; ++half) {
                float4 ga[4], be[4];
                const float4 g0 = *reinterpret_cast<const float4*>(&fl_ub[k4]);
                const float4 b0 = *reinterpret_cast<const float4*>(&fl_ub[E + k4]);
#pragma unroll
                for (int tt = 0; tt < 4; ++tt) { ga[tt] = g0; be[tt] = b0; }
#pragma unroll
                for (int j = 0; j < 16; ++j) {
                    const float4 ug = *reinterpret_cast<const float4*>(&fl_uw[(size_t)j * 2 * E + k4]);
                    const float4 ub = *reinterpret_cast<const float4*>(&fl_uw[(size_t)j * 2 * E + E + k4]);
#pragma unroll
                    for (int tt = 0; tt < 4; ++tt) {
                        const float tj = sgv[half * 4 + tt][j];
                        ga[tt].x += tj * ug.x; ga[tt].y += tj * ug.y;
                        ga[tt].z += tj * ug.z; ga[tt].w += tj * ug.w;
                        be[tt].x += tj * ub.x; be[tt].y += tj * ub.y;
                        be[tt].z += tj * ub.z; be[tt].w += tj * ub.w;
                    }
                }
#pragma unroll
                for (int tt = 0; tt < 4; ++tt) {
                    const int ix = half * 4 + tt;
                    if (ix < nt) {
                        const float sc = ssc[ix];
                        const float4 xv = *reinterpret_cast<const float4*>(&x[(size_t)stoks[ix] * E + k4]);
                        float4 o;
                        o.x = (ga[tt].x * xv.x + be[tt].x) * sc;
                        o.y = (ga[tt].y * xv.y + be[tt].y) * sc;
                        o.z = (ga[tt].z * xv.z + be[tt].z) * sc;
                        o.w = (ga[tt].w * xv.w + be[tt].w) * sc;
                        *reinterpret_cast<float4*>(&out[(size_t)stoks[ix] * E + k4]) = o;
                    }
                }
            }
        }
    }
}

// ---------------- GEMM2 (experts 0/1 down-proj), pure GEMM ------------------
// Grid 1024. xcd=bb&7, slot=bb>>3 in [0,128): nx=slot&15, strip=xcd+8*(slot>>4)
// in [0,64), z=strip&1, i0=(strip>>1)*64. 64x64 tiles, BK=64, 32KB LDS.
__global__ __launch_bounds__(256)
void moe_gemm2_kernel(const unsigned short* __restrict__ h1, const unsigned short* __restrict__ h2,
                      const unsigned short* __restrict__ dpj, const unsigned short* __restrict__ spj,
                      const float* __restrict__ dproj_b, const float* __restrict__ sproj_b,
                      const int* __restrict__ counts, const int* __restrict__ tlist,
                      const float* __restrict__ scale,
                      float* __restrict__ out) {
    __shared__ __align__(16) unsigned short As[2][64 * 64];   // 16 KB
    __shared__ __align__(16) unsigned short Bs[2][64 * 64];   // 16 KB
    __shared__ int toks[64];
    const int tid = threadIdx.x;
    const int bb = blockIdx.x;
    const int lane = tid & 63;

    const int xcd = bb & 7, slot = bb >> 3;    // [0,128)
    const int nx = slot & 15;
    const int strip = xcd + 8 * (slot >> 4);   // [0,64)
    const int z = strip & 1;
    const int i0 = (strip >> 1) * 64;
    const int n0 = nx * 64;
    const int K = z ? 1024 : 2048;
    const int cnt = counts[z];
    if (i0 >= cnt) return;
    const int rows = min(64, cnt - i0);
    const unsigned short* Az = z ? h2 : h1;
    const unsigned short* Bz = z ? spj : dpj;
    const float* bias = z ? sproj_b : dproj_b;

    if (tid < 64) toks[tid] = tlist[z * NTOK + min(i0 + tid, cnt - 1)];
    __syncthreads();

    const int wv = tid >> 6;
    const int wm = (wv & 1) * 32, wn = (wv >> 1) * 32;
    const int lm = lane & 15, q = lane >> 4;
    const int r0 = tid >> 2, gsl = tid & 3;
    const int g = gsl ^ ((r0 >> 1) & 3);
    const int lbase = wv * 512;

    const unsigned short* pa = Az + (size_t)(i0 + r0) * K + g * 8;
    const unsigned short* pb = Bz + (size_t)(n0 + r0) * K + g * 8;

    f32x4 acc[2][2];
#pragma unroll
    for (int s = 0; s < 2; ++s)
#pragma unroll
        for (int t = 0; t < 2; ++t) acc[s][t] = (f32x4){0.f, 0.f, 0.f, 0.f};

    glds16(pa, &As[0][lbase]);
    glds16(pa + 32, &As[0][2048 + lbase]);
    glds16(pb, &Bs[0][lbase]);
    glds16(pb + 32, &Bs[0][2048 + lbase]);

    int cur = 0;
    for (int k0 = 0;; k0 += 64) {
        __syncthreads();
        const int kn = k0 + 64;
        if (kn < K) {
            glds16(pa + kn, &As[cur ^ 1][lbase]);
            glds16(pa + kn + 32, &As[cur ^ 1][2048 + lbase]);
            glds16(pb + kn, &Bs[cur ^ 1][lbase]);
            glds16(pb + kn + 32, &Bs[cur ^ 1][2048 + lbase]);
        }
#pragma unroll
        for (int sub = 0; sub < 2; ++sub) {
            const int off = sub * 2048;
            bf16x8 af[2], bfr[2];
#pragma unroll
            for (int s = 0; s < 2; ++s) af[s] = *(const bf16x8*)&As[cur][off + ldso(wm + s * 16 + lm, q)];
#pragma unroll
            for (int t = 0; t < 2; ++t) bfr[t] = *(const bf16x8*)&Bs[cur][off + ldso(wn + t * 16 + lm, q)];
#pragma unroll
            for (int s = 0; s < 2; ++s)
#pragma unroll
                for (int t = 0; t < 2; ++t)
                    acc[s][t] = __builtin_amdgcn_mfma_f32_16x16x32_bf16(af[s], bfr[t], acc[s][t], 0, 0, 0);
        }
        if (kn >= K) break;
        cur ^= 1;
    }
#pragma unroll
    for (int s = 0; s < 2; ++s)
#pragma unroll
        for (int t = 0; t < 2; ++t)
#pragma unroll
            for (int rg = 0; rg < 4; ++rg) {
                int rl = wm + s * 16 + q * 4 + rg;
                if (rl < rows) {
                    int gc = n0 + wn + t * 16 + lm;
                    int tok = toks[rl];
                    out[(size_t)tok * E + gc] = scale[tok] * (acc[s][t][rg] + bias[gc]);
                }
            }
}

extern "C" void kernel_launch(void* const* d_in, const int* in_sizes, int n_in,
                              void* d_out, int out_size, void* d_ws, size_t ws_size,
                              hipStream_t stream) {
    const float* x        = (const float*)d_in[0];
    const float* gw1      = (const float*)d_in[1];
    const float* gb1      = (const float*)d_in[2];
    const float* gw2      = (const float*)d_in[3];
    const float* gb2      = (const float*)d_in[4];
    const float* ebias    = (const float*)d_in[5];
    const float* pm_alpha = (const float*)d_in[6];
    const float* dfc_w    = (const float*)d_in[7];
    const float* dfc_b    = (const float*)d_in[8];
    const float* dproj_w  = (const float*)d_in[9];
    const float* dproj_b  = (const float*)d_in[10];
    const float* sfc_w    = (const float*)d_in[11];
    const float* sfc_b    = (const float*)d_in[12];
    const float* sproj_w  = (const float*)d_in[13];
    const float* sproj_b  = (const float*)d_in[14];
    const float* p2_w     = (const float*)d_in[15];
    const float* p2_v     = (const float*)d_in[16];
    const float* p2_alpha = (const float*)d_in[17];
    const float* p2_b     = (const float*)d_in[18];
    const float* p2_bias  = (const float*)d_in[19];
    const float* p4_w     = (const float*)d_in[20];
    const float* p4_v     = (const float*)d_in[21];
    const float* p4_alpha = (const float*)d_in[22];
    const float* p4_b     = (const float*)d_in[23];
    const float* p4_bias  = (const float*)d_in[24];
    const float* rg_u     = (const float*)d_in[25];
    const float* rg_a     = (const float*)d_in[26];
    const float* rg_b     = (const float*)d_in[27];
    const float* rg_bias  = (const float*)d_in[28];
    const float* fl_dw    = (const float*)d_in[29];
    const float* fl_db    = (const float*)d_in[30];
    const float* fl_uw    = (const float*)d_in[31];
    const float* fl_ub    = (const float*)d_in[32];
    float* out = (float*)d_out;

    char* ws = (char*)d_ws;
    size_t off = 0;
    int*            counts = (int*)(ws + off);            off += 256;
    float*          scale  = (float*)(ws + off);          off += (size_t)NTOK * 4;
    int*            tlist  = (int*)(ws + off);            off += (size_t)NEXP * NTOK * 4;
    int*            eid    = (int*)(ws + off);            off += (size_t)NTOK * 4;
    float*          gvec   = (float*)(ws + off);          off += (size_t)NTOK * NCH * 4;
    float*          cdot   = (float*)(ws + off);          off += (size_t)4 * NTOK * NCH * 4;
    unsigned short* w1cheap= (unsigned short*)(ws + off); off += (size_t)64 * 2048 * 2;
    unsigned short* w1cat  = (unsigned short*)(ws + off); off += (size_t)GH * 2048 * 2;
    unsigned short* dfc_wt = (unsigned short*)(ws + off); off += (size_t)2048 * 1024 * 2;
    unsigned short* dpj_wt = (unsigned short*)(ws + off); off += (size_t)1024 * 2048 * 2;
    unsigned short* sfc_wt = (unsigned short*)(ws + off); off += (size_t)1024 * 1024 * 2;
    unsigned short* spj_wt = (unsigned short*)(ws + off); off += (size_t)1024 * 1024 * 2;
    unsigned short* x_hi   = (unsigned short*)(ws + off); off += (size_t)NTOK * E * 2;
    // Union region: gate phase {x_lo} then expert phase {h1, h2}
    char* U = ws + off;
    unsigned short* x_lo = (unsigned short*)U;                              // 16 MB
    unsigned short* h1   = (unsigned short*)U;                              // 16 MB (2048 x 2048)
    unsigned short* h2   = (unsigned short*)(U + (size_t)16 * 1024 * 1024); // 8 MB (2048 x 1024)
    // 4 hp partials (4 x 8 MB = 32 MB) live in d_out (dead after finalize,
    // before gemm1-cheap/gemm2 rewrite every token row).
    float* hp = out;

    hipMemsetAsync(counts, 0, 256, stream);
    prep_kernel<<<8512, 256, 0, stream>>>(x, x_hi, x_lo, gw1, w1cat,
                                          p2_w, p4_w, rg_u, fl_dw, w1cheap,
                                          dfc_w, dfc_wt, dproj_w, dpj_wt,
                                          sfc_w, sfc_wt, sproj_w, spj_wt);
    gate_partial_kernel<<<512, 256, 0, stream>>>(
        x_hi, x_lo, w1cat, w1cheap, hp, cdot);
    gate_finalize_kernel<<<NTOK / 32, 256, 0, stream>>>(
        hp, gb1, gw2, gb2, ebias, pm_alpha, cdot,
        p2_alpha, p2_b, p4_alpha, p4_b, rg_b, fl_db,
        scale, counts, tlist, eid, gvec);
    // y: 32 x 64-row tiles = 2048 rows per expert (mean+20sigma of counts)
    gemm1_cheap_kernel<<<4096, 256, 0, stream>>>(
        x_hi, dfc_wt, sfc_wt, dfc_b, sfc_b, counts, tlist, h1, h2,
        scale, x, gvec,
        p2_v, p2_bias, p4_v, p4_bias,
        rg_a, rg_bias, fl_uw, fl_ub, out);
    moe_gemm2_kernel<<<1024, 256, 0, stream>>>(
        h1, h2, dpj_wt, spj_wt, dproj_b, sproj_b, counts, tlist, scale, out);
    (void)in_sizes; (void)n_in; (void)out_size; (void)ws_size;
}

// Round 8
// 283.551 us; speedup vs baseline: 1.1648x; 1.0267x over previous
//
#include <hip/hip_runtime.h>
#include <math.h>

// Top-1 MoE, 7-dispatch pipeline.
//   memset -> prep -> gate_partial -> gate_finalize -> gemm1 -> gemm2 -> cheap.
// r13: cheap-expert dots ride gate_partial's MFMA (gvec).
// r14: XCD-chunked swizzle on all MFMA GEMMs (FETCH 132->59MB).
// r15: gate_partial 128x128 tiles + global_load_lds dbuf.
// r16/r17/r18: tile/BK shuffles -- all neutral. Diagnosis: expert-GEMM work
// pinned at ~58us / 1.1TB/s / Mfma 3% across Occ 8-30%, BK 32/64, tiles
// 64/128 => the __syncthreads vmcnt(0) DRAIN exposes ~900cy HBM latency
// every K-step regardless of geometry.
// r19: depth-3 counted-vmcnt pipeline on gemm1/gemm2 (T3/T4): 3 LDS buffers,
// raw s_barrier (no drain), s_waitcnt vmcnt(8/4/0) so 2 tiles stay in flight
// across barriers (ordered completion => oldest tile landed). Cheap experts
// back to standalone batched kernel (fusing it kept poisoning VGPR/LDS).

#define E 1024
#define GH 256
#define NEXP 6
#define NTOK 8192
#define NCH 24   // cheap-dot cols: 2 p2 + 4 p4 + 1 rg + 16 film + 1 pad

typedef __attribute__((ext_vector_type(8))) short bf16x8;
typedef __attribute__((ext_vector_type(4))) float f32x4;

__device__ __forceinline__ float gelu_erf(float v) {
    return 0.5f * v * (1.0f + erff(v * 0.70710678118654752440f));
}

__device__ __forceinline__ unsigned short f2bf(float f) {
    union { float f; unsigned u; } c; c.f = f;
    unsigned u = c.u;
    u += 0x7fffu + ((u >> 16) & 1u);   // RNE
    return (unsigned short)(u >> 16);
}

__device__ __forceinline__ float bf2f(unsigned short h) {
    union { unsigned u; float f; } c; c.u = ((unsigned)h) << 16;
    return c.f;
}

// LDS tile addressing (ushort units) within a [rows][32] sub-tile:
// row stride 32 (=64B), k-group XOR swizzle.
__device__ __forceinline__ int ldso(int row, int q) {
    return row * 32 + ((q ^ ((row >> 1) & 3)) << 3);
}

// async global->LDS, 16B per lane; lds dest is wave-uniform base + lane*16.
__device__ __forceinline__ void glds16(const void* g, void* l) {
    __builtin_amdgcn_global_load_lds(
        (const __attribute__((address_space(1))) void*)g,
        (__attribute__((address_space(3))) void*)l, 16, 0, 0);
}

// ---------------- prep: convert + all transposes, one kernel ----------------
__global__ __launch_bounds__(256)
void prep_kernel(const float* __restrict__ x, unsigned short* __restrict__ xh,
                 unsigned short* __restrict__ xl,
                 const float* __restrict__ gw1, unsigned short* __restrict__ w1cat,
                 const float* __restrict__ p2_w, const float* __restrict__ p4_w,
                 const float* __restrict__ rg_u, const float* __restrict__ fl_dw,
                 unsigned short* __restrict__ w1cheap,
                 const float* __restrict__ dfc_w, unsigned short* __restrict__ dfc_wt,
                 const float* __restrict__ dproj_w, unsigned short* __restrict__ dpj_wt,
                 const float* __restrict__ sfc_w, unsigned short* __restrict__ sfc_wt,
                 const float* __restrict__ sproj_w, unsigned short* __restrict__ spj_wt) {
    __shared__ float tile[32][33];
    const int tid = threadIdx.x;
    const int tx = tid & 31, ty = tid >> 5;
    int b = blockIdx.x;
    if (b < 2048) {                       // x -> x_hi + x_lo
        const int n4 = NTOK * E / 4;
        for (int i = b * 256 + tid; i < n4; i += 2048 * 256) {
            float4 v = reinterpret_cast<const float4*>(x)[i];
            ushort4 h, l;
            h.x = f2bf(v.x); l.x = f2bf(v.x - bf2f(h.x));
            h.y = f2bf(v.y); l.y = f2bf(v.y - bf2f(h.y));
            h.z = f2bf(v.z); l.z = f2bf(v.z - bf2f(h.z));
            h.w = f2bf(v.w); l.w = f2bf(v.w - bf2f(h.w));
            reinterpret_cast<ushort4*>(xh)[i] = h;
            reinterpret_cast<ushort4*>(xl)[i] = l;
        }
        return;
    }
    b -= 2048;
    if (b < 256) {                        // gw1 [E][GH] -> w1cat [GH][hi|lo]
        const int c0 = (b & 7) * 32, r0 = (b >> 3) * 32;
#pragma unroll
        for (int i = 0; i < 4; ++i)
            tile[ty + i * 8][tx] = gw1[(size_t)(r0 + ty + i * 8) * GH + c0 + tx];
        __syncthreads();
#pragma unroll
        for (int i = 0; i < 4; ++i) {
            float v = tile[tx][ty + i * 8];
            unsigned short h = f2bf(v);
            size_t row = (size_t)(c0 + ty + i * 8) * 2048;
            w1cat[row + r0 + tx] = h;
            w1cat[row + 1024 + r0 + tx] = f2bf(v - bf2f(h));
        }
        return;
    }
    b -= 256;
    if (b < 64) {                         // cheap-dot weights -> w1cheap [64][hi|lo]
        const int r = b;
        const int k4 = tid * 4;
        float4 v = {0.f, 0.f, 0.f, 0.f};
        if (r < 2)       v = *reinterpret_cast<const float4*>(&p2_w[r * E + k4]);
        else if (r < 6)  v = *reinterpret_cast<const float4*>(&p4_w[(r - 2) * E + k4]);
        else if (r == 6) v = *reinterpret_cast<const float4*>(&rg_u[k4]);
        else if (r < 23) {
            const int j = r - 7;          // fl_dw is [E][16]: gather column j
            v.x = fl_dw[(k4 + 0) * 16 + j];
            v.y = fl_dw[(k4 + 1) * 16 + j];
            v.z = fl_dw[(k4 + 2) * 16 + j];
            v.w = fl_dw[(k4 + 3) * 16 + j];
        }
        ushort4 h, l;
        h.x = f2bf(v.x); l.x = f2bf(v.x - bf2f(h.x));
        h.y = f2bf(v.y); l.y = f2bf(v.y - bf2f(h.y));
        h.z = f2bf(v.z); l.z = f2bf(v.z - bf2f(h.z));
        h.w = f2bf(v.w); l.w = f2bf(v.w - bf2f(h.w));
        *reinterpret_cast<ushort4*>(&w1cheap[r * 2048 + k4]) = h;
        *reinterpret_cast<ushort4*>(&w1cheap[r * 2048 + 1024 + k4]) = l;
        return;
    }
    b -= 64;
    const float* src; unsigned short* dst; int R, C, nbx;
    if (b < 2048)      { src = dfc_w;   dst = dfc_wt; R = 1024; C = 2048; nbx = 64; }
    else if (b < 4096) { src = dproj_w; dst = dpj_wt; R = 2048; C = 1024; nbx = 32; b -= 2048; }
    else if (b < 5120) { src = sfc_w;   dst = sfc_wt; R = 1024; C = 1024; nbx = 32; b -= 4096; }
    else               { src = sproj_w; dst = spj_wt; R = 1024; C = 1024; nbx = 32; b -= 5120; }
    const int c0 = (b % nbx) * 32, r0 = (b / nbx) * 32;
#pragma unroll
    for (int i = 0; i < 4; ++i)
        tile[ty + i * 8][tx] = src[(size_t)(r0 + ty + i * 8) * C + c0 + tx];
    __syncthreads();
#pragma unroll
    for (int i = 0; i < 4; ++i)
        dst[(size_t)(c0 + ty + i * 8) * R + r0 + tx] = f2bf(tile[tx][ty + i * 8]);
}

// ------ gate partial GEMM: hp[c2] = A_z @ w1cat[:, h-half], 128x128 tiles ---
// Grid 512, 2 blocks/CU (LDS 64KB). BK=64, two sub-chunks per buffer,
// 16 barriers for K=1024. Cheap dots: every wave adds 2 MFMAs per sub-step.
__global__ __launch_bounds__(256)
void gate_partial_kernel(const unsigned short* __restrict__ xh,
                         const unsigned short* __restrict__ xl,
                         const unsigned short* __restrict__ w1cat,
                         const unsigned short* __restrict__ w1cheap,
                         float* __restrict__ hp,      // [4][NTOK][GH]
                         float* __restrict__ cdot) {  // [4][NTOK][NCH]
    __shared__ __align__(16) unsigned short As[2][128 * 64];   // 32 KB
    __shared__ __align__(16) unsigned short Bs[2][128 * 64];   // 32 KB
    const int tid = threadIdx.x;
    const int bid = blockIdx.x;
    const int xcd = bid & 7, slot = bid >> 3;
    const int nx = slot & 1;
    const int strip = xcd * 32 + (slot >> 1);      // [0,256)
    const int m = strip >> 2, c2 = strip & 3;
    const int z = c2 & 1, h = c2 >> 1;
    const int t0 = m * 128, n0 = nx * 128;
    const unsigned short* A = z ? xl : xh;
    float* hpz = hp + (size_t)c2 * ((size_t)NTOK * GH);
    float* cd  = cdot + (size_t)c2 * ((size_t)NTOK * NCH);

    const int lane = tid & 63, wv = tid >> 6;
    const int wr = wv >> 1, wc = wv & 1;
    const int lm = lane & 15, q = lane >> 4;
    const int r0 = tid >> 2, gsl = tid & 3;
    const int g = gsl ^ ((r0 >> 1) & 3);
    const int lbase = wv * 512;

    const unsigned short* pa0 = A + (size_t)(t0 + r0) * E + g * 8;
    const unsigned short* pa1 = A + (size_t)(t0 + 64 + r0) * E + g * 8;
    const unsigned short* pb0 = w1cat + (size_t)(n0 + r0) * 2048 + h * 1024 + g * 8;
    const unsigned short* pb1 = w1cat + (size_t)(n0 + 64 + r0) * 2048 + h * 1024 + g * 8;
    const unsigned short* pcw = w1cheap + (size_t)(nx * 16 + lm) * 2048 + h * 1024 + q * 8;

    f32x4 acc[4][4];
#pragma unroll
    for (int s = 0; s < 4; ++s)
#pragma unroll
        for (int t = 0; t < 4; ++t) acc[s][t] = (f32x4){0.f, 0.f, 0.f, 0.f};
    f32x4 accC[2];
    accC[0] = (f32x4){0.f, 0.f, 0.f, 0.f};
    accC[1] = (f32x4){0.f, 0.f, 0.f, 0.f};

    glds16(pa0, &As[0][lbase]);
    glds16(pa1, &As[0][2048 + lbase]);
    glds16(pa0 + 32, &As[0][4096 + lbase]);
    glds16(pa1 + 32, &As[0][4096 + 2048 + lbase]);
    glds16(pb0, &Bs[0][lbase]);
    glds16(pb1, &Bs[0][2048 + lbase]);
    glds16(pb0 + 32, &Bs[0][4096 + lbase]);
    glds16(pb1 + 32, &Bs[0][4096 + 2048 + lbase]);
    bf16x8 cf0 = *(const bf16x8*)pcw;
    bf16x8 cf1 = *(const bf16x8*)(pcw + 32);

    int cur = 0;
    for (int k0 = 0;; k0 += 64) {
        __syncthreads();                  // drains vmcnt -> buf[cur] landed
        const int kn = k0 + 64;
        bf16x8 cf0n, cf1n;
        if (kn < 1024) {
            glds16(pa0 + kn, &As[cur ^ 1][lbase]);
            glds16(pa1 + kn, &As[cur ^ 1][2048 + lbase]);
            glds16(pa0 + kn + 32, &As[cur ^ 1][4096 + lbase]);
            glds16(pa1 + kn + 32, &As[cur ^ 1][4096 + 2048 + lbase]);
            glds16(pb0 + kn, &Bs[cur ^ 1][lbase]);
            glds16(pb1 + kn, &Bs[cur ^ 1][2048 + lbase]);
            glds16(pb0 + kn + 32, &Bs[cur ^ 1][4096 + lbase]);
            glds16(pb1 + kn + 32, &Bs[cur ^ 1][4096 + 2048 + lbase]);
            cf0n = *(const bf16x8*)(pcw + kn);
            cf1n = *(const bf16x8*)(pcw + kn + 32);
        }
#pragma unroll
        for (int sub = 0; sub < 2; ++sub) {
            const int off = sub * 4096;
            bf16x8 af[4], bfr[4];
#pragma unroll
            for (int s = 0; s < 4; ++s) af[s] = *(const bf16x8*)&As[cur][off + ldso(wr * 64 + s * 16 + lm, q)];
#pragma unroll
            for (int t = 0; t < 4; ++t) bfr[t] = *(const bf16x8*)&Bs[cur][off + ldso(wc * 64 + t * 16 + lm, q)];
#pragma unroll
            for (int s = 0; s < 4; ++s)
#pragma unroll
                for (int t = 0; t < 4; ++t)
                    acc[s][t] = __builtin_amdgcn_mfma_f32_16x16x32_bf16(af[s], bfr[t], acc[s][t], 0, 0, 0);
            bf16x8 cf = sub ? cf1 : cf0;
            bf16x8 ac0 = wc ? af[2] : af[0];
            bf16x8 ac1 = wc ? af[3] : af[1];
            accC[0] = __builtin_amdgcn_mfma_f32_16x16x32_bf16(ac0, cf, accC[0], 0, 0, 0);
            accC[1] = __builtin_amdgcn_mfma_f32_16x16x32_bf16(ac1, cf, accC[1], 0, 0, 0);
        }
        if (kn >= 1024) break;
        cf0 = cf0n; cf1 = cf1n; cur ^= 1;
    }
#pragma unroll
    for (int s = 0; s < 4; ++s)
#pragma unroll
        for (int t = 0; t < 4; ++t)
#pragma unroll
            for (int rg = 0; rg < 4; ++rg) {
                int rl = wr * 64 + s * 16 + q * 4 + rg;
                int c  = wc * 64 + t * 16 + lm;
                hpz[(size_t)(t0 + rl) * GH + n0 + c] = acc[s][t][rg];
            }
    const int cc = nx * 16 + lm;
    if (cc < NCH) {
#pragma unroll
        for (int i = 0; i < 2; ++i)
#pragma unroll
            for (int rg = 0; rg < 4; ++rg) {
                int rl = wr * 64 + wc * 32 + i * 16 + q * 4 + rg;
                cd[(size_t)(t0 + rl) * NCH + cc] = accC[i][rg];
            }
    }
}

// ------- finalize: h=gelu(sum4 hp+gb1); logits=h@gw2; softmax/argmax --------
// Also converts summed cheap dots (4 partials) into gate scalars gvec[NCH].
__global__ __launch_bounds__(256)
void gate_finalize_kernel(const float* __restrict__ hp,    // [4][NTOK][GH]
                          const float* __restrict__ gb1, const float* __restrict__ gw2,
                          const float* __restrict__ gb2, const float* __restrict__ ebias,
                          const float* __restrict__ pm_alpha,
                          const float* __restrict__ cdot,  // [4][NTOK][NCH]
                          const float* __restrict__ p2_alpha, const float* __restrict__ p2_b,
                          const float* __restrict__ p4_alpha, const float* __restrict__ p4_b,
                          const float* __restrict__ rg_b, const float* __restrict__ fl_db,
                          float* __restrict__ scale, int* __restrict__ counts,
                          int* __restrict__ tlist, int* __restrict__ eid,
                          float* __restrict__ gvec) {
    __shared__ float hs[32][264];
    __shared__ float g2s[GH * NEXP];
    __shared__ int tokexp[32];
    const int tid = threadIdx.x;
    const int t0 = blockIdx.x * 32;
    const size_t HPS = (size_t)NTOK * GH;
    for (int i = tid; i < GH * NEXP; i += 256) g2s[i] = gw2[i];
#pragma unroll
    for (int i = 0; i < 8; ++i) {
        int f4 = i * 256 + tid;
        int row = f4 >> 6, c4 = (f4 & 63) * 4;
        size_t base = (size_t)(t0 + row) * GH + c4;
        float4 a = *reinterpret_cast<const float4*>(&hp[base]);
        float4 b = *reinterpret_cast<const float4*>(&hp[HPS + base]);
        float4 c = *reinterpret_cast<const float4*>(&hp[2 * HPS + base]);
        float4 d = *reinterpret_cast<const float4*>(&hp[3 * HPS + base]);
        float4 o;
        o.x = gelu_erf(a.x + b.x + c.x + d.x + gb1[c4 + 0]);
        o.y = gelu_erf(a.y + b.y + c.y + d.y + gb1[c4 + 1]);
        o.z = gelu_erf(a.z + b.z + c.z + d.z + gb1[c4 + 2]);
        o.w = gelu_erf(a.w + b.w + c.w + d.w + gb1[c4 + 3]);
        *reinterpret_cast<float4*>(&hs[row][c4]) = o;
    }
    __syncthreads();
    const int t = tid >> 3, j = tid & 7;
    float p[NEXP] = {0.f, 0.f, 0.f, 0.f, 0.f, 0.f};
#pragma unroll 8
    for (int kk = 0; kk < 32; ++kk) {
        int k = j + kk * 8;
        float hv = hs[t][k];
        const float* gr = &g2s[k * NEXP];
#pragma unroll
        for (int m = 0; m < NEXP; ++m) p[m] += hv * gr[m];
    }
#pragma unroll
    for (int m = 0; m < NEXP; ++m) {
        p[m] += __shfl_xor(p[m], 4, 64);
        p[m] += __shfl_xor(p[m], 2, 64);
        p[m] += __shfl_xor(p[m], 1, 64);
    }
    if (j == 0) {
        float L[NEXP];
#pragma unroll
        for (int m = 0; m < NEXP; ++m) L[m] = p[m] + gb2[m] + ebias[m];
        float mx = L[0]; int am = 0;
#pragma unroll
        for (int m = 1; m < NEXP; ++m) { if (L[m] > mx) { mx = L[m]; am = m; } }
        float S = 0.f;
#pragma unroll
        for (int m = 0; m < NEXP; ++m) S += expf(L[m] - mx);
        float pt = 1.f / S;
        scale[t0 + t] = pm_alpha[0] * (pt / (pt + 1e-9f));
        eid[t0 + t] = am;
        tokexp[t] = am;
    }
    __syncthreads();
    if (tid < NEXP) {
        const int e = tid;
        int cnt = 0;
#pragma unroll
        for (int i = 0; i < 32; ++i) cnt += (tokexp[i] == e);
        if (cnt) {
            int base = atomicAdd(&counts[e], cnt);
            int pos = 0;
#pragma unroll
            for (int i = 0; i < 32; ++i)
                if (tokexp[i] == e) tlist[e * NTOK + base + (pos++)] = t0 + i;
        }
    }
    // ---- per-token cheap-gate scalars (independent of the above) ----
    const size_t CDS = (size_t)NTOK * NCH;
    for (int i = tid; i < 32 * NCH; i += 256) {
        const int tt = i / NCH, slot = i - tt * NCH;
        const int tok = t0 + tt;
        size_t idx = (size_t)tok * NCH + slot;
        float s = cdot[idx] + cdot[CDS + idx] + cdot[2 * CDS + idx] + cdot[3 * CDS + idx];
        float val;
        if (slot < 2)       val = p2_alpha[slot] * gelu_erf(s + p2_b[slot]);
        else if (slot < 6)  val = p4_alpha[slot - 2] * gelu_erf(s + p4_b[slot - 2]);
        else if (slot == 6) val = 1.f / (1.f + expf(-(s + rg_b[0])));
        else if (slot < 23) val = gelu_erf(s + fl_db[slot - 7]);
        else                val = 0.f;
        gvec[(size_t)tok * NCH + slot] = val;
    }
}

// ---- depth-3 counted-vmcnt pipelined staging: 4 glds16 per tile per thread.
#define STAGEAB(t, jb)                                            \
    do {                                                          \
        glds16(pa + (t) * 64,      &As[jb][lbase]);               \
        glds16(pa + (t) * 64 + 32, &As[jb][2048 + lbase]);        \
        glds16(pb + (t) * 64,      &Bs[jb][lbase]);               \
        glds16(pb + (t) * 64 + 32, &Bs[jb][2048 + lbase]);        \
    } while (0)

// ---------------- GEMM1: gather x_hi -> gelu -> packed bf16 h ---------------
// Grid 2048 (r14 decode). 64x64 tiles, BK=64, 3 LDS buffers (48KB),
// s_waitcnt vmcnt(8/4/0) + raw s_barrier: 2 tiles stay in flight across
// barriers instead of draining to 0 (the r13-r18 ~58us latency stall).
__global__ __launch_bounds__(256)
void moe_gemm1_kernel(const unsigned short* __restrict__ xh,
                      const unsigned short* __restrict__ B0, const unsigned short* __restrict__ B1,
                      const float* __restrict__ bias0, const float* __restrict__ bias1,
                      const int* __restrict__ counts, const int* __restrict__ tlist,
                      unsigned short* __restrict__ H0, unsigned short* __restrict__ H1) {
    __shared__ __align__(16) unsigned short As[3][64 * 64];   // 24 KB
    __shared__ __align__(16) unsigned short Bs[3][64 * 64];   // 24 KB
    __shared__ int toks[64];
    const int tid = threadIdx.x;
    const int bid = blockIdx.x;
    const int xcd = bid & 7, slot = bid >> 3;      // [0,256)
    const int nx = slot & 31;
    const int strip = xcd + 8 * (slot >> 5);       // [0,64), XCD-strided
    const int z = strip & 1;
    const int N = z ? 1024 : 2048;
    const int cnt = counts[z];
    const int i0 = (strip >> 1) * 64;
    const int n0 = nx * 64;
    if (i0 >= cnt || n0 >= N) return;
    const unsigned short* Bz = z ? B1 : B0;
    const float* bias = z ? bias1 : bias0;

    if (tid < 64) toks[tid] = tlist[z * NTOK + min(i0 + tid, cnt - 1)];
    __syncthreads();

    const int lane = tid & 63, wv = tid >> 6;
    const int wm = (wv & 1) * 32, wn = (wv >> 1) * 32;
    const int lm = lane & 15, q = lane >> 4;
    const int r0 = tid >> 2, gsl = tid & 3;
    const int g = gsl ^ ((r0 >> 1) & 3);
    const int lbase = wv * 512;

    const unsigned short* pa = xh + (size_t)toks[r0] * E + g * 8;
    const unsigned short* pb = Bz + (size_t)(n0 + r0) * E + g * 8;

    f32x4 acc[2][2];
#pragma unroll
    for (int s = 0; s < 2; ++s)
#pragma unroll
        for (int t = 0; t < 2; ++t) acc[s][t] = (f32x4){0.f, 0.f, 0.f, 0.f};

    STAGEAB(0, 0); STAGEAB(1, 1); STAGEAB(2, 2);

    const int nt = E / 64;                        // 16
    for (int i = 0; i < nt; ++i) {
        const int ahead = nt - 1 - i;
        if (ahead >= 2)      asm volatile("s_waitcnt vmcnt(8)" ::: "memory");
        else if (ahead == 1) asm volatile("s_waitcnt vmcnt(4)" ::: "memory");
        else                 asm volatile("s_waitcnt vmcnt(0)" ::: "memory");
        asm volatile("s_barrier" ::: "memory");   // all waves: tile i landed
        const int jb = i % 3;
#pragma unroll
        for (int sub = 0; sub < 2; ++sub) {
            const int off = sub * 2048;
            bf16x8 af[2], bfr[2];
#pragma unroll
            for (int s = 0; s < 2; ++s) af[s] = *(const bf16x8*)&As[jb][off + ldso(wm + s * 16 + lm, q)];
#pragma unroll
            for (int t = 0; t < 2; ++t) bfr[t] = *(const bf16x8*)&Bs[jb][off + ldso(wn + t * 16 + lm, q)];
#pragma unroll
            for (int s = 0; s < 2; ++s)
#pragma unroll
                for (int t = 0; t < 2; ++t)
                    acc[s][t] = __builtin_amdgcn_mfma_f32_16x16x32_bf16(af[s], bfr[t], acc[s][t], 0, 0, 0);
        }
        asm volatile("s_barrier" ::: "memory");   // all waves done reading buf
        if (i + 3 < nt) STAGEAB(i + 3, jb);
    }
    unsigned short* Hz = z ? H1 : H0;
#pragma unroll
    for (int s = 0; s < 2; ++s)
#pragma unroll
        for (int t = 0; t < 2; ++t)
#pragma unroll
            for (int rg = 0; rg < 4; ++rg) {
                int rl = wm + s * 16 + q * 4 + rg;
                int gc = n0 + wn + t * 16 + lm;
                float v = acc[s][t][rg] + bias[gc];
                Hz[(size_t)(i0 + rl) * N + gc] = f2bf(gelu_erf(v));
            }
}

// ---------------- GEMM2 (experts 0/1 down-proj), pure GEMM ------------------
// Grid 1024. 64x64 tiles, BK=64, depth-3 counted-vmcnt pipeline (48KB LDS).
__global__ __launch_bounds__(256)
void moe_gemm2_kernel(const unsigned short* __restrict__ h1, const unsigned short* __restrict__ h2,
                      const unsigned short* __restrict__ dpj, const unsigned short* __restrict__ spj,
                      const float* __restrict__ dproj_b, const float* __restrict__ sproj_b,
                      const int* __restrict__ counts, const int* __restrict__ tlist,
                      const float* __restrict__ scale,
                      float* __restrict__ out) {
    __shared__ __align__(16) unsigned short As[3][64 * 64];   // 24 KB
    __shared__ __align__(16) unsigned short Bs[3][64 * 64];   // 24 KB
    __shared__ int toks[64];
    const int tid = threadIdx.x;
    const int bb = blockIdx.x;
    const int lane = tid & 63;

    const int xcd = bb & 7, slot = bb >> 3;    // [0,128)
    const int nx = slot & 15;
    const int strip = xcd + 8 * (slot >> 4);   // [0,64)
    const int z = strip & 1;
    const int i0 = (strip >> 1) * 64;
    const int n0 = nx * 64;
    const int K = z ? 1024 : 2048;
    const int cnt = counts[z];
    if (i0 >= cnt) return;
    const int rows = min(64, cnt - i0);
    const unsigned short* Az = z ? h2 : h1;
    const unsigned short* Bz = z ? spj : dpj;
    const float* bias = z ? sproj_b : dproj_b;

    if (tid < 64) toks[tid] = tlist[z * NTOK + min(i0 + tid, cnt - 1)];
    __syncthreads();

    const int wv = tid >> 6;
    const int wm = (wv & 1) * 32, wn = (wv >> 1) * 32;
    const int lm = lane & 15, q = lane >> 4;
    const int r0 = tid >> 2, gsl = tid & 3;
    const int g = gsl ^ ((r0 >> 1) & 3);
    const int lbase = wv * 512;

    const unsigned short* pa = Az + (size_t)(i0 + r0) * K + g * 8;
    const unsigned short* pb = Bz + (size_t)(n0 + r0) * K + g * 8;

    f32x4 acc[2][2];
#pragma unroll
    for (int s = 0; s < 2; ++s)
#pragma unroll
        for (int t = 0; t < 2; ++t) acc[s][t] = (f32x4){0.f, 0.f, 0.f, 0.f};

    STAGEAB(0, 0); STAGEAB(1, 1); STAGEAB(2, 2);

    const int nt = K / 64;                        // 16 or 32
    for (int i = 0; i < nt; ++i) {
        const int ahead = nt - 1 - i;
        if (ahead >= 2)      asm volatile("s_waitcnt vmcnt(8)" ::: "memory");
        else if (ahead == 1) asm volatile("s_waitcnt vmcnt(4)" ::: "memory");
        else                 asm volatile("s_waitcnt vmcnt(0)" ::: "memory");
        asm volatile("s_barrier" ::: "memory");
        const int jb = i % 3;
#pragma unroll
        for (int sub = 0; sub < 2; ++sub) {
            const int off = sub * 2048;
            bf16x8 af[2], bfr[2];
#pragma unroll
            for (int s = 0; s < 2; ++s) af[s] = *(const bf16x8*)&As[jb][off + ldso(wm + s * 16 + lm, q)];
#pragma unroll
            for (int t = 0; t < 2; ++t) bfr[t] = *(const bf16x8*)&Bs[jb][off + ldso(wn + t * 16 + lm, q)];
#pragma unroll
            for (int s = 0; s < 2; ++s)
#pragma unroll
                for (int t = 0; t < 2; ++t)
                    acc[s][t] = __builtin_amdgcn_mfma_f32_16x16x32_bf16(af[s], bfr[t], acc[s][t], 0, 0, 0);
        }
        asm volatile("s_barrier" ::: "memory");
        if (i + 3 < nt) STAGEAB(i + 3, jb);
    }
#pragma unroll
    for (int s = 0; s < 2; ++s)
#pragma unroll
        for (int t = 0; t < 2; ++t)
#pragma unroll
            for (int rg = 0; rg < 4; ++rg) {
                int rl = wm + s * 16 + q * 4 + rg;
                if (rl < rows) {
                    int gc = n0 + wn + t * 16 + lm;
                    int tok = toks[rl];
                    out[(size_t)tok * E + gc] = scale[tok] * (acc[s][t][rg] + bias[gc]);
                }
            }
}

// ---------------- cheap experts (2..5): batched 8-token tiles ---------------
// Grid 2048, tiny LDS. Slot s in [0,4096): e = 2+(s&3), ti = s>>2.
// Tokens expert-sorted from tlist -> no eid read, no divergence in a block.
// FiLM j-outer with 8-token register accumulators (fl_uw once per tile).
__global__ __launch_bounds__(256)
void cheap_kernel(const int* __restrict__ counts, const int* __restrict__ tlist,
                  const float* __restrict__ scale, const float* __restrict__ x,
                  const float* __restrict__ gvec,
                  const float* __restrict__ p2_v, const float* __restrict__ p2_bias,
                  const float* __restrict__ p4_v, const float* __restrict__ p4_bias,
                  const float* __restrict__ rg_a, const float* __restrict__ rg_bias,
                  const float* __restrict__ fl_uw, const float* __restrict__ fl_ub,
                  float* __restrict__ out) {
    __shared__ int stoks[8];
    __shared__ float ssc[8];
    __shared__ float sgv[8][17];
    const int tid = threadIdx.x;
    const int k4 = tid * 4;
    for (int s = blockIdx.x; s < 4096; s += 2048) {
        const int e = 2 + (s & 3);
        const int ti = s >> 2;
        const int cnt = counts[e];
        const int i0 = ti * 8;
        if (i0 >= cnt) continue;
        const int nt = min(8, cnt - i0);
        __syncthreads();                       // LDS reuse guard across strides
        if (tid < 128) {
            const int tt = tid >> 4, sl = tid & 15;
            const int tk = tlist[e * NTOK + min(i0 + tt, cnt - 1)];
            if (sl == 0) { stoks[tt] = tk; ssc[tt] = scale[tk]; }
            const int base = (e == 2) ? 0 : (e == 3) ? 2 : (e == 4) ? 6 : 7;
            const int ng   = (e == 2) ? 2 : (e == 3) ? 4 : (e == 4) ? 1 : 16;
            if (sl < ng) sgv[tt][sl] = gvec[(size_t)tk * NCH + base + sl];
        }
        __syncthreads();
        if (e == 2) {
            const float4 b0 = *reinterpret_cast<const float4*>(&p2_bias[k4]);
            const float4 v0 = *reinterpret_cast<const float4*>(&p2_v[k4]);
            const float4 v1 = *reinterpret_cast<const float4*>(&p2_v[E + k4]);
#pragma unroll
            for (int tt = 0; tt < 8; ++tt) {
                if (tt < nt) {
                    const float g0 = sgv[tt][0], g1 = sgv[tt][1], sc = ssc[tt];
                    float4 o;
                    o.x = (b0.x + g0 * v0.x + g1 * v1.x) * sc;
                    o.y = (b0.y + g0 * v0.y + g1 * v1.y) * sc;
                    o.z = (b0.z + g0 * v0.z + g1 * v1.z) * sc;
                    o.w = (b0.w + g0 * v0.w + g1 * v1.w) * sc;
                    *reinterpret_cast<float4*>(&out[(size_t)stoks[tt] * E + k4]) = o;
                }
            }
        } else if (e == 3) {
            const float4 b0 = *reinterpret_cast<const float4*>(&p4_bias[k4]);
            float4 vv[4];
#pragma unroll
            for (int j = 0; j < 4; ++j)
                vv[j] = *reinterpret_cast<const float4*>(&p4_v[j * E + k4]);
#pragma unroll
            for (int tt = 0; tt < 8; ++tt) {
                if (tt < nt) {
                    float4 o = b0;
#pragma unroll
                    for (int j = 0; j < 4; ++j) {
                        const float gj = sgv[tt][j];
                        o.x += gj * vv[j].x; o.y += gj * vv[j].y;
                        o.z += gj * vv[j].z; o.w += gj * vv[j].w;
                    }
                    const float sc = ssc[tt];
                    o.x *= sc; o.y *= sc; o.z *= sc; o.w *= sc;
                    *reinterpret_cast<float4*>(&out[(size_t)stoks[tt] * E + k4]) = o;
                }
            }
        } else if (e == 4) {
            const float4 av = *reinterpret_cast<const float4*>(&rg_a[k4]);
            const float4 bv = *reinterpret_cast<const float4*>(&rg_bias[k4]);
#pragma unroll
            for (int tt = 0; tt < 8; ++tt) {
                if (tt < nt) {
                    const float sg = sgv[tt][0], sc = ssc[tt];
                    const float4 xv = *reinterpret_cast<const float4*>(&x[(size_t)stoks[tt] * E + k4]);
                    float4 o;
                    o.x = (sg * xv.x * av.x + bv.x) * sc;
                    o.y = (sg * xv.y * av.y + bv.y) * sc;
                    o.z = (sg * xv.z * av.z + bv.z) * sc;
                    o.w = (sg * xv.w * av.w + bv.w) * sc;
                    *reinterpret_cast<float4*>(&out[(size_t)stoks[tt] * E + k4]) = o;
                }
            }
        } else {  // FiLM: j-outer, 8-token register accumulators
            float4 ga[8], be[8];
            const float4 g0 = *reinterpret_cast<const float4*>(&fl_ub[k4]);
            const float4 b0 = *reinterpret_cast<const float4*>(&fl_ub[E + k4]);
#pragma unroll
            for (int tt = 0; tt < 8; ++tt) { ga[tt] = g0; be[tt] = b0; }
#pragma unroll
            for (int j = 0; j < 16; ++j) {
                const float4 ug = *reinterpret_cast<const float4*>(&fl_uw[(size_t)j * 2 * E + k4]);
                const float4 ub = *reinterpret_cast<const float4*>(&fl_uw[(size_t)j * 2 * E + E + k4]);
#pragma unroll
                for (int tt = 0; tt < 8; ++tt) {
                    const float tj = sgv[tt][j];
                    ga[tt].x += tj * ug.x; ga[tt].y += tj * ug.y;
                    ga[tt].z += tj * ug.z; ga[tt].w += tj * ug.w;
                    be[tt].x += tj * ub.x; be[tt].y += tj * ub.y;
                    be[tt].z += tj * ub.z; be[tt].w += tj * ub.w;
                }
            }
#pragma unroll
            for (int tt = 0; tt < 8; ++tt) {
                if (tt < nt) {
                    const float sc = ssc[tt];
                    const float4 xv = *reinterpret_cast<const float4*>(&x[(size_t)stoks[tt] * E + k4]);
                    float4 o;
                    o.x = (ga[tt].x * xv.x + be[tt].x) * sc;
                    o.y = (ga[tt].y * xv.y + be[tt].y) * sc;
                    o.z = (ga[tt].z * xv.z + be[tt].z) * sc;
                    o.w = (ga[tt].w * xv.w + be[tt].w) * sc;
                    *reinterpret_cast<float4*>(&out[(size_t)stoks[tt] * E + k4]) = o;
                }
            }
        }
    }
}

extern "C" void kernel_launch(void* const* d_in, const int* in_sizes, int n_in,
                              void* d_out, int out_size, void* d_ws, size_t ws_size,
                              hipStream_t stream) {
    const float* x        = (const float*)d_in[0];
    const float* gw1      = (const float*)d_in[1];
    const float* gb1      = (const float*)d_in[2];
    const float* gw2      = (const float*)d_in[3];
    const float* gb2      = (const float*)d_in[4];
    const float* ebias    = (const float*)d_in[5];
    const float* pm_alpha = (const float*)d_in[6];
    const float* dfc_w    = (const float*)d_in[7];
    const float* dfc_b    = (const float*)d_in[8];
    const float* dproj_w  = (const float*)d_in[9];
    const float* dproj_b  = (const float*)d_in[10];
    const float* sfc_w    = (const float*)d_in[11];
    const float* sfc_b    = (const float*)d_in[12];
    const float* sproj_w  = (const float*)d_in[13];
    const float* sproj_b  = (const float*)d_in[14];
    const float* p2_w     = (const float*)d_in[15];
    const float* p2_v     = (const float*)d_in[16];
    const float* p2_alpha = (const float*)d_in[17];
    const float* p2_b     = (const float*)d_in[18];
    const float* p2_bias  = (const float*)d_in[19];
    const float* p4_w     = (const float*)d_in[20];
    const float* p4_v     = (const float*)d_in[21];
    const float* p4_alpha = (const float*)d_in[22];
    const float* p4_b     = (const float*)d_in[23];
    const float* p4_bias  = (const float*)d_in[24];
    const float* rg_u     = (const float*)d_in[25];
    const float* rg_a     = (const float*)d_in[26];
    const float* rg_b     = (const float*)d_in[27];
    const float* rg_bias  = (const float*)d_in[28];
    const float* fl_dw    = (const float*)d_in[29];
    const float* fl_db    = (const float*)d_in[30];
    const float* fl_uw    = (const float*)d_in[31];
    const float* fl_ub    = (const float*)d_in[32];
    float* out = (float*)d_out;

    char* ws = (char*)d_ws;
    size_t off = 0;
    int*            counts = (int*)(ws + off);            off += 256;
    float*          scale  = (float*)(ws + off);          off += (size_t)NTOK * 4;
    int*            tlist  = (int*)(ws + off);            off += (size_t)NEXP * NTOK * 4;
    int*            eid    = (int*)(ws + off);            off += (size_t)NTOK * 4;
    float*          gvec   = (float*)(ws + off);          off += (size_t)NTOK * NCH * 4;
    float*          cdot   = (float*)(ws + off);          off += (size_t)4 * NTOK * NCH * 4;
    unsigned short* w1cheap= (unsigned short*)(ws + off); off += (size_t)64 * 2048 * 2;
    unsigned short* w1cat  = (unsigned short*)(ws + off); off += (size_t)GH * 2048 * 2;
    unsigned short* dfc_wt = (unsigned short*)(ws + off); off += (size_t)2048 * 1024 * 2;
    unsigned short* dpj_wt = (unsigned short*)(ws + off); off += (size_t)1024 * 2048 * 2;
    unsigned short* sfc_wt = (unsigned short*)(ws + off); off += (size_t)1024 * 1024 * 2;
    unsigned short* spj_wt = (unsigned short*)(ws + off); off += (size_t)1024 * 1024 * 2;
    unsigned short* x_hi   = (unsigned short*)(ws + off); off += (size_t)NTOK * E * 2;
    // Union region: gate phase {x_lo} then expert phase {h1, h2}
    char* U = ws + off;
    unsigned short* x_lo = (unsigned short*)U;                              // 16 MB
    unsigned short* h1   = (unsigned short*)U;                              // 16 MB (2048 x 2048)
    unsigned short* h2   = (unsigned short*)(U + (size_t)16 * 1024 * 1024); // 8 MB (2048 x 1024)
    // 4 hp partials (4 x 8 MB = 32 MB) live in d_out (dead after finalize,
    // before gemm2/cheap rewrite every token row).
    float* hp = out;

    hipMemsetAsync(counts, 0, 256, stream);
    prep_kernel<<<8512, 256, 0, stream>>>(x, x_hi, x_lo, gw1, w1cat,
                                          p2_w, p4_w, rg_u, fl_dw, w1cheap,
                                          dfc_w, dfc_wt, dproj_w, dpj_wt,
                                          sfc_w, sfc_wt, sproj_w, spj_wt);
    gate_partial_kernel<<<512, 256, 0, stream>>>(
        x_hi, x_lo, w1cat, w1cheap, hp, cdot);
    gate_finalize_kernel<<<NTOK / 32, 256, 0, stream>>>(
        hp, gb1, gw2, gb2, ebias, pm_alpha, cdot,
        p2_alpha, p2_b, p4_alpha, p4_b, rg_b, fl_db,
        scale, counts, tlist, eid, gvec);
    // y: 32 x 64-row tiles = 2048 rows per expert (mean+20sigma of counts)
    moe_gemm1_kernel<<<2048, 256, 0, stream>>>(
        x_hi, dfc_wt, sfc_wt, dfc_b, sfc_b, counts, tlist, h1, h2);
    moe_gemm2_kernel<<<1024, 256, 0, stream>>>(
        h1, h2, dpj_wt, spj_wt, dproj_b, sproj_b, counts, tlist, scale, out);
    cheap_kernel<<<2048, 256, 0, stream>>>(
        counts, tlist, scale, x, gvec,
        p2_v, p2_bias, p4_v, p4_bias,
        rg_a, rg_bias, fl_uw, fl_ub, out);
    (void)in_sizes; (void)n_in; (void)out_size; (void)ws_size;
}

// Round 9
// 260.205 us; speedup vs baseline: 1.2693x; 1.0897x over previous
//
#include <hip/hip_runtime.h>
#include <math.h>

// Top-1 MoE, 6-dispatch pipeline.
//   memset -> prep -> gate_partial -> gate_finalize -> gemm1+coefgemm -> gemm2.
// r13: cheap-expert dots ride gate_partial's MFMA.
// r14: XCD-chunked swizzle on all MFMA GEMMs.
// r15: gate_partial 128x128 tiles + global_load_lds dbuf.
// r19: depth-3 counted-vmcnt pipeline on gemm1/gemm2 (GEMMs left top-5).
// r20: cheap experts (2..5) are a rank-27 linear map: out=(mul.x+add)*scale,
// [add|mul] = c(token) @ Basis27. The scalar cheap_kernel was pinned at
// ~50us (MfmaUtil 0, Occ 5.5%, 33MB moved -- pure gather-latency). Replaced
// by a dense MFMA coefficient-GEMM (M=8192,N=1024,K=64 hi|lo, dual-B) fused
// into gemm1's dispatch, writing ALL tokens (zero coeffs for e0/e1) which
// gemm2 then overwrites. prep builds Bt_add/Bt_mul bf16; finalize emits
// Cm[8192][64] bf16 hi|lo instead of gvec.

#define E 1024
#define GH 256
#define NEXP 6
#define NTOK 8192
#define NCH 24   // cheap-dot cols: 2 p2 + 4 p4 + 1 rg + 16 film + 1 pad

typedef __attribute__((ext_vector_type(8))) short bf16x8;
typedef __attribute__((ext_vector_type(4))) float f32x4;

__device__ __forceinline__ float gelu_erf(float v) {
    return 0.5f * v * (1.0f + erff(v * 0.70710678118654752440f));
}

__device__ __forceinline__ unsigned short f2bf(float f) {
    union { float f; unsigned u; } c; c.f = f;
    unsigned u = c.u;
    u += 0x7fffu + ((u >> 16) & 1u);   // RNE
    return (unsigned short)(u >> 16);
}

__device__ __forceinline__ float bf2f(unsigned short h) {
    union { unsigned u; float f; } c; c.u = ((unsigned)h) << 16;
    return c.f;
}

// LDS tile addressing (ushort units) within a [rows][32] sub-tile:
// row stride 32 (=64B), k-group XOR swizzle.
__device__ __forceinline__ int ldso(int row, int q) {
    return row * 32 + ((q ^ ((row >> 1) & 3)) << 3);
}

// async global->LDS, 16B per lane; lds dest is wave-uniform base + lane*16.
__device__ __forceinline__ void glds16(const void* g, void* l) {
    __builtin_amdgcn_global_load_lds(
        (const __attribute__((address_space(1))) void*)g,
        (__attribute__((address_space(3))) void*)l, 16, 0, 0);
}

// ---------------- prep: convert + all transposes, one kernel ----------------
__global__ __launch_bounds__(256)
void prep_kernel(const float* __restrict__ x, unsigned short* __restrict__ xh,
                 unsigned short* __restrict__ xl,
                 const float* __restrict__ gw1, unsigned short* __restrict__ w1cat,
                 const float* __restrict__ p2_w, const float* __restrict__ p4_w,
                 const float* __restrict__ rg_u, const float* __restrict__ fl_dw,
                 unsigned short* __restrict__ w1cheap,
                 const float* __restrict__ p2_bias, const float* __restrict__ p2_v,
                 const float* __restrict__ p4_bias, const float* __restrict__ p4_v,
                 const float* __restrict__ rg_a, const float* __restrict__ rg_bias,
                 const float* __restrict__ fl_uw, const float* __restrict__ fl_ub,
                 unsigned short* __restrict__ bta, unsigned short* __restrict__ btm,
                 const float* __restrict__ dfc_w, unsigned short* __restrict__ dfc_wt,
                 const float* __restrict__ dproj_w, unsigned short* __restrict__ dpj_wt,
                 const float* __restrict__ sfc_w, unsigned short* __restrict__ sfc_wt,
                 const float* __restrict__ sproj_w, unsigned short* __restrict__ spj_wt) {
    __shared__ float tile[32][33];
    const int tid = threadIdx.x;
    const int tx = tid & 31, ty = tid >> 5;
    int b = blockIdx.x;
    if (b < 2048) {                       // x -> x_hi + x_lo
        const int n4 = NTOK * E / 4;
        for (int i = b * 256 + tid; i < n4; i += 2048 * 256) {
            float4 v = reinterpret_cast<const float4*>(x)[i];
            ushort4 h, l;
            h.x = f2bf(v.x); l.x = f2bf(v.x - bf2f(h.x));
            h.y = f2bf(v.y); l.y = f2bf(v.y - bf2f(h.y));
            h.z = f2bf(v.z); l.z = f2bf(v.z - bf2f(h.z));
            h.w = f2bf(v.w); l.w = f2bf(v.w - bf2f(h.w));
            reinterpret_cast<ushort4*>(xh)[i] = h;
            reinterpret_cast<ushort4*>(xl)[i] = l;
        }
        return;
    }
    b -= 2048;
    if (b < 256) {                        // gw1 [E][GH] -> w1cat [GH][hi|lo]
        const int c0 = (b & 7) * 32, r0 = (b >> 3) * 32;
#pragma unroll
        for (int i = 0; i < 4; ++i)
            tile[ty + i * 8][tx] = gw1[(size_t)(r0 + ty + i * 8) * GH + c0 + tx];
        __syncthreads();
#pragma unroll
        for (int i = 0; i < 4; ++i) {
            float v = tile[tx][ty + i * 8];
            unsigned short h = f2bf(v);
            size_t row = (size_t)(c0 + ty + i * 8) * 2048;
            w1cat[row + r0 + tx] = h;
            w1cat[row + 1024 + r0 + tx] = f2bf(v - bf2f(h));
        }
        return;
    }
    b -= 256;
    if (b < 64) {                         // cheap-dot weights -> w1cheap [64][hi|lo]
        const int r = b;
        const int k4 = tid * 4;
        float4 v = {0.f, 0.f, 0.f, 0.f};
        if (r < 2)       v = *reinterpret_cast<const float4*>(&p2_w[r * E + k4]);
        else if (r < 6)  v = *reinterpret_cast<const float4*>(&p4_w[(r - 2) * E + k4]);
        else if (r == 6) v = *reinterpret_cast<const float4*>(&rg_u[k4]);
        else if (r < 23) {
            const int j = r - 7;          // fl_dw is [E][16]: gather column j
            v.x = fl_dw[(k4 + 0) * 16 + j];
            v.y = fl_dw[(k4 + 1) * 16 + j];
            v.z = fl_dw[(k4 + 2) * 16 + j];
            v.w = fl_dw[(k4 + 3) * 16 + j];
        }
        ushort4 h, l;
        h.x = f2bf(v.x); l.x = f2bf(v.x - bf2f(h.x));
        h.y = f2bf(v.y); l.y = f2bf(v.y - bf2f(h.y));
        h.z = f2bf(v.z); l.z = f2bf(v.z - bf2f(h.z));
        h.w = f2bf(v.w); l.w = f2bf(v.w - bf2f(h.w));
        *reinterpret_cast<ushort4*>(&w1cheap[r * 2048 + k4]) = h;
        *reinterpret_cast<ushort4*>(&w1cheap[r * 2048 + 1024 + k4]) = l;
        return;
    }
    b -= 64;
    if (b < 4) {                          // cheap basis: Bt_add/Bt_mul [1024][64]
        const int n = b * 256 + tid;      // output column in [0, E)
        float av[32], mv[32];
#pragma unroll
        for (int r = 0; r < 32; ++r) { av[r] = 0.f; mv[r] = 0.f; }
        av[0] = p2_bias[n];
        av[1] = p2_v[n]; av[2] = p2_v[E + n];
        av[3] = p4_bias[n];
#pragma unroll
        for (int j = 0; j < 4; ++j) av[4 + j] = p4_v[j * E + n];
        av[8] = rg_bias[n];
        mv[9] = rg_a[n];
        av[10] = fl_ub[E + n];            // beta const
        mv[10] = fl_ub[n];                // gamma const
#pragma unroll
        for (int j = 0; j < 16; ++j) {
            av[11 + j] = fl_uw[(size_t)j * 2 * E + E + n];   // beta weights
            mv[11 + j] = fl_uw[(size_t)j * 2 * E + n];       // gamma weights
        }
#pragma unroll
        for (int r = 0; r < 32; ++r) {
            unsigned short ha = f2bf(av[r]), hm = f2bf(mv[r]);
            bta[n * 64 + r] = ha; bta[n * 64 + 32 + r] = ha;  // dup for lo-coeff half
            btm[n * 64 + r] = hm; btm[n * 64 + 32 + r] = hm;
        }
        return;
    }
    b -= 4;
    const float* src; unsigned short* dst; int R, C, nbx;
    if (b < 2048)      { src = dfc_w;   dst = dfc_wt; R = 1024; C = 2048; nbx = 64; }
    else if (b < 4096) { src = dproj_w; dst = dpj_wt; R = 2048; C = 1024; nbx = 32; b -= 2048; }
    else if (b < 5120) { src = sfc_w;   dst = sfc_wt; R = 1024; C = 1024; nbx = 32; b -= 4096; }
    else               { src = sproj_w; dst = spj_wt; R = 1024; C = 1024; nbx = 32; b -= 5120; }
    const int c0 = (b % nbx) * 32, r0 = (b / nbx) * 32;
#pragma unroll
    for (int i = 0; i < 4; ++i)
        tile[ty + i * 8][tx] = src[(size_t)(r0 + ty + i * 8) * C + c0 + tx];
    __syncthreads();
#pragma unroll
    for (int i = 0; i < 4; ++i)
        dst[(size_t)(c0 + ty + i * 8) * R + r0 + tx] = f2bf(tile[tx][ty + i * 8]);
}

// ------ gate partial GEMM: hp[c2] = A_z @ w1cat[:, h-half], 128x128 tiles ---
// Grid 512, 2 blocks/CU (LDS 64KB). BK=64. Cheap dots: +2 MFMAs per sub-step.
__global__ __launch_bounds__(256)
void gate_partial_kernel(const unsigned short* __restrict__ xh,
                         const unsigned short* __restrict__ xl,
                         const unsigned short* __restrict__ w1cat,
                         const unsigned short* __restrict__ w1cheap,
                         float* __restrict__ hp,      // [4][NTOK][GH]
                         float* __restrict__ cdot) {  // [4][NTOK][NCH]
    __shared__ __align__(16) unsigned short As[2][128 * 64];   // 32 KB
    __shared__ __align__(16) unsigned short Bs[2][128 * 64];   // 32 KB
    const int tid = threadIdx.x;
    const int bid = blockIdx.x;
    const int xcd = bid & 7, slot = bid >> 3;
    const int nx = slot & 1;
    const int strip = xcd * 32 + (slot >> 1);      // [0,256)
    const int m = strip >> 2, c2 = strip & 3;
    const int z = c2 & 1, h = c2 >> 1;
    const int t0 = m * 128, n0 = nx * 128;
    const unsigned short* A = z ? xl : xh;
    float* hpz = hp + (size_t)c2 * ((size_t)NTOK * GH);
    float* cd  = cdot + (size_t)c2 * ((size_t)NTOK * NCH);

    const int lane = tid & 63, wv = tid >> 6;
    const int wr = wv >> 1, wc = wv & 1;
    const int lm = lane & 15, q = lane >> 4;
    const int r0 = tid >> 2, gsl = tid & 3;
    const int g = gsl ^ ((r0 >> 1) & 3);
    const int lbase = wv * 512;

    const unsigned short* pa0 = A + (size_t)(t0 + r0) * E + g * 8;
    const unsigned short* pa1 = A + (size_t)(t0 + 64 + r0) * E + g * 8;
    const unsigned short* pb0 = w1cat + (size_t)(n0 + r0) * 2048 + h * 1024 + g * 8;
    const unsigned short* pb1 = w1cat + (size_t)(n0 + 64 + r0) * 2048 + h * 1024 + g * 8;
    const unsigned short* pcw = w1cheap + (size_t)(nx * 16 + lm) * 2048 + h * 1024 + q * 8;

    f32x4 acc[4][4];
#pragma unroll
    for (int s = 0; s < 4; ++s)
#pragma unroll
        for (int t = 0; t < 4; ++t) acc[s][t] = (f32x4){0.f, 0.f, 0.f, 0.f};
    f32x4 accC[2];
    accC[0] = (f32x4){0.f, 0.f, 0.f, 0.f};
    accC[1] = (f32x4){0.f, 0.f, 0.f, 0.f};

    glds16(pa0, &As[0][lbase]);
    glds16(pa1, &As[0][2048 + lbase]);
    glds16(pa0 + 32, &As[0][4096 + lbase]);
    glds16(pa1 + 32, &As[0][4096 + 2048 + lbase]);
    glds16(pb0, &Bs[0][lbase]);
    glds16(pb1, &Bs[0][2048 + lbase]);
    glds16(pb0 + 32, &Bs[0][4096 + lbase]);
    glds16(pb1 + 32, &Bs[0][4096 + 2048 + lbase]);
    bf16x8 cf0 = *(const bf16x8*)pcw;
    bf16x8 cf1 = *(const bf16x8*)(pcw + 32);

    int cur = 0;
    for (int k0 = 0;; k0 += 64) {
        __syncthreads();                  // drains vmcnt -> buf[cur] landed
        const int kn = k0 + 64;
        bf16x8 cf0n, cf1n;
        if (kn < 1024) {
            glds16(pa0 + kn, &As[cur ^ 1][lbase]);
            glds16(pa1 + kn, &As[cur ^ 1][2048 + lbase]);
            glds16(pa0 + kn + 32, &As[cur ^ 1][4096 + lbase]);
            glds16(pa1 + kn + 32, &As[cur ^ 1][4096 + 2048 + lbase]);
            glds16(pb0 + kn, &Bs[cur ^ 1][lbase]);
            glds16(pb1 + kn, &Bs[cur ^ 1][2048 + lbase]);
            glds16(pb0 + kn + 32, &Bs[cur ^ 1][4096 + lbase]);
            glds16(pb1 + kn + 32, &Bs[cur ^ 1][4096 + 2048 + lbase]);
            cf0n = *(const bf16x8*)(pcw + kn);
            cf1n = *(const bf16x8*)(pcw + kn + 32);
        }
#pragma unroll
        for (int sub = 0; sub < 2; ++sub) {
            const int off = sub * 4096;
            bf16x8 af[4], bfr[4];
#pragma unroll
            for (int s = 0; s < 4; ++s) af[s] = *(const bf16x8*)&As[cur][off + ldso(wr * 64 + s * 16 + lm, q)];
#pragma unroll
            for (int t = 0; t < 4; ++t) bfr[t] = *(const bf16x8*)&Bs[cur][off + ldso(wc * 64 + t * 16 + lm, q)];
#pragma unroll
            for (int s = 0; s < 4; ++s)
#pragma unroll
                for (int t = 0; t < 4; ++t)
                    acc[s][t] = __builtin_amdgcn_mfma_f32_16x16x32_bf16(af[s], bfr[t], acc[s][t], 0, 0, 0);
            bf16x8 cf = sub ? cf1 : cf0;
            bf16x8 ac0 = wc ? af[2] : af[0];
            bf16x8 ac1 = wc ? af[3] : af[1];
            accC[0] = __builtin_amdgcn_mfma_f32_16x16x32_bf16(ac0, cf, accC[0], 0, 0, 0);
            accC[1] = __builtin_amdgcn_mfma_f32_16x16x32_bf16(ac1, cf, accC[1], 0, 0, 0);
        }
        if (kn >= 1024) break;
        cf0 = cf0n; cf1 = cf1n; cur ^= 1;
    }
#pragma unroll
    for (int s = 0; s < 4; ++s)
#pragma unroll
        for (int t = 0; t < 4; ++t)
#pragma unroll
            for (int rg = 0; rg < 4; ++rg) {
                int rl = wr * 64 + s * 16 + q * 4 + rg;
                int c  = wc * 64 + t * 16 + lm;
                hpz[(size_t)(t0 + rl) * GH + n0 + c] = acc[s][t][rg];
            }
    const int cc = nx * 16 + lm;
    if (cc < NCH) {
#pragma unroll
        for (int i = 0; i < 2; ++i)
#pragma unroll
            for (int rg = 0; rg < 4; ++rg) {
                int rl = wr * 64 + wc * 32 + i * 16 + q * 4 + rg;
                cd[(size_t)(t0 + rl) * NCH + cc] = accC[i][rg];
            }
    }
}

// ------- finalize: h=gelu(sum4 hp+gb1); logits=h@gw2; softmax/argmax --------
// Emits per-token coefficient rows Cm[8192][64] bf16 (hi|lo) for the
// cheap coefficient-GEMM; zero rows for experts 0/1.
__global__ __launch_bounds__(256)
void gate_finalize_kernel(const float* __restrict__ hp,    // [4][NTOK][GH]
                          const float* __restrict__ gb1, const float* __restrict__ gw2,
                          const float* __restrict__ gb2, const float* __restrict__ ebias,
                          const float* __restrict__ pm_alpha,
                          const float* __restrict__ cdot,  // [4][NTOK][NCH]
                          const float* __restrict__ p2_alpha, const float* __restrict__ p2_b,
                          const float* __restrict__ p4_alpha, const float* __restrict__ p4_b,
                          const float* __restrict__ rg_b, const float* __restrict__ fl_db,
                          float* __restrict__ scale, int* __restrict__ counts,
                          int* __restrict__ tlist,
                          unsigned short* __restrict__ Cm) {
    __shared__ float hs[32][264];
    __shared__ float g2s[GH * NEXP];
    __shared__ int tokexp[32];
    const int tid = threadIdx.x;
    const int t0 = blockIdx.x * 32;
    const size_t HPS = (size_t)NTOK * GH;
    for (int i = tid; i < GH * NEXP; i += 256) g2s[i] = gw2[i];
#pragma unroll
    for (int i = 0; i < 8; ++i) {
        int f4 = i * 256 + tid;
        int row = f4 >> 6, c4 = (f4 & 63) * 4;
        size_t base = (size_t)(t0 + row) * GH + c4;
        float4 a = *reinterpret_cast<const float4*>(&hp[base]);
        float4 b = *reinterpret_cast<const float4*>(&hp[HPS + base]);
        float4 c = *reinterpret_cast<const float4*>(&hp[2 * HPS + base]);
        float4 d = *reinterpret_cast<const float4*>(&hp[3 * HPS + base]);
        float4 o;
        o.x = gelu_erf(a.x + b.x + c.x + d.x + gb1[c4 + 0]);
        o.y = gelu_erf(a.y + b.y + c.y + d.y + gb1[c4 + 1]);
        o.z = gelu_erf(a.z + b.z + c.z + d.z + gb1[c4 + 2]);
        o.w = gelu_erf(a.w + b.w + c.w + d.w + gb1[c4 + 3]);
        *reinterpret_cast<float4*>(&hs[row][c4]) = o;
    }
    __syncthreads();
    const int t = tid >> 3, j = tid & 7;
    float p[NEXP] = {0.f, 0.f, 0.f, 0.f, 0.f, 0.f};
#pragma unroll 8
    for (int kk = 0; kk < 32; ++kk) {
        int k = j + kk * 8;
        float hv = hs[t][k];
        const float* gr = &g2s[k * NEXP];
#pragma unroll
        for (int m = 0; m < NEXP; ++m) p[m] += hv * gr[m];
    }
#pragma unroll
    for (int m = 0; m < NEXP; ++m) {
        p[m] += __shfl_xor(p[m], 4, 64);
        p[m] += __shfl_xor(p[m], 2, 64);
        p[m] += __shfl_xor(p[m], 1, 64);
    }
    if (j == 0) {
        float L[NEXP];
#pragma unroll
        for (int m = 0; m < NEXP; ++m) L[m] = p[m] + gb2[m] + ebias[m];
        float mx = L[0]; int am = 0;
#pragma unroll
        for (int m = 1; m < NEXP; ++m) { if (L[m] > mx) { mx = L[m]; am = m; } }
        float S = 0.f;
#pragma unroll
        for (int m = 0; m < NEXP; ++m) S += expf(L[m] - mx);
        float pt = 1.f / S;
        scale[t0 + t] = pm_alpha[0] * (pt / (pt + 1e-9f));
        tokexp[t] = am;
    }
    __syncthreads();
    if (tid < NEXP) {
        const int e = tid;
        int cnt = 0;
#pragma unroll
        for (int i = 0; i < 32; ++i) cnt += (tokexp[i] == e);
        if (cnt) {
            int base = atomicAdd(&counts[e], cnt);
            int pos = 0;
#pragma unroll
            for (int i = 0; i < 32; ++i)
                if (tokexp[i] == e) tlist[e * NTOK + base + (pos++)] = t0 + i;
        }
    }
    // ---- per-token coefficient rows for the cheap coefficient-GEMM ----
    const size_t CDS = (size_t)NTOK * NCH;
    for (int i = tid; i < 32 * 32; i += 256) {
        const int tt = i >> 5, r = i & 31;
        const int tok = t0 + tt;
        const int e = tokexp[tt];
        float c = 0.f;
        int slot = -1;
        if (r == 0)       { if (e == 2) c = 1.f; }
        else if (r <= 2)  { if (e == 2) slot = r - 1; }
        else if (r == 3)  { if (e == 3) c = 1.f; }
        else if (r <= 7)  { if (e == 3) slot = r - 2; }
        else if (r == 8)  { if (e == 4) c = 1.f; }
        else if (r == 9)  { if (e == 4) slot = 6; }
        else if (r == 10) { if (e == 5) c = 1.f; }
        else if (r <= 26) { if (e == 5) slot = r - 4; }
        if (slot >= 0) {
            size_t idx = (size_t)tok * NCH + slot;
            float s = cdot[idx] + cdot[CDS + idx] + cdot[2 * CDS + idx] + cdot[3 * CDS + idx];
            if (slot < 2)       c = p2_alpha[slot] * gelu_erf(s + p2_b[slot]);
            else if (slot < 6)  c = p4_alpha[slot - 2] * gelu_erf(s + p4_b[slot - 2]);
            else if (slot == 6) c = 1.f / (1.f + expf(-(s + rg_b[0])));
            else                c = gelu_erf(s + fl_db[slot - 7]);
        }
        unsigned short hi = f2bf(c);
        Cm[(size_t)tok * 64 + r] = hi;
        Cm[(size_t)tok * 64 + 32 + r] = f2bf(c - bf2f(hi));
    }
}

// ---- depth-3 counted-vmcnt pipelined staging: 4 glds16 per tile per thread.
#define STAGEAB(t, jb)                                            \
    do {                                                          \
        glds16(pa + (t) * 64,      &As[jb][lbase]);               \
        glds16(pa + (t) * 64 + 32, &As[jb][2048 + lbase]);        \
        glds16(pb + (t) * 64,      &Bs[jb][lbase]);               \
        glds16(pb + (t) * 64 + 32, &Bs[jb][2048 + lbase]);        \
    } while (0)

// -------- GEMM1 (gather x_hi -> gelu -> bf16 h) + cheap coefficient-GEMM ----
// blocks [0,2048): gemm1, 64x64 tiles, depth-3 counted-vmcnt pipeline.
// blocks [2048,4096): coefgemm: out[8192][1024] = (Cm@Btm . x + Cm@Bta)*scale,
// dense over ALL tokens (e0/e1 rows get zeros; gemm2 overwrites them next
// dispatch). M=8192 (128 mtiles), N=1024 (16 ntiles), K=64, single K-tile.
__global__ __launch_bounds__(256)
void moe_gemm1_kernel(const unsigned short* __restrict__ xh,
                      const unsigned short* __restrict__ B0, const unsigned short* __restrict__ B1,
                      const float* __restrict__ bias0, const float* __restrict__ bias1,
                      const int* __restrict__ counts, const int* __restrict__ tlist,
                      unsigned short* __restrict__ H0, unsigned short* __restrict__ H1,
                      const unsigned short* __restrict__ Cm,
                      const unsigned short* __restrict__ bta, const unsigned short* __restrict__ btm,
                      const float* __restrict__ x, const float* __restrict__ scale,
                      float* __restrict__ out) {
    __shared__ __align__(16) unsigned short As[3][64 * 64];   // 24 KB
    __shared__ __align__(16) unsigned short Bs[3][64 * 64];   // 24 KB
    __shared__ int toks[64];
    const int tid = threadIdx.x;
    const int bid = blockIdx.x;
    const int lane = tid & 63, wv = tid >> 6;
    const int wm = (wv & 1) * 32, wn = (wv >> 1) * 32;
    const int lm = lane & 15, q = lane >> 4;
    const int r0 = tid >> 2, gsl = tid & 3;
    const int g = gsl ^ ((r0 >> 1) & 3);
    const int lbase = wv * 512;

    if (bid >= 2048) {
        // ---- cheap coefficient-GEMM ----
        const int cg = bid - 2048;
        const int xcd = cg & 7, s = cg >> 3;       // [0,256)
        const int nx = s & 15;
        const int mt = xcd + 8 * (s >> 4);         // [0,128)
        const int t0 = mt * 64, n0 = nx * 64;
        unsigned short* Ct = &As[0][0];
        unsigned short* Ba = &As[1][0];
        unsigned short* Bm = &As[2][0];

        const unsigned short* pc = Cm + (size_t)(t0 + r0) * 64 + g * 8;
        const unsigned short* pba = bta + (size_t)(n0 + r0) * 64 + g * 8;
        const unsigned short* pbm = btm + (size_t)(n0 + r0) * 64 + g * 8;
        glds16(pc,       &Ct[lbase]);
        glds16(pc + 32,  &Ct[2048 + lbase]);
        glds16(pba,      &Ba[lbase]);
        glds16(pba + 32, &Ba[2048 + lbase]);
        glds16(pbm,      &Bm[lbase]);
        glds16(pbm + 32, &Bm[2048 + lbase]);

        f32x4 accA[2][2], accM[2][2];
#pragma unroll
        for (int s2 = 0; s2 < 2; ++s2)
#pragma unroll
            for (int t2 = 0; t2 < 2; ++t2) {
                accA[s2][t2] = (f32x4){0.f, 0.f, 0.f, 0.f};
                accM[s2][t2] = (f32x4){0.f, 0.f, 0.f, 0.f};
            }
        __syncthreads();                           // drains vmcnt
#pragma unroll
        for (int sub = 0; sub < 2; ++sub) {
            const int off = sub * 2048;
            bf16x8 af[2], ba[2], bm[2];
#pragma unroll
            for (int s2 = 0; s2 < 2; ++s2) af[s2] = *(const bf16x8*)&Ct[off + ldso(wm + s2 * 16 + lm, q)];
#pragma unroll
            for (int t2 = 0; t2 < 2; ++t2) {
                ba[t2] = *(const bf16x8*)&Ba[off + ldso(wn + t2 * 16 + lm, q)];
                bm[t2] = *(const bf16x8*)&Bm[off + ldso(wn + t2 * 16 + lm, q)];
            }
#pragma unroll
            for (int s2 = 0; s2 < 2; ++s2)
#pragma unroll
                for (int t2 = 0; t2 < 2; ++t2) {
                    accA[s2][t2] = __builtin_amdgcn_mfma_f32_16x16x32_bf16(af[s2], ba[t2], accA[s2][t2], 0, 0, 0);
                    accM[s2][t2] = __builtin_amdgcn_mfma_f32_16x16x32_bf16(af[s2], bm[t2], accM[s2][t2], 0, 0, 0);
                }
        }
#pragma unroll
        for (int s2 = 0; s2 < 2; ++s2)
#pragma unroll
            for (int t2 = 0; t2 < 2; ++t2)
#pragma unroll
                for (int rg = 0; rg < 4; ++rg) {
                    int rl = wm + s2 * 16 + q * 4 + rg;
                    int gc = n0 + wn + t2 * 16 + lm;
                    int tok = t0 + rl;
                    float xv = x[(size_t)tok * E + gc];
                    out[(size_t)tok * E + gc] =
                        scale[tok] * (accM[s2][t2][rg] * xv + accA[s2][t2][rg]);
                }
        return;
    }

    // ---- gemm1 ----
    const int xcd = bid & 7, slot = bid >> 3;      // [0,256)
    const int nx = slot & 31;
    const int strip = xcd + 8 * (slot >> 5);       // [0,64), XCD-strided
    const int z = strip & 1;
    const int N = z ? 1024 : 2048;
    const int cnt = counts[z];
    const int i0 = (strip >> 1) * 64;
    const int n0 = nx * 64;
    if (i0 >= cnt || n0 >= N) return;
    const unsigned short* Bz = z ? B1 : B0;
    const float* bias = z ? bias1 : bias0;

    if (tid < 64) toks[tid] = tlist[z * NTOK + min(i0 + tid, cnt - 1)];
    __syncthreads();

    const unsigned short* pa = xh + (size_t)toks[r0] * E + g * 8;
    const unsigned short* pb = Bz + (size_t)(n0 + r0) * E + g * 8;

    f32x4 acc[2][2];
#pragma unroll
    for (int s = 0; s < 2; ++s)
#pragma unroll
        for (int t = 0; t < 2; ++t) acc[s][t] = (f32x4){0.f, 0.f, 0.f, 0.f};

    STAGEAB(0, 0); STAGEAB(1, 1); STAGEAB(2, 2);

    const int nt = E / 64;                        // 16
    for (int i = 0; i < nt; ++i) {
        const int ahead = nt - 1 - i;
        if (ahead >= 2)      asm volatile("s_waitcnt vmcnt(8)" ::: "memory");
        else if (ahead == 1) asm volatile("s_waitcnt vmcnt(4)" ::: "memory");
        else                 asm volatile("s_waitcnt vmcnt(0)" ::: "memory");
        asm volatile("s_barrier" ::: "memory");   // all waves: tile i landed
        const int jb = i % 3;
#pragma unroll
        for (int sub = 0; sub < 2; ++sub) {
            const int off = sub * 2048;
            bf16x8 af[2], bfr[2];
#pragma unroll
            for (int s = 0; s < 2; ++s) af[s] = *(const bf16x8*)&As[jb][off + ldso(wm + s * 16 + lm, q)];
#pragma unroll
            for (int t = 0; t < 2; ++t) bfr[t] = *(const bf16x8*)&Bs[jb][off + ldso(wn + t * 16 + lm, q)];
#pragma unroll
            for (int s = 0; s < 2; ++s)
#pragma unroll
                for (int t = 0; t < 2; ++t)
                    acc[s][t] = __builtin_amdgcn_mfma_f32_16x16x32_bf16(af[s], bfr[t], acc[s][t], 0, 0, 0);
        }
        asm volatile("s_barrier" ::: "memory");   // all waves done reading buf
        if (i + 3 < nt) STAGEAB(i + 3, jb);
    }
    unsigned short* Hz = z ? H1 : H0;
#pragma unroll
    for (int s = 0; s < 2; ++s)
#pragma unroll
        for (int t = 0; t < 2; ++t)
#pragma unroll
            for (int rg = 0; rg < 4; ++rg) {
                int rl = wm + s * 16 + q * 4 + rg;
                int gc = n0 + wn + t * 16 + lm;
                float v = acc[s][t][rg] + bias[gc];
                Hz[(size_t)(i0 + rl) * N + gc] = f2bf(gelu_erf(v));
            }
}

// ---------------- GEMM2 (experts 0/1 down-proj), pure GEMM ------------------
// Grid 1024. 64x64 tiles, BK=64, depth-3 counted-vmcnt pipeline (48KB LDS).
__global__ __launch_bounds__(256)
void moe_gemm2_kernel(const unsigned short* __restrict__ h1, const unsigned short* __restrict__ h2,
                      const unsigned short* __restrict__ dpj, const unsigned short* __restrict__ spj,
                      const float* __restrict__ dproj_b, const float* __restrict__ sproj_b,
                      const int* __restrict__ counts, const int* __restrict__ tlist,
                      const float* __restrict__ scale,
                      float* __restrict__ out) {
    __shared__ __align__(16) unsigned short As[3][64 * 64];   // 24 KB
    __shared__ __align__(16) unsigned short Bs[3][64 * 64];   // 24 KB
    __shared__ int toks[64];
    const int tid = threadIdx.x;
    const int bb = blockIdx.x;
    const int lane = tid & 63;

    const int xcd = bb & 7, slot = bb >> 3;    // [0,128)
    const int nx = slot & 15;
    const int strip = xcd + 8 * (slot >> 4);   // [0,64)
    const int z = strip & 1;
    const int i0 = (strip >> 1) * 64;
    const int n0 = nx * 64;
    const int K = z ? 1024 : 2048;
    const int cnt = counts[z];
    if (i0 >= cnt) return;
    const int rows = min(64, cnt - i0);
    const unsigned short* Az = z ? h2 : h1;
    const unsigned short* Bz = z ? spj : dpj;
    const float* bias = z ? sproj_b : dproj_b;

    if (tid < 64) toks[tid] = tlist[z * NTOK + min(i0 + tid, cnt - 1)];
    __syncthreads();

    const int wv = tid >> 6;
    const int wm = (wv & 1) * 32, wn = (wv >> 1) * 32;
    const int lm = lane & 15, q = lane >> 4;
    const int r0 = tid >> 2, gsl = tid & 3;
    const int g = gsl ^ ((r0 >> 1) & 3);
    const int lbase = wv * 512;

    const unsigned short* pa = Az + (size_t)(i0 + r0) * K + g * 8;
    const unsigned short* pb = Bz + (size_t)(n0 + r0) * K + g * 8;

    f32x4 acc[2][2];
#pragma unroll
    for (int s = 0; s < 2; ++s)
#pragma unroll
        for (int t = 0; t < 2; ++t) acc[s][t] = (f32x4){0.f, 0.f, 0.f, 0.f};

    STAGEAB(0, 0); STAGEAB(1, 1); STAGEAB(2, 2);

    const int nt = K / 64;                        // 16 or 32
    for (int i = 0; i < nt; ++i) {
        const int ahead = nt - 1 - i;
        if (ahead >= 2)      asm volatile("s_waitcnt vmcnt(8)" ::: "memory");
        else if (ahead == 1) asm volatile("s_waitcnt vmcnt(4)" ::: "memory");
        else                 asm volatile("s_waitcnt vmcnt(0)" ::: "memory");
        asm volatile("s_barrier" ::: "memory");
        const int jb = i % 3;
#pragma unroll
        for (int sub = 0; sub < 2; ++sub) {
            const int off = sub * 2048;
            bf16x8 af[2], bfr[2];
#pragma unroll
            for (int s = 0; s < 2; ++s) af[s] = *(const bf16x8*)&As[jb][off + ldso(wm + s * 16 + lm, q)];
#pragma unroll
            for (int t = 0; t < 2; ++t) bfr[t] = *(const bf16x8*)&Bs[jb][off + ldso(wn + t * 16 + lm, q)];
#pragma unroll
            for (int s = 0; s < 2; ++s)
#pragma unroll
                for (int t = 0; t < 2; ++t)
                    acc[s][t] = __builtin_amdgcn_mfma_f32_16x16x32_bf16(af[s], bfr[t], acc[s][t], 0, 0, 0);
        }
        asm volatile("s_barrier" ::: "memory");
        if (i + 3 < nt) STAGEAB(i + 3, jb);
    }
#pragma unroll
    for (int s = 0; s < 2; ++s)
#pragma unroll
        for (int t = 0; t < 2; ++t)
#pragma unroll
            for (int rg = 0; rg < 4; ++rg) {
                int rl = wm + s * 16 + q * 4 + rg;
                if (rl < rows) {
                    int gc = n0 + wn + t * 16 + lm;
                    int tok = toks[rl];
                    out[(size_t)tok * E + gc] = scale[tok] * (acc[s][t][rg] + bias[gc]);
                }
            }
}

extern "C" void kernel_launch(void* const* d_in, const int* in_sizes, int n_in,
                              void* d_out, int out_size, void* d_ws, size_t ws_size,
                              hipStream_t stream) {
    const float* x        = (const float*)d_in[0];
    const float* gw1      = (const float*)d_in[1];
    const float* gb1      = (const float*)d_in[2];
    const float* gw2      = (const float*)d_in[3];
    const float* gb2      = (const float*)d_in[4];
    const float* ebias    = (const float*)d_in[5];
    const float* pm_alpha = (const float*)d_in[6];
    const float* dfc_w    = (const float*)d_in[7];
    const float* dfc_b    = (const float*)d_in[8];
    const float* dproj_w  = (const float*)d_in[9];
    const float* dproj_b  = (const float*)d_in[10];
    const float* sfc_w    = (const float*)d_in[11];
    const float* sfc_b    = (const float*)d_in[12];
    const float* sproj_w  = (const float*)d_in[13];
    const float* sproj_b  = (const float*)d_in[14];
    const float* p2_w     = (const float*)d_in[15];
    const float* p2_v     = (const float*)d_in[16];
    const float* p2_alpha = (const float*)d_in[17];
    const float* p2_b     = (const float*)d_in[18];
    const float* p2_bias  = (const float*)d_in[19];
    const float* p4_w     = (const float*)d_in[20];
    const float* p4_v     = (const float*)d_in[21];
    const float* p4_alpha = (const float*)d_in[22];
    const float* p4_b     = (const float*)d_in[23];
    const float* p4_bias  = (const float*)d_in[24];
    const float* rg_u     = (const float*)d_in[25];
    const float* rg_a     = (const float*)d_in[26];
    const float* rg_b     = (const float*)d_in[27];
    const float* rg_bias  = (const float*)d_in[28];
    const float* fl_dw    = (const float*)d_in[29];
    const float* fl_db    = (const float*)d_in[30];
    const float* fl_uw    = (const float*)d_in[31];
    const float* fl_ub    = (const float*)d_in[32];
    float* out = (float*)d_out;

    char* ws = (char*)d_ws;
    size_t off = 0;
    int*            counts = (int*)(ws + off);            off += 256;
    float*          scale  = (float*)(ws + off);          off += (size_t)NTOK * 4;
    int*            tlist  = (int*)(ws + off);            off += (size_t)NEXP * NTOK * 4;
    float*          cdot   = (float*)(ws + off);          off += (size_t)4 * NTOK * NCH * 4;
    unsigned short* Cm     = (unsigned short*)(ws + off); off += (size_t)NTOK * 64 * 2;
    unsigned short* bta    = (unsigned short*)(ws + off); off += (size_t)E * 64 * 2;
    unsigned short* btm    = (unsigned short*)(ws + off); off += (size_t)E * 64 * 2;
    unsigned short* w1cheap= (unsigned short*)(ws + off); off += (size_t)64 * 2048 * 2;
    unsigned short* w1cat  = (unsigned short*)(ws + off); off += (size_t)GH * 2048 * 2;
    unsigned short* dfc_wt = (unsigned short*)(ws + off); off += (size_t)2048 * 1024 * 2;
    unsigned short* dpj_wt = (unsigned short*)(ws + off); off += (size_t)1024 * 2048 * 2;
    unsigned short* sfc_wt = (unsigned short*)(ws + off); off += (size_t)1024 * 1024 * 2;
    unsigned short* spj_wt = (unsigned short*)(ws + off); off += (size_t)1024 * 1024 * 2;
    unsigned short* x_hi   = (unsigned short*)(ws + off); off += (size_t)NTOK * E * 2;
    // Union region: gate phase {x_lo} then expert phase {h1, h2}
    char* U = ws + off;
    unsigned short* x_lo = (unsigned short*)U;                              // 16 MB
    unsigned short* h1   = (unsigned short*)U;                              // 16 MB (2048 x 2048)
    unsigned short* h2   = (unsigned short*)(U + (size_t)16 * 1024 * 1024); // 8 MB (2048 x 1024)
    // 4 hp partials (4 x 8 MB = 32 MB) live in d_out (dead after finalize;
    // coefgemm then rewrites every token row, gemm2 overwrites e0/e1 rows).
    float* hp = out;

    hipMemsetAsync(counts, 0, 256, stream);
    prep_kernel<<<8516, 256, 0, stream>>>(x, x_hi, x_lo, gw1, w1cat,
                                          p2_w, p4_w, rg_u, fl_dw, w1cheap,
                                          p2_bias, p2_v, p4_bias, p4_v,
                                          rg_a, rg_bias, fl_uw, fl_ub, bta, btm,
                                          dfc_w, dfc_wt, dproj_w, dpj_wt,
                                          sfc_w, sfc_wt, sproj_w, spj_wt);
    gate_partial_kernel<<<512, 256, 0, stream>>>(
        x_hi, x_lo, w1cat, w1cheap, hp, cdot);
    gate_finalize_kernel<<<NTOK / 32, 256, 0, stream>>>(
        hp, gb1, gw2, gb2, ebias, pm_alpha, cdot,
        p2_alpha, p2_b, p4_alpha, p4_b, rg_b, fl_db,
        scale, counts, tlist, Cm);
    // blocks [0,2048): gemm1 (32 x 64-row tiles = 2048 rows per expert);
    // blocks [2048,4096): cheap coefficient-GEMM over all 8192 tokens.
    moe_gemm1_kernel<<<4096, 256, 0, stream>>>(
        x_hi, dfc_wt, sfc_wt, dfc_b, sfc_b, counts, tlist, h1, h2,
        Cm, bta, btm, x, scale, out);
    moe_gemm2_kernel<<<1024, 256, 0, stream>>>(
        h1, h2, dpj_wt, spj_wt, dproj_b, sproj_b, counts, tlist, scale, out);
    (void)in_sizes; (void)n_in; (void)out_size; (void)ws_size;
}